// Round 1
// baseline (898.749 us; speedup 1.0000x reference)
//
#include <hip/hip_runtime.h>
#include <cstddef>

#define Bn 2
#define Sn 1500
#define SPn 1536
#define Cn 1024
#define Hn 16
#define FFn 4096

typedef __attribute__((ext_vector_type(8))) short bf16x8;
typedef __attribute__((ext_vector_type(4))) float f32x4;
typedef unsigned short u16;

__device__ __forceinline__ u16 f2bu(float f) {
  unsigned u = __float_as_uint(f);
  return (u16)((u + 0x7fffu + ((u >> 16) & 1u)) >> 16);
}

// ---------------- transpose + cast input: x (B,C,S) -> xT (B,SP,C) f32 + bf16 ----------------
__global__ __launch_bounds__(256) void k_transpose_in(
    const float* __restrict__ x, float* __restrict__ xT, u16* __restrict__ xTb)
{
  __shared__ float t[32][33];
  const int b = blockIdx.z, c0 = blockIdx.x * 32, s0 = blockIdx.y * 32;
  const int tx = threadIdx.x & 31, ty = threadIdx.x >> 5;
#pragma unroll
  for (int i = 0; i < 32; i += 8) {
    int c = c0 + ty + i, s = s0 + tx;
    t[ty + i][tx] = (s < Sn) ? x[((size_t)b * Cn + c) * Sn + s] : 0.f;
  }
  __syncthreads();
#pragma unroll
  for (int i = 0; i < 32; i += 8) {
    int s = s0 + ty + i, c = c0 + tx;
    float v = t[tx][ty + i];
    size_t o = ((size_t)b * SPn + s) * Cn + c;
    xT[o] = v;
    xTb[o] = f2bu(v);
  }
}

// ---------------- transpose output: outT (B,SP,C) -> out (B,C,S) ----------------
__global__ __launch_bounds__(256) void k_transpose_out(
    const float* __restrict__ oT, float* __restrict__ o)
{
  __shared__ float t[32][33];
  const int b = blockIdx.z, c0 = blockIdx.x * 32, s0 = blockIdx.y * 32;
  const int tx = threadIdx.x & 31, ty = threadIdx.x >> 5;
#pragma unroll
  for (int i = 0; i < 32; i += 8) {
    int s = s0 + ty + i, c = c0 + tx;
    t[ty + i][tx] = oT[((size_t)b * SPn + s) * Cn + c];  // [s-local][c-local]
  }
  __syncthreads();
#pragma unroll
  for (int i = 0; i < 32; i += 8) {
    int c = c0 + ty + i, s = s0 + tx;
    if (s < Sn) o[((size_t)b * Cn + c) * Sn + s] = t[tx][ty + i];
  }
}

// ---------------- f32 -> bf16 cast (n4 = count of float4 groups) ----------------
__global__ __launch_bounds__(256) void k_cast_b(
    const float* __restrict__ src, u16* __restrict__ dst, int n4)
{
  int i = blockIdx.x * 256 + threadIdx.x;
  if (i < n4) {
    float4 v = *(const float4*)(src + (size_t)i * 4);
    ushort4 o;
    o.x = f2bu(v.x); o.y = f2bu(v.y); o.z = f2bu(v.z); o.w = f2bu(v.w);
    *(ushort4*)(dst + (size_t)i * 4) = o;
  }
}

__global__ __launch_bounds__(256) void k_pack_bias(
    const float* __restrict__ q, const float* __restrict__ k,
    const float* __restrict__ v, float* __restrict__ o)
{
  int i = blockIdx.x * 256 + threadIdx.x;
  if (i < 3 * Cn) o[i] = (i < Cn) ? q[i] : ((i < 2 * Cn) ? k[i - Cn] : v[i - 2 * Cn]);
}

// ---------------- gate: gate[b,h,s] from x (original layout, coalesced over s) ----------------
__global__ __launch_bounds__(256) void k_gate(
    const float* __restrict__ x, const float* __restrict__ Wg,
    const float* __restrict__ bg, const float* __restrict__ gc,
    float* __restrict__ gate)
{
  const int b = blockIdx.z, h = blockIdx.y;
  const int s = blockIdx.x * 256 + threadIdx.x;
  const bool vld = s < Sn;
  const float* xp = x + ((size_t)b * Cn + h * 64) * Sn + (vld ? s : 0);
  float dot[8];
#pragma unroll
  for (int o = 0; o < 8; o++) dot[o] = 0.f;
  for (int d = 0; d < 64; d++) {
    float v = xp[(size_t)d * Sn];
#pragma unroll
    for (int o = 0; o < 8; o++) dot[o] += Wg[o * 64 + d] * v;
  }
  float sa = dot[0] + dot[1] + dot[2] + dot[3] + bg[0] + bg[1] + bg[2] + bg[3];
  float sb = dot[4] + dot[5] + dot[6] + dot[7] + bg[4] + bg[5] + bg[6] + bg[7];
  float ga = 1.f / (1.f + __expf(-sa));
  float gb = 1.f / (1.f + __expf(-sb));
  float gv = ga * (gb * gc[h] - 1.f) + 2.f;
  gate[((size_t)b * Hn + h) * SPn + s] = vld ? gv : 0.f;
}

// ---------------- bf16 MFMA GEMM: OutT[b][s][o] = sum_c A[o][c]*X[b][s][c] + bias[o] ----------------
// A: M x K row-major bf16. X: B x SP x K row-major bf16. Out: B x SP x M (f32 or gelu->bf16).
template <int EPI>
__global__ __launch_bounds__(256) void k_gemm(
    const u16* __restrict__ A, const u16* __restrict__ X,
    const float* __restrict__ bias, void* __restrict__ out, int M, int K)
{
  const int b = blockIdx.z;
  const int m0 = blockIdx.x * 128;
  const int s0 = blockIdx.y * 128;
  const int tid = threadIdx.x;
  const int lane = tid & 63;
  const int wid = tid >> 6;
  const int wm = (wid >> 1) * 64;
  const int wn = (wid & 1) * 64;
  const int l15 = lane & 15;
  const int g4 = lane >> 4;

  __shared__ __align__(16) u16 lA[128][32];
  __shared__ __align__(16) u16 lX[128][32];

  f32x4 acc[4][4];
  f32x4 zr; zr[0] = 0.f; zr[1] = 0.f; zr[2] = 0.f; zr[3] = 0.f;
#pragma unroll
  for (int i = 0; i < 4; i++)
#pragma unroll
    for (int j = 0; j < 4; j++) acc[i][j] = zr;

  const size_t xbase = ((size_t)b * SPn + s0) * K;

  for (int kt = 0; kt < K; kt += 32) {
    __syncthreads();
#pragma unroll
    for (int r = 0; r < 2; r++) {
      int idx = r * 256 + tid;
      int row = idx >> 2;
      int c = idx & 3;
      int cs = c ^ (row & 3);
      int4 av = *(const int4*)(A + (size_t)(m0 + row) * K + kt + c * 8);
      *(int4*)&lA[row][cs * 8] = av;
      int4 xv = *(const int4*)(X + xbase + (size_t)row * K + kt + c * 8);
      *(int4*)&lX[row][cs * 8] = xv;
    }
    __syncthreads();
    bf16x8 af[4], bfr[4];
#pragma unroll
    for (int i = 0; i < 4; i++) {
      int ra = wm + i * 16 + l15;
      af[i] = *(const bf16x8*)&lA[ra][(g4 ^ (ra & 3)) * 8];
      int rb = wn + i * 16 + l15;
      bfr[i] = *(const bf16x8*)&lX[rb][(g4 ^ (rb & 3)) * 8];
    }
#pragma unroll
    for (int i = 0; i < 4; i++)
#pragma unroll
      for (int j = 0; j < 4; j++)
        acc[i][j] = __builtin_amdgcn_mfma_f32_16x16x32_bf16(af[i], bfr[j], acc[i][j], 0, 0, 0);
  }

#pragma unroll
  for (int i = 0; i < 4; i++) {
    int o = m0 + wm + i * 16 + g4 * 4;
    float4 bs = *(const float4*)(bias + o);
#pragma unroll
    for (int j = 0; j < 4; j++) {
      int s = s0 + wn + j * 16 + l15;
      size_t oidx = ((size_t)b * SPn + s) * M + o;
      f32x4 v = acc[i][j];
      float x0 = v[0] + bs.x, x1 = v[1] + bs.y, x2 = v[2] + bs.z, x3 = v[3] + bs.w;
      if (EPI == 0) {
        float4 st; st.x = x0; st.y = x1; st.z = x2; st.w = x3;
        *(float4*)((float*)out + oidx) = st;
      } else {
        // exact gelu then bf16
        x0 = 0.5f * x0 * (1.f + erff(x0 * 0.70710678118654752f));
        x1 = 0.5f * x1 * (1.f + erff(x1 * 0.70710678118654752f));
        x2 = 0.5f * x2 * (1.f + erff(x2 * 0.70710678118654752f));
        x3 = 0.5f * x3 * (1.f + erff(x3 * 0.70710678118654752f));
        ushort4 st;
        st.x = f2bu(x0); st.y = f2bu(x1); st.z = f2bu(x2); st.w = f2bu(x3);
        *(ushort4*)((u16*)out + oidx) = st;
      }
    }
  }
}

// ---------------- flash attention (fp32), 4 threads per query, defer-max online softmax ----------------
__global__ __launch_bounds__(256) void k_flash(
    const float* __restrict__ qkv, const float* __restrict__ pb,
    const float* __restrict__ am, const float* __restrict__ gate,
    u16* __restrict__ ctx)
{
  const int bh = blockIdx.y, b = bh >> 4, h = bh & 15;
  const int q0 = blockIdx.x * 64;
  const int tid = threadIdx.x;
  const int lq = tid >> 2, dp = tid & 3, dbase = dp * 16;
  const int sq = q0 + lq;

  __shared__ float kls[64][64];
  __shared__ float vls[64][64];
  __shared__ float pls[64][68];
  __shared__ float kpm[64];

  float qr[16];
  {
    const float* qp = qkv + ((size_t)b * SPn + sq) * 3072 + h * 64 + dbase;
#pragma unroll
    for (int i = 0; i < 16; i++) qr[i] = qp[i];
  }
  const float gr = gate[((size_t)b * Hn + h) * SPn + sq];
  float m = -__builtin_inff(), l = 0.f;
  float acc[16];
#pragma unroll
  for (int i = 0; i < 16; i++) acc[i] = 0.f;

  for (int kt = 0; kt < 24; kt++) {
    const int k0 = kt * 64;
    __syncthreads();
#pragma unroll
    for (int r = 0; r < 4; r++) {
      int idx = r * 256 + tid;
      int row = idx >> 4, cg = (idx & 15) * 4;
      const float* src = qkv + ((size_t)b * SPn + k0 + row) * 3072 + 1024 + h * 64 + cg;
      *(float4*)&kls[row][cg] = *(const float4*)src;
      *(float4*)&vls[row][cg] = *(const float4*)(src + 1024);
    }
#pragma unroll
    for (int r = 0; r < 4; r++) {
      int idx = r * 256 + tid;
      int row = idx >> 4, cg = (idx & 15) * 4;
      int sqr = q0 + row, skc = k0 + cg;
      float4 p4; p4.x = 0.f; p4.y = 0.f; p4.z = 0.f; p4.w = 0.f;
      if (sqr < Sn) {
        const float* ps = pb + ((size_t)bh * Sn + sqr) * Sn + skc;
        if (skc + 3 < Sn) p4 = *(const float4*)ps;
        else {
          if (skc + 0 < Sn) p4.x = ps[0];
          if (skc + 1 < Sn) p4.y = ps[1];
          if (skc + 2 < Sn) p4.z = ps[2];
          if (skc + 3 < Sn) p4.w = ps[3];
        }
      }
      *(float4*)&pls[row][cg] = p4;
    }
    if (tid < 64) {
      int sk = k0 + tid;
      kpm[tid] = (sk < Sn) ? (1.f - am[b * Sn + sk]) * -10000.f : -1e30f;
    }
    __syncthreads();
    for (int kk = 0; kk < 64; kk++) {
      float sp = 0.f;
#pragma unroll
      for (int i4 = 0; i4 < 4; i4++) {
        float4 kv = *(const float4*)&kls[kk][dbase + i4 * 4];
        sp += qr[i4 * 4 + 0] * kv.x + qr[i4 * 4 + 1] * kv.y +
              qr[i4 * 4 + 2] * kv.z + qr[i4 * 4 + 3] * kv.w;
      }
      sp += __shfl_xor(sp, 1);
      sp += __shfl_xor(sp, 2);
      float sc = sp * 0.125f + gr * pls[lq][kk] + kpm[kk];
      if (sc > m + 8.f) {           // defer-max rescale (T13)
        float corr = __expf(m - sc);
        m = sc;
        l *= corr;
#pragma unroll
        for (int i = 0; i < 16; i++) acc[i] *= corr;
      }
      float p = __expf(sc - m);
      l += p;
#pragma unroll
      for (int i4 = 0; i4 < 4; i4++) {
        float4 vv = *(const float4*)&vls[kk][dbase + i4 * 4];
        acc[i4 * 4 + 0] += p * vv.x; acc[i4 * 4 + 1] += p * vv.y;
        acc[i4 * 4 + 2] += p * vv.z; acc[i4 * 4 + 3] += p * vv.w;
      }
    }
  }
  float inv = 1.f / l;
  const bool qv = sq < Sn;
  union { u16 u[16]; int4 q[2]; } ob;
#pragma unroll
  for (int i = 0; i < 16; i++) ob.u[i] = f2bu(qv ? acc[i] * inv : 0.f);
  int4* dst = (int4*)(ctx + ((size_t)b * SPn + sq) * Cn + h * 64 + dbase);
  dst[0] = ob.q[0];
  dst[1] = ob.q[1];
}

// ---------------- fused residual + LayerNorm over C (contiguous in transposed layout) ----------------
__global__ __launch_bounds__(256) void k_ln(
    const float* __restrict__ r1, const float* __restrict__ r2,
    const float* __restrict__ g, const float* __restrict__ be,
    float* __restrict__ outF, u16* __restrict__ outB)
{
  const int s = blockIdx.x, b = blockIdx.y;
  const size_t base = ((size_t)b * SPn + s) * Cn;
  __shared__ float buf[Cn];
  __shared__ float red[8];
  const int tid = threadIdx.x;
  float sum = 0.f;
#pragma unroll
  for (int i = 0; i < 4; i++) {
    int c = tid + i * 256;
    float t = r1[base + c] + r2[base + c];
    buf[c] = t;
    sum += t;
  }
#pragma unroll
  for (int mk = 1; mk < 64; mk <<= 1) sum += __shfl_xor(sum, mk);
  if ((tid & 63) == 0) red[tid >> 6] = sum;
  __syncthreads();
  float mu = (red[0] + red[1] + red[2] + red[3]) * (1.f / Cn);
  float vs = 0.f;
#pragma unroll
  for (int i = 0; i < 4; i++) {
    int c = tid + i * 256;
    float d = buf[c] - mu;
    vs += d * d;
  }
#pragma unroll
  for (int mk = 1; mk < 64; mk <<= 1) vs += __shfl_xor(vs, mk);
  if ((tid & 63) == 0) red[4 + (tid >> 6)] = vs;
  __syncthreads();
  float var = (red[4] + red[5] + red[6] + red[7]) * (1.f / Cn);
  float rstd = rsqrtf(var + 1e-5f);
#pragma unroll
  for (int i = 0; i < 4; i++) {
    int c = tid + i * 256;
    float val = (buf[c] - mu) * rstd * g[c] + be[c];
    outF[base + c] = val;
    if (outB) outB[base + c] = f2bu(val);
  }
}

extern "C" void kernel_launch(void* const* d_in, const int* in_sizes, int n_in,
                              void* d_out, int out_size, void* d_ws, size_t ws_size,
                              hipStream_t stream)
{
  const float* x    = (const float*)d_in[0];
  const float* am   = (const float*)d_in[1];
  const float* pb   = (const float*)d_in[2];
  const float* Wq   = (const float*)d_in[3];
  const float* bq   = (const float*)d_in[4];
  const float* Wk   = (const float*)d_in[5];
  const float* bk   = (const float*)d_in[6];
  const float* Wv   = (const float*)d_in[7];
  const float* bv   = (const float*)d_in[8];
  const float* Wo   = (const float*)d_in[9];
  const float* bo   = (const float*)d_in[10];
  const float* Wg   = (const float*)d_in[11];
  const float* bg   = (const float*)d_in[12];
  const float* gc   = (const float*)d_in[13];
  const float* ln1g = (const float*)d_in[14];
  const float* ln1b = (const float*)d_in[15];
  const float* W1   = (const float*)d_in[16];
  const float* b1   = (const float*)d_in[17];
  const float* W2   = (const float*)d_in[18];
  const float* b2   = (const float*)d_in[19];
  const float* ln2g = (const float*)d_in[20];
  const float* ln2b = (const float*)d_in[21];

  // workspace arena (94,580,736 bytes total, lifetime-aliased)
  char* ws = (char*)d_ws;
  float* xT    = (float*)(ws + 0);            // 12,582,912  (live: ->LN1) ; outT later
  u16*   xTb   = (u16*)(ws + 12582912);       //  6,291,456  (->QKV gemm) ; ctxT later
  u16*   wqkvb = (u16*)(ws + 18874368);       //  6,291,456  (->QKV gemm) ; hT_b16 later
  u16*   wob   = (u16*)(ws + 25165824);       //  2,097,152
  u16*   w1b   = (u16*)(ws + 27262976);       //  8,388,608
  u16*   w2b   = (u16*)(ws + 35651584);       //  8,388,608
  float* bqkv  = (float*)(ws + 44040192);     //     12,288
  float* gate  = (float*)(ws + 44052480);     //    196,608
  float* qkvT  = (float*)(ws + 44249088);     // 37,748,736  (->flash) ; hT f32 + fT later
  u16*   fT    = (u16*)(ws + 44249088 + 12582912);
  float* attnT = (float*)(ws + 81997824);     // 12,582,912  (->LN1) ; f2T later

  u16*   ctxT = xTb;
  float* hT   = qkvT;
  u16*   hTb  = wqkvb;
  float* f2T  = attnT;
  float* outT = xT;

  dim3 blk(256);
  k_transpose_in<<<dim3(Cn / 32, SPn / 32, Bn), blk, 0, stream>>>(x, xT, xTb);
  k_cast_b<<<dim3(1024), blk, 0, stream>>>(Wq, wqkvb, 262144);
  k_cast_b<<<dim3(1024), blk, 0, stream>>>(Wk, wqkvb + 1048576, 262144);
  k_cast_b<<<dim3(1024), blk, 0, stream>>>(Wv, wqkvb + 2097152, 262144);
  k_cast_b<<<dim3(1024), blk, 0, stream>>>(Wo, wob, 262144);
  k_cast_b<<<dim3(4096), blk, 0, stream>>>(W1, w1b, 1048576);
  k_cast_b<<<dim3(4096), blk, 0, stream>>>(W2, w2b, 1048576);
  k_pack_bias<<<dim3(12), blk, 0, stream>>>(bq, bk, bv, bqkv);
  k_gate<<<dim3(SPn / 256, Hn, Bn), blk, 0, stream>>>(x, Wg, bg, gc, gate);

  // QKV projection: M=3072, K=1024
  k_gemm<0><<<dim3(24, 12, Bn), blk, 0, stream>>>(wqkvb, xTb, bqkv, qkvT, 3072, 1024);
  // attention (writes ctxT bf16; zero for padded rows)
  k_flash<<<dim3(24, Bn * Hn), blk, 0, stream>>>(qkvT, pb, am, gate, ctxT);
  // Wo: M=1024, K=1024
  k_gemm<0><<<dim3(8, 12, Bn), blk, 0, stream>>>(wob, ctxT, bo, attnT, 1024, 1024);
  // LN1 -> hT (f32) + hTb (bf16)
  k_ln<<<dim3(SPn, Bn), blk, 0, stream>>>(xT, attnT, ln1g, ln1b, hT, hTb);
  // FFN1 + gelu -> fT (bf16): M=4096, K=1024
  k_gemm<1><<<dim3(32, 12, Bn), blk, 0, stream>>>(w1b, hTb, b1, fT, 4096, 1024);
  // FFN2 -> f2T (f32): M=1024, K=4096
  k_gemm<0><<<dim3(8, 12, Bn), blk, 0, stream>>>(w2b, fT, b2, f2T, 1024, 4096);
  // LN2 -> outT
  k_ln<<<dim3(SPn, Bn), blk, 0, stream>>>(hT, f2T, ln2g, ln2b, outT, (u16*)nullptr);
  // back to (B,C,1,S)
  k_transpose_out<<<dim3(Cn / 32, SPn / 32, Bn), blk, 0, stream>>>(outT, (float*)d_out);
}

// Round 3
// 401.336 us; speedup vs baseline: 2.2394x; 2.2394x over previous
//
#include <hip/hip_runtime.h>
#include <cstddef>

#define Bn 2
#define Sn 1500
#define SPn 1536
#define Cn 1024
#define Hn 16
#define FFn 4096

typedef __attribute__((ext_vector_type(8))) short bf16x8;
typedef __attribute__((ext_vector_type(4))) float f32x4;
typedef unsigned short u16;
typedef unsigned int u32;

__device__ __forceinline__ u16 f2bu(float f) {
  unsigned u = __float_as_uint(f);
  return (u16)((u + 0x7fffu + ((u >> 16) & 1u)) >> 16);
}

// ---------------- transpose + cast input: x (B,C,S) -> xT (B,SP,C) f32 + bf16 ----------------
__global__ __launch_bounds__(256) void k_transpose_in(
    const float* __restrict__ x, float* __restrict__ xT, u16* __restrict__ xTb)
{
  __shared__ float t[32][33];
  const int b = blockIdx.z, c0 = blockIdx.x * 32, s0 = blockIdx.y * 32;
  const int tx = threadIdx.x & 31, ty = threadIdx.x >> 5;
#pragma unroll
  for (int i = 0; i < 32; i += 8) {
    int c = c0 + ty + i, s = s0 + tx;
    t[ty + i][tx] = (s < Sn) ? x[((size_t)b * Cn + c) * Sn + s] : 0.f;
  }
  __syncthreads();
#pragma unroll
  for (int i = 0; i < 32; i += 8) {
    int s = s0 + ty + i, c = c0 + tx;
    float v = t[tx][ty + i];
    size_t o = ((size_t)b * SPn + s) * Cn + c;
    xT[o] = v;
    xTb[o] = f2bu(v);
  }
}

// ---------------- transpose output: outT (B,SP,C) -> out (B,C,S) ----------------
__global__ __launch_bounds__(256) void k_transpose_out(
    const float* __restrict__ oT, float* __restrict__ o)
{
  __shared__ float t[32][33];
  const int b = blockIdx.z, c0 = blockIdx.x * 32, s0 = blockIdx.y * 32;
  const int tx = threadIdx.x & 31, ty = threadIdx.x >> 5;
#pragma unroll
  for (int i = 0; i < 32; i += 8) {
    int s = s0 + ty + i, c = c0 + tx;
    t[ty + i][tx] = oT[((size_t)b * SPn + s) * Cn + c];
  }
  __syncthreads();
#pragma unroll
  for (int i = 0; i < 32; i += 8) {
    int c = c0 + ty + i, s = s0 + tx;
    if (s < Sn) o[((size_t)b * Cn + c) * Sn + s] = t[tx][ty + i];
  }
}

// ---------------- V^T builder: qkvB (B,SP,3072 bf16) V-part -> vT (BH,64,SP bf16) ----------------
__global__ __launch_bounds__(256) void k_vtrans(
    const u16* __restrict__ qkv, u16* __restrict__ vT)
{
  __shared__ u16 t[32][34];
  const int bh = blockIdx.z, b = bh >> 4, h = bh & 15;
  const int s0 = blockIdx.x * 32, d0 = blockIdx.y * 32;
  const int tx = threadIdx.x & 31, ty = threadIdx.x >> 5;
#pragma unroll
  for (int i = 0; i < 32; i += 8) {
    int s = s0 + ty + i;
    t[ty + i][tx] = qkv[((size_t)b * SPn + s) * 3072 + 2048 + h * 64 + d0 + tx];
  }
  __syncthreads();
#pragma unroll
  for (int i = 0; i < 32; i += 8) {
    int d = d0 + ty + i;
    vT[((size_t)bh * 64 + d) * SPn + s0 + tx] = t[tx][ty + i];
  }
}

// ---------------- f32 -> bf16 cast ----------------
__global__ __launch_bounds__(256) void k_cast_b(
    const float* __restrict__ src, u16* __restrict__ dst, int n4)
{
  int i = blockIdx.x * 256 + threadIdx.x;
  if (i < n4) {
    float4 v = *(const float4*)(src + (size_t)i * 4);
    ushort4 o;
    o.x = f2bu(v.x); o.y = f2bu(v.y); o.z = f2bu(v.z); o.w = f2bu(v.w);
    *(ushort4*)(dst + (size_t)i * 4) = o;
  }
}

__global__ __launch_bounds__(256) void k_pack_bias(
    const float* __restrict__ q, const float* __restrict__ k,
    const float* __restrict__ v, float* __restrict__ o)
{
  int i = blockIdx.x * 256 + threadIdx.x;
  if (i < 3 * Cn) o[i] = (i < Cn) ? q[i] : ((i < 2 * Cn) ? k[i - Cn] : v[i - 2 * Cn]);
}

// ---------------- gate: gate[b,h,s] ----------------
__global__ __launch_bounds__(256) void k_gate(
    const float* __restrict__ x, const float* __restrict__ Wg,
    const float* __restrict__ bg, const float* __restrict__ gc,
    float* __restrict__ gate)
{
  const int b = blockIdx.z, h = blockIdx.y;
  const int s = blockIdx.x * 256 + threadIdx.x;
  const bool vld = s < Sn;
  const float* xp = x + ((size_t)b * Cn + h * 64) * Sn + (vld ? s : 0);
  float dot[8];
#pragma unroll
  for (int o = 0; o < 8; o++) dot[o] = 0.f;
  for (int d = 0; d < 64; d++) {
    float v = xp[(size_t)d * Sn];
#pragma unroll
    for (int o = 0; o < 8; o++) dot[o] += Wg[o * 64 + d] * v;
  }
  float sa = dot[0] + dot[1] + dot[2] + dot[3] + bg[0] + bg[1] + bg[2] + bg[3];
  float sb = dot[4] + dot[5] + dot[6] + dot[7] + bg[4] + bg[5] + bg[6] + bg[7];
  float ga = 1.f / (1.f + __expf(-sa));
  float gb = 1.f / (1.f + __expf(-sb));
  float gv = ga * (gb * gc[h] - 1.f) + 2.f;
  gate[((size_t)b * Hn + h) * SPn + s] = vld ? gv : 0.f;
}

// ---------------- bf16 MFMA GEMM ----------------
// EPI: 0 = f32 out, 1 = gelu -> bf16, 2 = bf16 out
template <int EPI>
__global__ __launch_bounds__(256) void k_gemm(
    const u16* __restrict__ A, const u16* __restrict__ X,
    const float* __restrict__ bias, void* __restrict__ out, int M, int K)
{
  const int b = blockIdx.z;
  const int m0 = blockIdx.x * 128;
  const int s0 = blockIdx.y * 128;
  const int tid = threadIdx.x;
  const int lane = tid & 63;
  const int wid = tid >> 6;
  const int wm = (wid >> 1) * 64;
  const int wn = (wid & 1) * 64;
  const int l15 = lane & 15;
  const int g4 = lane >> 4;

  __shared__ __align__(16) u16 lA[128][32];
  __shared__ __align__(16) u16 lX[128][32];

  f32x4 acc[4][4];
  f32x4 zr; zr[0] = 0.f; zr[1] = 0.f; zr[2] = 0.f; zr[3] = 0.f;
#pragma unroll
  for (int i = 0; i < 4; i++)
#pragma unroll
    for (int j = 0; j < 4; j++) acc[i][j] = zr;

  const size_t xbase = ((size_t)b * SPn + s0) * K;

  for (int kt = 0; kt < K; kt += 32) {
    __syncthreads();
#pragma unroll
    for (int r = 0; r < 2; r++) {
      int idx = r * 256 + tid;
      int row = idx >> 2;
      int c = idx & 3;
      int cs = c ^ (row & 3);
      int4 av = *(const int4*)(A + (size_t)(m0 + row) * K + kt + c * 8);
      *(int4*)&lA[row][cs * 8] = av;
      int4 xv = *(const int4*)(X + xbase + (size_t)row * K + kt + c * 8);
      *(int4*)&lX[row][cs * 8] = xv;
    }
    __syncthreads();
    bf16x8 af[4], bfr[4];
#pragma unroll
    for (int i = 0; i < 4; i++) {
      int ra = wm + i * 16 + l15;
      af[i] = *(const bf16x8*)&lA[ra][(g4 ^ (ra & 3)) * 8];
      int rb = wn + i * 16 + l15;
      bfr[i] = *(const bf16x8*)&lX[rb][(g4 ^ (rb & 3)) * 8];
    }
#pragma unroll
    for (int i = 0; i < 4; i++)
#pragma unroll
      for (int j = 0; j < 4; j++)
        acc[i][j] = __builtin_amdgcn_mfma_f32_16x16x32_bf16(af[i], bfr[j], acc[i][j], 0, 0, 0);
  }

#pragma unroll
  for (int i = 0; i < 4; i++) {
    int o = m0 + wm + i * 16 + g4 * 4;
    float4 bs = *(const float4*)(bias + o);
#pragma unroll
    for (int j = 0; j < 4; j++) {
      int s = s0 + wn + j * 16 + l15;
      size_t oidx = ((size_t)b * SPn + s) * M + o;
      f32x4 v = acc[i][j];
      float x0 = v[0] + bs.x, x1 = v[1] + bs.y, x2 = v[2] + bs.z, x3 = v[3] + bs.w;
      if (EPI == 0) {
        float4 st; st.x = x0; st.y = x1; st.z = x2; st.w = x3;
        *(float4*)((float*)out + oidx) = st;
      } else if (EPI == 1) {
        x0 = 0.5f * x0 * (1.f + erff(x0 * 0.70710678118654752f));
        x1 = 0.5f * x1 * (1.f + erff(x1 * 0.70710678118654752f));
        x2 = 0.5f * x2 * (1.f + erff(x2 * 0.70710678118654752f));
        x3 = 0.5f * x3 * (1.f + erff(x3 * 0.70710678118654752f));
        ushort4 st;
        st.x = f2bu(x0); st.y = f2bu(x1); st.z = f2bu(x2); st.w = f2bu(x3);
        *(ushort4*)((u16*)out + oidx) = st;
      } else {
        ushort4 st;
        st.x = f2bu(x0); st.y = f2bu(x1); st.z = f2bu(x2); st.w = f2bu(x3);
        *(ushort4*)((u16*)out + oidx) = st;
      }
    }
  }
}

// ---------------- MFMA flash attention ----------------
// 4 waves/block, 16 queries/wave (QBLK=64), KV tile 64.
// Swapped QK^T: mfma(K,Q) -> lane holds 16 scores of ONE query (q = lane&15).
// PV: mfma(V^T, P) -> ctx^T accumulated in regs.
__global__ __launch_bounds__(256) void k_flash_mfma(
    const u16* __restrict__ qkv,    // [B][SP][3072] bf16 (Q|K|V)
    const u16* __restrict__ vT,     // [BH][64][SP] bf16
    const float* __restrict__ pb,   // [BH][S][S] f32
    const float* __restrict__ am,   // [B][S]
    const float* __restrict__ gate, // [BH][SP]
    u16* __restrict__ ctx)          // [B][SP][C] bf16
{
  const int bh = blockIdx.y, b = bh >> 4, h = bh & 15;
  const int q0 = blockIdx.x * 64;
  const int tid = threadIdx.x;
  const int lane = tid & 63, wid = tid >> 6;
  const int l15 = lane & 15, g4 = lane >> 4;
  const int q = q0 + wid * 16 + l15;  // this lane's query

  __shared__ __align__(16) u16 kls[64][72];
  __shared__ __align__(16) u16 vls[64][72];
  __shared__ __align__(16) u16 pls[4][16][72];
  __shared__ float kpm[64];

  // Q fragment (B-operand): lane reads Q[q][h*64 + dc*32 + g4*8 + j]
  bf16x8 qf[2];
  {
    const u16* qp = qkv + ((size_t)b * SPn + q) * 3072 + h * 64 + g4 * 8;  // BUGFIX: + h*64
    qf[0] = *(const bf16x8*)qp;
    qf[1] = *(const bf16x8*)(qp + 32);
  }
  const float gr = gate[(size_t)bh * SPn + q];
  const int qpb = (q < Sn) ? q : (Sn - 1);
  const float* pbrow = pb + ((size_t)bh * Sn + qpb) * Sn;

  float m = -3.0e38f, l = 0.f;
  f32x4 accO[4];
  f32x4 zr; zr[0] = 0.f; zr[1] = 0.f; zr[2] = 0.f; zr[3] = 0.f;
#pragma unroll
  for (int i = 0; i < 4; i++) accO[i] = zr;

  for (int kt = 0; kt < 24; kt++) {
    const int k0 = kt * 64;
    __syncthreads();
    // stage K-tile [64 k][64 d] and V^T-tile [64 d][64 k]
#pragma unroll
    for (int i = 0; i < 2; i++) {
      int idx = i * 256 + tid;
      int row = idx >> 3, c8 = (idx & 7) * 8;
      *(int4*)&kls[row][c8] =
          *(const int4*)(qkv + ((size_t)b * SPn + k0 + row) * 3072 + 1024 + h * 64 + c8);  // BUGFIX: + h*64
      *(int4*)&vls[row][c8] =
          *(const int4*)(vT + ((size_t)bh * 64 + row) * SPn + k0 + c8);
    }
    if (tid < 64) {
      int sk = k0 + tid;
      kpm[tid] = (sk < Sn) ? (1.f - am[b * Sn + sk]) * -10000.f : -1e30f;
    }
    __syncthreads();

    // QK^T (swapped): D[k][q] — A = K rows, B = Q regs
    f32x4 sAcc[4];
#pragma unroll
    for (int km = 0; km < 4; km++) {
      sAcc[km] = zr;
#pragma unroll
      for (int dc = 0; dc < 2; dc++) {
        bf16x8 af = *(const bf16x8*)&kls[km * 16 + l15][dc * 32 + g4 * 8];
        sAcc[km] = __builtin_amdgcn_mfma_f32_16x16x32_bf16(af, qf[dc], sAcc[km], 0, 0, 0);
      }
    }

    // scores = qk*scale + gate*pos_bias + key_pad_mask
    float sc[16];
    const bool tail = (k0 + 63 >= Sn);
#pragma unroll
    for (int km = 0; km < 4; km++) {
      int kk = k0 + km * 16 + g4 * 4;
      float4 pbv;
      if (!tail) {
        pbv = *(const float4*)(pbrow + kk);
      } else {
        pbv.x = (kk + 0 < Sn) ? pbrow[kk + 0] : 0.f;
        pbv.y = (kk + 1 < Sn) ? pbrow[kk + 1] : 0.f;
        pbv.z = (kk + 2 < Sn) ? pbrow[kk + 2] : 0.f;
        pbv.w = (kk + 3 < Sn) ? pbrow[kk + 3] : 0.f;
      }
      float4 kp = *(const float4*)&kpm[km * 16 + g4 * 4];
      sc[km * 4 + 0] = sAcc[km][0] * 0.125f + gr * pbv.x + kp.x;
      sc[km * 4 + 1] = sAcc[km][1] * 0.125f + gr * pbv.y + kp.y;
      sc[km * 4 + 2] = sAcc[km][2] * 0.125f + gr * pbv.z + kp.z;
      sc[km * 4 + 3] = sAcc[km][3] * 0.125f + gr * pbv.w + kp.w;
    }

    // row max (16 local + lanes q, q+16, q+32, q+48)
    float mloc = sc[0];
#pragma unroll
    for (int i = 1; i < 16; i++) mloc = fmaxf(mloc, sc[i]);
    mloc = fmaxf(mloc, __shfl_xor(mloc, 16));
    mloc = fmaxf(mloc, __shfl_xor(mloc, 32));

    // defer-max online rescale (T13, THR=8)
    if (mloc > m + 8.f) {
      float corr = __expf(m - mloc);
      m = mloc;
      l *= corr;
#pragma unroll
      for (int i = 0; i < 4; i++) {
        accO[i][0] *= corr; accO[i][1] *= corr;
        accO[i][2] *= corr; accO[i][3] *= corr;
      }
    }

    float ls = 0.f;
#pragma unroll
    for (int i = 0; i < 16; i++) {
      float p = __expf(sc[i] - m);
      sc[i] = p;
      ls += p;
    }
    ls += __shfl_xor(ls, 16);
    ls += __shfl_xor(ls, 32);
    l += ls;

    // P -> bf16 -> wave-private LDS [q][k]
#pragma unroll
    for (int km = 0; km < 4; km++) {
      u32 lo = (u32)f2bu(sc[km * 4 + 0]) | ((u32)f2bu(sc[km * 4 + 1]) << 16);
      u32 hi = (u32)f2bu(sc[km * 4 + 2]) | ((u32)f2bu(sc[km * 4 + 3]) << 16);
      u32* dst = (u32*)&pls[wid][l15][km * 16 + g4 * 4];
      dst[0] = lo; dst[1] = hi;
    }

    // PV: D[d][q] — A = V^T rows, B = P rows
    bf16x8 pf[2];
    pf[0] = *(const bf16x8*)&pls[wid][l15][g4 * 8];
    pf[1] = *(const bf16x8*)&pls[wid][l15][32 + g4 * 8];
#pragma unroll
    for (int dm = 0; dm < 4; dm++) {
#pragma unroll
      for (int kc = 0; kc < 2; kc++) {
        bf16x8 af = *(const bf16x8*)&vls[dm * 16 + l15][kc * 32 + g4 * 8];
        accO[dm] = __builtin_amdgcn_mfma_f32_16x16x32_bf16(af, pf[kc], accO[dm], 0, 0, 0);
      }
    }
  }

  float inv = 1.f / l;
  const bool qv = q < Sn;
#pragma unroll
  for (int dm = 0; dm < 4; dm++) {
    ushort4 st;
    st.x = f2bu(qv ? accO[dm][0] * inv : 0.f);
    st.y = f2bu(qv ? accO[dm][1] * inv : 0.f);
    st.z = f2bu(qv ? accO[dm][2] * inv : 0.f);
    st.w = f2bu(qv ? accO[dm][3] * inv : 0.f);
    *(ushort4*)(ctx + ((size_t)b * SPn + q) * Cn + h * 64 + dm * 16 + g4 * 4) = st;
  }
}

// ---------------- fused residual + LayerNorm over C ----------------
__global__ __launch_bounds__(256) void k_ln(
    const float* __restrict__ r1, const float* __restrict__ r2,
    const float* __restrict__ g, const float* __restrict__ be,
    float* __restrict__ outF, u16* __restrict__ outB)
{
  const int s = blockIdx.x, b = blockIdx.y;
  const size_t base = ((size_t)b * SPn + s) * Cn;
  __shared__ float buf[Cn];
  __shared__ float red[8];
  const int tid = threadIdx.x;
  float sum = 0.f;
#pragma unroll
  for (int i = 0; i < 4; i++) {
    int c = tid + i * 256;
    float t = r1[base + c] + r2[base + c];
    buf[c] = t;
    sum += t;
  }
#pragma unroll
  for (int mk = 1; mk < 64; mk <<= 1) sum += __shfl_xor(sum, mk);
  if ((tid & 63) == 0) red[tid >> 6] = sum;
  __syncthreads();
  float mu = (red[0] + red[1] + red[2] + red[3]) * (1.f / Cn);
  float vs = 0.f;
#pragma unroll
  for (int i = 0; i < 4; i++) {
    int c = tid + i * 256;
    float d = buf[c] - mu;
    vs += d * d;
  }
#pragma unroll
  for (int mk = 1; mk < 64; mk <<= 1) vs += __shfl_xor(vs, mk);
  if ((tid & 63) == 0) red[4 + (tid >> 6)] = vs;
  __syncthreads();
  float var = (red[4] + red[5] + red[6] + red[7]) * (1.f / Cn);
  float rstd = rsqrtf(var + 1e-5f);
#pragma unroll
  for (int i = 0; i < 4; i++) {
    int c = tid + i * 256;
    float val = (buf[c] - mu) * rstd * g[c] + be[c];
    outF[base + c] = val;
    if (outB) outB[base + c] = f2bu(val);
  }
}

extern "C" void kernel_launch(void* const* d_in, const int* in_sizes, int n_in,
                              void* d_out, int out_size, void* d_ws, size_t ws_size,
                              hipStream_t stream)
{
  const float* x    = (const float*)d_in[0];
  const float* am   = (const float*)d_in[1];
  const float* pb   = (const float*)d_in[2];
  const float* Wq   = (const float*)d_in[3];
  const float* bq   = (const float*)d_in[4];
  const float* Wk   = (const float*)d_in[5];
  const float* bk   = (const float*)d_in[6];
  const float* Wv   = (const float*)d_in[7];
  const float* bv   = (const float*)d_in[8];
  const float* Wo   = (const float*)d_in[9];
  const float* bo   = (const float*)d_in[10];
  const float* Wg   = (const float*)d_in[11];
  const float* bg   = (const float*)d_in[12];
  const float* gc   = (const float*)d_in[13];
  const float* ln1g = (const float*)d_in[14];
  const float* ln1b = (const float*)d_in[15];
  const float* W1   = (const float*)d_in[16];
  const float* b1   = (const float*)d_in[17];
  const float* W2   = (const float*)d_in[18];
  const float* b2   = (const float*)d_in[19];
  const float* ln2g = (const float*)d_in[20];
  const float* ln2b = (const float*)d_in[21];

  // workspace arena (max 81,997,824 bytes used; lifetime-aliased)
  char* ws = (char*)d_ws;
  float* xT    = (float*)(ws + 0);             // [t_in .. LN1]
  u16*   xTb   = (u16*)(ws + 12582912);        // [t_in .. QKV]  -> ctxT
  u16*   wqkvb = (u16*)(ws + 18874368);        // [cast .. QKV]  -> hTb
  u16*   wob   = (u16*)(ws + 25165824);
  u16*   w1b   = (u16*)(ws + 27262976);
  u16*   w2b   = (u16*)(ws + 35651584);
  float* bqkv  = (float*)(ws + 44040192);
  float* gate  = (float*)(ws + 44052480);
  u16*   qkvB  = (u16*)(ws + 44249088);        // [QKV .. flash] -> hT
  u16*   vT    = (u16*)(ws + 63123456);        // [vtrans .. flash]
  float* attnT = (float*)(ws + 69414912);      // [Wo .. LN1]
  u16*   ctxT  = xTb;
  float* hT    = (float*)(ws + 44249088);
  u16*   hTb   = wqkvb;
  u16*   fT    = (u16*)(ws + 56832000);        // [FFN1 .. FFN2]
  float* f2T   = (float*)(ws + 0);             // [FFN2 .. LN2]
  float* outT  = (float*)(ws + 12582912);      // [LN2 .. t_out]

  dim3 blk(256);
  k_transpose_in<<<dim3(Cn / 32, SPn / 32, Bn), blk, 0, stream>>>(x, xT, xTb);
  k_cast_b<<<dim3(1024), blk, 0, stream>>>(Wq, wqkvb, 262144);
  k_cast_b<<<dim3(1024), blk, 0, stream>>>(Wk, wqkvb + 1048576, 262144);
  k_cast_b<<<dim3(1024), blk, 0, stream>>>(Wv, wqkvb + 2097152, 262144);
  k_cast_b<<<dim3(1024), blk, 0, stream>>>(Wo, wob, 262144);
  k_cast_b<<<dim3(4096), blk, 0, stream>>>(W1, w1b, 1048576);
  k_cast_b<<<dim3(4096), blk, 0, stream>>>(W2, w2b, 1048576);
  k_pack_bias<<<dim3(12), blk, 0, stream>>>(bq, bk, bv, bqkv);
  k_gate<<<dim3(SPn / 256, Hn, Bn), blk, 0, stream>>>(x, Wg, bg, gc, gate);

  // QKV projection -> bf16: M=3072, K=1024
  k_gemm<2><<<dim3(24, 12, Bn), blk, 0, stream>>>(wqkvb, xTb, bqkv, qkvB, 3072, 1024);
  // V^T for PV MFMA
  k_vtrans<<<dim3(SPn / 32, 2, Bn * Hn), blk, 0, stream>>>(qkvB, vT);
  // MFMA flash attention
  k_flash_mfma<<<dim3(SPn / 64, Bn * Hn), blk, 0, stream>>>(qkvB, vT, pb, am, gate, ctxT);
  // Wo: M=1024, K=1024
  k_gemm<0><<<dim3(8, 12, Bn), blk, 0, stream>>>(wob, ctxT, bo, attnT, 1024, 1024);
  // LN1 -> hT (f32) + hTb (bf16)
  k_ln<<<dim3(SPn, Bn), blk, 0, stream>>>(xT, attnT, ln1g, ln1b, hT, hTb);
  // FFN1 + gelu -> fT (bf16): M=4096, K=1024
  k_gemm<1><<<dim3(32, 12, Bn), blk, 0, stream>>>(w1b, hTb, b1, fT, 4096, 1024);
  // FFN2 -> f2T (f32): M=1024, K=4096
  k_gemm<0><<<dim3(8, 12, Bn), blk, 0, stream>>>(w2b, fT, b2, f2T, 1024, 4096);
  // LN2 -> outT
  k_ln<<<dim3(SPn, Bn), blk, 0, stream>>>(hT, f2T, ln2g, ln2b, outT, (u16*)nullptr);
  // back to (B,C,1,S)
  k_transpose_out<<<dim3(Cn / 32, SPn / 32, Bn), blk, 0, stream>>>(outT, (float*)d_out);
}

// Round 4
// 357.212 us; speedup vs baseline: 2.5160x; 1.1235x over previous
//
#include <hip/hip_runtime.h>
#include <cstddef>
#include <cstdint>

#define Bn 2
#define Sn 1500
#define SPn 1536
#define Cn 1024
#define Hn 16
#define FFn 4096

typedef __attribute__((ext_vector_type(8))) short bf16x8;
typedef __attribute__((ext_vector_type(4))) float f32x4;
typedef unsigned short u16;
typedef unsigned int u32;

__device__ __forceinline__ u16 f2bu(float f) {
  unsigned u = __float_as_uint(f);
  return (u16)((u + 0x7fffu + ((u >> 16) & 1u)) >> 16);
}

// async global->LDS, 16B per lane. LDS dest = wave-uniform base + lane*16.
__device__ __forceinline__ void gl_lds16(const u16* g, u16* l) {
  __builtin_amdgcn_global_load_lds(
      (__attribute__((address_space(1))) void*)(uintptr_t)g,
      (__attribute__((address_space(3))) void*)(u32)(uintptr_t)l,
      16, 0, 0);
}

// ---------------- transpose + cast input: x (B,C,S) -> xT (B,SP,C) f32 + bf16 ----------------
__global__ __launch_bounds__(256) void k_transpose_in(
    const float* __restrict__ x, float* __restrict__ xT, u16* __restrict__ xTb)
{
  __shared__ float t[32][33];
  const int b = blockIdx.z, c0 = blockIdx.x * 32, s0 = blockIdx.y * 32;
  const int tx = threadIdx.x & 31, ty = threadIdx.x >> 5;
#pragma unroll
  for (int i = 0; i < 32; i += 8) {
    int c = c0 + ty + i, s = s0 + tx;
    t[ty + i][tx] = (s < Sn) ? x[((size_t)b * Cn + c) * Sn + s] : 0.f;
  }
  __syncthreads();
#pragma unroll
  for (int i = 0; i < 32; i += 8) {
    int s = s0 + ty + i, c = c0 + tx;
    float v = t[tx][ty + i];
    size_t o = ((size_t)b * SPn + s) * Cn + c;
    xT[o] = v;
    xTb[o] = f2bu(v);
  }
}

// ---------------- transpose output: outT (B,SP,C) -> out (B,C,S) ----------------
__global__ __launch_bounds__(256) void k_transpose_out(
    const float* __restrict__ oT, float* __restrict__ o)
{
  __shared__ float t[32][33];
  const int b = blockIdx.z, c0 = blockIdx.x * 32, s0 = blockIdx.y * 32;
  const int tx = threadIdx.x & 31, ty = threadIdx.x >> 5;
#pragma unroll
  for (int i = 0; i < 32; i += 8) {
    int s = s0 + ty + i, c = c0 + tx;
    t[ty + i][tx] = oT[((size_t)b * SPn + s) * Cn + c];
  }
  __syncthreads();
#pragma unroll
  for (int i = 0; i < 32; i += 8) {
    int c = c0 + ty + i, s = s0 + tx;
    if (s < Sn) o[((size_t)b * Cn + c) * Sn + s] = t[tx][ty + i];
  }
}

// ---------------- V^T builder: qkvB V-part -> vT (BH,64,SP bf16) ----------------
__global__ __launch_bounds__(256) void k_vtrans(
    const u16* __restrict__ qkv, u16* __restrict__ vT)
{
  __shared__ u16 t[32][34];
  const int bh = blockIdx.z, b = bh >> 4, h = bh & 15;
  const int s0 = blockIdx.x * 32, d0 = blockIdx.y * 32;
  const int tx = threadIdx.x & 31, ty = threadIdx.x >> 5;
#pragma unroll
  for (int i = 0; i < 32; i += 8) {
    int s = s0 + ty + i;
    t[ty + i][tx] = qkv[((size_t)b * SPn + s) * 3072 + 2048 + h * 64 + d0 + tx];
  }
  __syncthreads();
#pragma unroll
  for (int i = 0; i < 32; i += 8) {
    int d = d0 + ty + i;
    vT[((size_t)bh * 64 + d) * SPn + s0 + tx] = t[tx][ty + i];
  }
}

// ---------------- f32 -> bf16 cast ----------------
__global__ __launch_bounds__(256) void k_cast_b(
    const float* __restrict__ src, u16* __restrict__ dst, int n4)
{
  int i = blockIdx.x * 256 + threadIdx.x;
  if (i < n4) {
    float4 v = *(const float4*)(src + (size_t)i * 4);
    ushort4 o;
    o.x = f2bu(v.x); o.y = f2bu(v.y); o.z = f2bu(v.z); o.w = f2bu(v.w);
    *(ushort4*)(dst + (size_t)i * 4) = o;
  }
}

__global__ __launch_bounds__(256) void k_pack_bias(
    const float* __restrict__ q, const float* __restrict__ k,
    const float* __restrict__ v, float* __restrict__ o)
{
  int i = blockIdx.x * 256 + threadIdx.x;
  if (i < 3 * Cn) o[i] = (i < Cn) ? q[i] : ((i < 2 * Cn) ? k[i - Cn] : v[i - 2 * Cn]);
}

// ---------------- gate: gate[b,h,s] ----------------
__global__ __launch_bounds__(256) void k_gate(
    const float* __restrict__ x, const float* __restrict__ Wg,
    const float* __restrict__ bg, const float* __restrict__ gc,
    float* __restrict__ gate)
{
  const int b = blockIdx.z, h = blockIdx.y;
  const int s = blockIdx.x * 256 + threadIdx.x;
  const bool vld = s < Sn;
  const float* xp = x + ((size_t)b * Cn + h * 64) * Sn + (vld ? s : 0);
  float dot[8];
#pragma unroll
  for (int o = 0; o < 8; o++) dot[o] = 0.f;
  for (int d = 0; d < 64; d++) {
    float v = xp[(size_t)d * Sn];
#pragma unroll
    for (int o = 0; o < 8; o++) dot[o] += Wg[o * 64 + d] * v;
  }
  float sa = dot[0] + dot[1] + dot[2] + dot[3] + bg[0] + bg[1] + bg[2] + bg[3];
  float sb = dot[4] + dot[5] + dot[6] + dot[7] + bg[4] + bg[5] + bg[6] + bg[7];
  float ga = 1.f / (1.f + __expf(-sa));
  float gb = 1.f / (1.f + __expf(-sb));
  float gv = ga * (gb * gc[h] - 1.f) + 2.f;
  gate[((size_t)b * Hn + h) * SPn + s] = vld ? gv : 0.f;
}

// ---------------- bf16 MFMA GEMM, global_load_lds staging ----------------
// EPI: 0 = f32 out, 1 = gelu -> bf16, 2 = bf16 out
// SPLIT: K split in one dispatch; half 0 -> out (+bias), half 1 -> out2 (no bias)
// LDS layout: linear dest; swizzle applied via global source col cg = cs ^ (row&3);
// read side col (g4 ^ (ra&3)) recovers global col g4.
template <int EPI, int SPLIT>
__global__ __launch_bounds__(256) void k_gemm(
    const u16* __restrict__ A, const u16* __restrict__ X,
    const float* __restrict__ bias, void* __restrict__ out, void* __restrict__ out2,
    int M, int Kst, int Ktot)
{
  const int zz = blockIdx.z;
  const int b = zz / SPLIT, half = zz % SPLIT;
  const int Kc = Ktot / SPLIT;
  const int m0 = blockIdx.x * 128;
  const int s0 = blockIdx.y * 128;
  const int tid = threadIdx.x;
  const int lane = tid & 63;
  const int wid = tid >> 6;
  const int wm = (wid >> 1) * 64;
  const int wn = (wid & 1) * 64;
  const int l15 = lane & 15;
  const int g4 = lane >> 4;

  __shared__ __align__(16) u16 lA[128][32];
  __shared__ __align__(16) u16 lX[128][32];

  f32x4 acc[4][4];
  f32x4 zr; zr[0] = 0.f; zr[1] = 0.f; zr[2] = 0.f; zr[3] = 0.f;
#pragma unroll
  for (int i = 0; i < 4; i++)
#pragma unroll
    for (int j = 0; j < 4; j++) acc[i][j] = zr;

  // staging addresses: wave wid covers rows [wid*32, wid*32+32), 2 insts per array
  const int rowA = wid * 32 + (lane >> 2);
  const int cg = (lane & 3) ^ ((lane >> 2) & 3);  // inverse-swizzled global col-block
  const int kbeg = half * Kc;
  const u16* gA = A + (size_t)(m0 + rowA) * Kst + cg * 8 + kbeg;
  const u16* gX = X + ((size_t)b * SPn + s0 + rowA) * Kst + cg * 8 + kbeg;
  u16* lAp = &lA[0][0] + wid * 1024;
  u16* lXp = &lX[0][0] + wid * 1024;
  const size_t rstep = (size_t)16 * Kst;

  for (int kt = 0; kt < Kc; kt += 32) {
    __syncthreads();
    gl_lds16(gA + kt, lAp);
    gl_lds16(gA + rstep + kt, lAp + 512);
    gl_lds16(gX + kt, lXp);
    gl_lds16(gX + rstep + kt, lXp + 512);
    __syncthreads();
    bf16x8 af[4], bfr[4];
#pragma unroll
    for (int i = 0; i < 4; i++) {
      int ra = wm + i * 16 + l15;
      af[i] = *(const bf16x8*)&lA[ra][(g4 ^ (ra & 3)) * 8];
      int rb = wn + i * 16 + l15;
      bfr[i] = *(const bf16x8*)&lX[rb][(g4 ^ (rb & 3)) * 8];
    }
#pragma unroll
    for (int i = 0; i < 4; i++)
#pragma unroll
      for (int j = 0; j < 4; j++)
        acc[i][j] = __builtin_amdgcn_mfma_f32_16x16x32_bf16(af[i], bfr[j], acc[i][j], 0, 0, 0);
  }

  const float hsc = (half == 0) ? 1.f : 0.f;
  void* outp = (half == 0) ? out : out2;
#pragma unroll
  for (int i = 0; i < 4; i++) {
    int o = m0 + wm + i * 16 + g4 * 4;
    float4 bs = *(const float4*)(bias + o);
#pragma unroll
    for (int j = 0; j < 4; j++) {
      int s = s0 + wn + j * 16 + l15;
      size_t oidx = ((size_t)b * SPn + s) * M + o;
      f32x4 v = acc[i][j];
      float x0 = v[0] + bs.x * hsc, x1 = v[1] + bs.y * hsc;
      float x2 = v[2] + bs.z * hsc, x3 = v[3] + bs.w * hsc;
      if (EPI == 0) {
        float4 st; st.x = x0; st.y = x1; st.z = x2; st.w = x3;
        *(float4*)((float*)outp + oidx) = st;
      } else if (EPI == 1) {
        x0 = 0.5f * x0 * (1.f + erff(x0 * 0.70710678118654752f));
        x1 = 0.5f * x1 * (1.f + erff(x1 * 0.70710678118654752f));
        x2 = 0.5f * x2 * (1.f + erff(x2 * 0.70710678118654752f));
        x3 = 0.5f * x3 * (1.f + erff(x3 * 0.70710678118654752f));
        ushort4 st;
        st.x = f2bu(x0); st.y = f2bu(x1); st.z = f2bu(x2); st.w = f2bu(x3);
        *(ushort4*)((u16*)outp + oidx) = st;
      } else {
        ushort4 st;
        st.x = f2bu(x0); st.y = f2bu(x1); st.z = f2bu(x2); st.w = f2bu(x3);
        *(ushort4*)((u16*)outp + oidx) = st;
      }
    }
  }
}

// ---------------- MFMA flash attention ----------------
__global__ __launch_bounds__(256) void k_flash_mfma(
    const u16* __restrict__ qkv,    // [B][SP][3072] bf16 (Q|K|V)
    const u16* __restrict__ vT,     // [BH][64][SP] bf16
    const float* __restrict__ pb,   // [BH][S][S] f32
    const float* __restrict__ am,   // [B][S]
    const float* __restrict__ gate, // [BH][SP]
    u16* __restrict__ ctx)          // [B][SP][C] bf16
{
  const int bh = blockIdx.y, b = bh >> 4, h = bh & 15;
  const int q0 = blockIdx.x * 64;
  const int tid = threadIdx.x;
  const int lane = tid & 63, wid = tid >> 6;
  const int l15 = lane & 15, g4 = lane >> 4;
  const int q = q0 + wid * 16 + l15;

  __shared__ __align__(16) u16 kls[64][72];
  __shared__ __align__(16) u16 vls[64][72];
  __shared__ __align__(16) u16 pls[4][16][72];
  __shared__ float kpm[64];

  bf16x8 qf[2];
  {
    const u16* qp = qkv + ((size_t)b * SPn + q) * 3072 + h * 64 + g4 * 8;
    qf[0] = *(const bf16x8*)qp;
    qf[1] = *(const bf16x8*)(qp + 32);
  }
  const float gr = gate[(size_t)bh * SPn + q];
  const int qpb = (q < Sn) ? q : (Sn - 1);
  const float* pbrow = pb + ((size_t)bh * Sn + qpb) * Sn;

  float m = -3.0e38f, l = 0.f;
  f32x4 accO[4];
  f32x4 zr; zr[0] = 0.f; zr[1] = 0.f; zr[2] = 0.f; zr[3] = 0.f;
#pragma unroll
  for (int i = 0; i < 4; i++) accO[i] = zr;

  for (int kt = 0; kt < 24; kt++) {
    const int k0 = kt * 64;
    __syncthreads();
#pragma unroll
    for (int i = 0; i < 2; i++) {
      int idx = i * 256 + tid;
      int row = idx >> 3, c8 = (idx & 7) * 8;
      *(int4*)&kls[row][c8] =
          *(const int4*)(qkv + ((size_t)b * SPn + k0 + row) * 3072 + 1024 + h * 64 + c8);
      *(int4*)&vls[row][c8] =
          *(const int4*)(vT + ((size_t)bh * 64 + row) * SPn + k0 + c8);
    }
    if (tid < 64) {
      int sk = k0 + tid;
      kpm[tid] = (sk < Sn) ? (1.f - am[b * Sn + sk]) * -10000.f : -1e30f;
    }
    __syncthreads();

    f32x4 sAcc[4];
#pragma unroll
    for (int km = 0; km < 4; km++) {
      sAcc[km] = zr;
#pragma unroll
      for (int dc = 0; dc < 2; dc++) {
        bf16x8 af = *(const bf16x8*)&kls[km * 16 + l15][dc * 32 + g4 * 8];
        sAcc[km] = __builtin_amdgcn_mfma_f32_16x16x32_bf16(af, qf[dc], sAcc[km], 0, 0, 0);
      }
    }

    float sc[16];
    const bool tail = (k0 + 63 >= Sn);
#pragma unroll
    for (int km = 0; km < 4; km++) {
      int kk = k0 + km * 16 + g4 * 4;
      float4 pbv;
      if (!tail) {
        pbv = *(const float4*)(pbrow + kk);
      } else {
        pbv.x = (kk + 0 < Sn) ? pbrow[kk + 0] : 0.f;
        pbv.y = (kk + 1 < Sn) ? pbrow[kk + 1] : 0.f;
        pbv.z = (kk + 2 < Sn) ? pbrow[kk + 2] : 0.f;
        pbv.w = (kk + 3 < Sn) ? pbrow[kk + 3] : 0.f;
      }
      float4 kp = *(const float4*)&kpm[km * 16 + g4 * 4];
      sc[km * 4 + 0] = sAcc[km][0] * 0.125f + gr * pbv.x + kp.x;
      sc[km * 4 + 1] = sAcc[km][1] * 0.125f + gr * pbv.y + kp.y;
      sc[km * 4 + 2] = sAcc[km][2] * 0.125f + gr * pbv.z + kp.z;
      sc[km * 4 + 3] = sAcc[km][3] * 0.125f + gr * pbv.w + kp.w;
    }

    float mloc = sc[0];
#pragma unroll
    for (int i = 1; i < 16; i++) mloc = fmaxf(mloc, sc[i]);
    mloc = fmaxf(mloc, __shfl_xor(mloc, 16));
    mloc = fmaxf(mloc, __shfl_xor(mloc, 32));

    if (mloc > m + 8.f) {
      float corr = __expf(m - mloc);
      m = mloc;
      l *= corr;
#pragma unroll
      for (int i = 0; i < 4; i++) {
        accO[i][0] *= corr; accO[i][1] *= corr;
        accO[i][2] *= corr; accO[i][3] *= corr;
      }
    }

    float ls = 0.f;
#pragma unroll
    for (int i = 0; i < 16; i++) {
      float p = __expf(sc[i] - m);
      sc[i] = p;
      ls += p;
    }
    ls += __shfl_xor(ls, 16);
    ls += __shfl_xor(ls, 32);
    l += ls;

#pragma unroll
    for (int km = 0; km < 4; km++) {
      u32 lo = (u32)f2bu(sc[km * 4 + 0]) | ((u32)f2bu(sc[km * 4 + 1]) << 16);
      u32 hi = (u32)f2bu(sc[km * 4 + 2]) | ((u32)f2bu(sc[km * 4 + 3]) << 16);
      u32* dst = (u32*)&pls[wid][l15][km * 16 + g4 * 4];
      dst[0] = lo; dst[1] = hi;
    }

    bf16x8 pf[2];
    pf[0] = *(const bf16x8*)&pls[wid][l15][g4 * 8];
    pf[1] = *(const bf16x8*)&pls[wid][l15][32 + g4 * 8];
#pragma unroll
    for (int dm = 0; dm < 4; dm++) {
#pragma unroll
      for (int kc = 0; kc < 2; kc++) {
        bf16x8 af = *(const bf16x8*)&vls[dm * 16 + l15][kc * 32 + g4 * 8];
        accO[dm] = __builtin_amdgcn_mfma_f32_16x16x32_bf16(af, pf[kc], accO[dm], 0, 0, 0);
      }
    }
  }

  float inv = 1.f / l;
  const bool qv = q < Sn;
#pragma unroll
  for (int dm = 0; dm < 4; dm++) {
    ushort4 st;
    st.x = f2bu(qv ? accO[dm][0] * inv : 0.f);
    st.y = f2bu(qv ? accO[dm][1] * inv : 0.f);
    st.z = f2bu(qv ? accO[dm][2] * inv : 0.f);
    st.w = f2bu(qv ? accO[dm][3] * inv : 0.f);
    *(ushort4*)(ctx + ((size_t)b * SPn + q) * Cn + h * 64 + dm * 16 + g4 * 4) = st;
  }
}

// ---------------- fused 3-way residual + LayerNorm over C ----------------
__global__ __launch_bounds__(256) void k_ln3(
    const float* __restrict__ r1, const float* __restrict__ r2,
    const float* __restrict__ r3,
    const float* __restrict__ g, const float* __restrict__ be,
    float* __restrict__ outF, u16* __restrict__ outB)
{
  const int s = blockIdx.x, b = blockIdx.y;
  const size_t base = ((size_t)b * SPn + s) * Cn;
  __shared__ float buf[Cn];
  __shared__ float red[8];
  const int tid = threadIdx.x;
  float sum = 0.f;
#pragma unroll
  for (int i = 0; i < 4; i++) {
    int c = tid + i * 256;
    float t = r1[base + c] + r2[base + c] + r3[base + c];
    buf[c] = t;
    sum += t;
  }
#pragma unroll
  for (int mk = 1; mk < 64; mk <<= 1) sum += __shfl_xor(sum, mk);
  if ((tid & 63) == 0) red[tid >> 6] = sum;
  __syncthreads();
  float mu = (red[0] + red[1] + red[2] + red[3]) * (1.f / Cn);
  float vs = 0.f;
#pragma unroll
  for (int i = 0; i < 4; i++) {
    int c = tid + i * 256;
    float d = buf[c] - mu;
    vs += d * d;
  }
#pragma unroll
  for (int mk = 1; mk < 64; mk <<= 1) vs += __shfl_xor(vs, mk);
  if ((tid & 63) == 0) red[4 + (tid >> 6)] = vs;
  __syncthreads();
  float var = (red[4] + red[5] + red[6] + red[7]) * (1.f / Cn);
  float rstd = rsqrtf(var + 1e-5f);
#pragma unroll
  for (int i = 0; i < 4; i++) {
    int c = tid + i * 256;
    float val = (buf[c] - mu) * rstd * g[c] + be[c];
    outF[base + c] = val;
    if (outB) outB[base + c] = f2bu(val);
  }
}

extern "C" void kernel_launch(void* const* d_in, const int* in_sizes, int n_in,
                              void* d_out, int out_size, void* d_ws, size_t ws_size,
                              hipStream_t stream)
{
  const float* x    = (const float*)d_in[0];
  const float* am   = (const float*)d_in[1];
  const float* pb   = (const float*)d_in[2];
  const float* Wq   = (const float*)d_in[3];
  const float* bq   = (const float*)d_in[4];
  const float* Wk   = (const float*)d_in[5];
  const float* bk   = (const float*)d_in[6];
  const float* Wv   = (const float*)d_in[7];
  const float* bv   = (const float*)d_in[8];
  const float* Wo   = (const float*)d_in[9];
  const float* bo   = (const float*)d_in[10];
  const float* Wg   = (const float*)d_in[11];
  const float* bg   = (const float*)d_in[12];
  const float* gc   = (const float*)d_in[13];
  const float* ln1g = (const float*)d_in[14];
  const float* ln1b = (const float*)d_in[15];
  const float* W1   = (const float*)d_in[16];
  const float* b1   = (const float*)d_in[17];
  const float* W2   = (const float*)d_in[18];
  const float* b2   = (const float*)d_in[19];
  const float* ln2g = (const float*)d_in[20];
  const float* ln2b = (const float*)d_in[21];

  // workspace arena (94,580,736 bytes; lifetime-aliased)
  char* ws = (char*)d_ws;
  float* xT     = (float*)(ws + 0);            // [t_in .. LN1]
  u16*   xTb    = (u16*)(ws + 12582912);       // [t_in .. QKV] -> ctxT [flash..Wo]
  u16*   wqkvb  = (u16*)(ws + 18874368);       // [cast .. QKV] -> hTb [LN1..FFN1]
  u16*   wob    = (u16*)(ws + 25165824);
  u16*   w1b    = (u16*)(ws + 27262976);
  u16*   w2b    = (u16*)(ws + 35651584);
  float* bqkv   = (float*)(ws + 44040192);
  float* gate   = (float*)(ws + 44052480);
  u16*   qkvB   = (u16*)(ws + 44249088);       // [QKV .. flash]; then hT f32 [LN1..LN2]
  u16*   vT     = (u16*)(ws + 63123456);       // [vtrans .. flash]
  float* attnTa = (float*)(ws + 69414912);     // [Wo .. LN1]
  float* attnTb = (float*)(ws + 81997824);     // [Wo .. LN1]
  u16*   ctxT   = xTb;
  float* hT     = (float*)(ws + 44249088);
  u16*   hTb    = wqkvb;
  u16*   fT     = (u16*)(ws + 56832000);       // [FFN1 .. FFN2] (25,165,824 B, over vT+attnTa)
  float* f2Ta   = (float*)(ws + 0);            // [FFN2 .. LN2] (over xT)
  float* f2Tb   = (float*)(ws + 81997824);     // [FFN2 .. LN2] (over attnTb)
  float* outT   = (float*)(ws + 12582912);     // [LN2 .. t_out] (over ctxT)

  dim3 blk(256);
  k_transpose_in<<<dim3(Cn / 32, SPn / 32, Bn), blk, 0, stream>>>(x, xT, xTb);
  k_cast_b<<<dim3(1024), blk, 0, stream>>>(Wq, wqkvb, 262144);
  k_cast_b<<<dim3(1024), blk, 0, stream>>>(Wk, wqkvb + 1048576, 262144);
  k_cast_b<<<dim3(1024), blk, 0, stream>>>(Wv, wqkvb + 2097152, 262144);
  k_cast_b<<<dim3(1024), blk, 0, stream>>>(Wo, wob, 262144);
  k_cast_b<<<dim3(4096), blk, 0, stream>>>(W1, w1b, 1048576);
  k_cast_b<<<dim3(4096), blk, 0, stream>>>(W2, w2b, 1048576);
  k_pack_bias<<<dim3(12), blk, 0, stream>>>(bq, bk, bv, bqkv);
  k_gate<<<dim3(SPn / 256, Hn, Bn), blk, 0, stream>>>(x, Wg, bg, gc, gate);

  // QKV projection -> bf16: M=3072, K=1024
  k_gemm<2, 1><<<dim3(24, 12, Bn), blk, 0, stream>>>(
      wqkvb, xTb, bqkv, qkvB, qkvB, 3072, 1024, 1024);
  // V^T for PV MFMA
  k_vtrans<<<dim3(SPn / 32, 2, Bn * Hn), blk, 0, stream>>>(qkvB, vT);
  // MFMA flash attention
  k_flash_mfma<<<dim3(SPn / 64, Bn * Hn), blk, 0, stream>>>(qkvB, vT, pb, am, gate, ctxT);
  // Wo: M=1024, K=1024, split-K=2 (occupancy: 192 -> 384 blocks)
  k_gemm<0, 2><<<dim3(8, 12, Bn * 2), blk, 0, stream>>>(
      wob, ctxT, bo, attnTa, attnTb, 1024, 1024, 1024);
  // LN1 = LN(x + attnA + attnB) -> hT (f32) + hTb (bf16)
  k_ln3<<<dim3(SPn, Bn), blk, 0, stream>>>(xT, attnTa, attnTb, ln1g, ln1b, hT, hTb);
  // FFN1 + gelu -> fT (bf16): M=4096, K=1024
  k_gemm<1, 1><<<dim3(32, 12, Bn), blk, 0, stream>>>(
      w1b, hTb, b1, fT, fT, 4096, 1024, 1024);
  // FFN2: M=1024, K=4096, split-K=2
  k_gemm<0, 2><<<dim3(8, 12, Bn * 2), blk, 0, stream>>>(
      w2b, fT, b2, f2Ta, f2Tb, 1024, 4096, 4096);
  // LN2 = LN(h + f2a + f2b) -> outT
  k_ln3<<<dim3(SPn, Bn), blk, 0, stream>>>(hT, f2Ta, f2Tb, ln2g, ln2b, outT, (u16*)nullptr);
  // back to (B,C,1,S)
  k_transpose_out<<<dim3(Cn / 32, SPn / 32, Bn), blk, 0, stream>>>(outT, (float*)d_out);
}

// Round 5
// 336.613 us; speedup vs baseline: 2.6700x; 1.0612x over previous
//
#include <hip/hip_runtime.h>
#include <cstddef>
#include <cstdint>

#define Bn 2
#define Sn 1500
#define SPn 1536
#define Cn 1024
#define Hn 16
#define FFn 4096

typedef __attribute__((ext_vector_type(8))) short bf16x8;
typedef __attribute__((ext_vector_type(4))) float f32x4;
typedef unsigned short u16;
typedef unsigned int u32;

__device__ __forceinline__ u16 f2bu(float f) {
  unsigned u = __float_as_uint(f);
  return (u16)((u + 0x7fffu + ((u >> 16) & 1u)) >> 16);
}

// async global->LDS, 16B per lane. LDS dest = wave-uniform base + lane*16.
__device__ __forceinline__ void gl_lds16(const u16* g, u16* l) {
  __builtin_amdgcn_global_load_lds(
      (__attribute__((address_space(1))) void*)(uintptr_t)g,
      (__attribute__((address_space(3))) void*)(u32)(uintptr_t)l,
      16, 0, 0);
}

// ---------------- transpose + cast input: x (B,C,S) -> xT (B,SP,C) f32 + bf16 ----------------
__global__ __launch_bounds__(256) void k_transpose_in(
    const float* __restrict__ x, float* __restrict__ xT, u16* __restrict__ xTb)
{
  __shared__ float t[32][33];
  const int b = blockIdx.z, c0 = blockIdx.x * 32, s0 = blockIdx.y * 32;
  const int tx = threadIdx.x & 31, ty = threadIdx.x >> 5;
#pragma unroll
  for (int i = 0; i < 32; i += 8) {
    int c = c0 + ty + i, s = s0 + tx;
    t[ty + i][tx] = (s < Sn) ? x[((size_t)b * Cn + c) * Sn + s] : 0.f;
  }
  __syncthreads();
#pragma unroll
  for (int i = 0; i < 32; i += 8) {
    int s = s0 + ty + i, c = c0 + tx;
    float v = t[tx][ty + i];
    size_t o = ((size_t)b * SPn + s) * Cn + c;
    xT[o] = v;
    xTb[o] = f2bu(v);
  }
}

// ---------------- transpose output: outT (B,SP,C) -> out (B,C,S) ----------------
__global__ __launch_bounds__(256) void k_transpose_out(
    const float* __restrict__ oT, float* __restrict__ o)
{
  __shared__ float t[32][33];
  const int b = blockIdx.z, c0 = blockIdx.x * 32, s0 = blockIdx.y * 32;
  const int tx = threadIdx.x & 31, ty = threadIdx.x >> 5;
#pragma unroll
  for (int i = 0; i < 32; i += 8) {
    int s = s0 + ty + i, c = c0 + tx;
    t[ty + i][tx] = oT[((size_t)b * SPn + s) * Cn + c];
  }
  __syncthreads();
#pragma unroll
  for (int i = 0; i < 32; i += 8) {
    int c = c0 + ty + i, s = s0 + tx;
    if (s < Sn) o[((size_t)b * Cn + c) * Sn + s] = t[tx][ty + i];
  }
}

// ---------------- V^T builder: qkvB V-part -> vT (BH,64,SP bf16) ----------------
__global__ __launch_bounds__(256) void k_vtrans(
    const u16* __restrict__ qkv, u16* __restrict__ vT)
{
  __shared__ u16 t[32][34];
  const int bh = blockIdx.z, b = bh >> 4, h = bh & 15;
  const int s0 = blockIdx.x * 32, d0 = blockIdx.y * 32;
  const int tx = threadIdx.x & 31, ty = threadIdx.x >> 5;
#pragma unroll
  for (int i = 0; i < 32; i += 8) {
    int s = s0 + ty + i;
    t[ty + i][tx] = qkv[((size_t)b * SPn + s) * 3072 + 2048 + h * 64 + d0 + tx];
  }
  __syncthreads();
#pragma unroll
  for (int i = 0; i < 32; i += 8) {
    int d = d0 + ty + i;
    vT[((size_t)bh * 64 + d) * SPn + s0 + tx] = t[tx][ty + i];
  }
}

// ---------------- fused weight casts + bias pack (one launch) ----------------
// float4-group index space:
// [0,786432)        Wq|Wk|Wv -> wqkvb
// [786432,1048576)  Wo -> wob
// [1048576,2097152) W1 -> w1b
// [2097152,3145728) W2 -> w2b
// [3145728,3146496) bq|bk|bv -> bqkv (f32 copy)
__global__ __launch_bounds__(256) void k_prep(
    const float* __restrict__ Wq, const float* __restrict__ Wk,
    const float* __restrict__ Wv, const float* __restrict__ Wo,
    const float* __restrict__ W1, const float* __restrict__ W2,
    const float* __restrict__ bq, const float* __restrict__ bk,
    const float* __restrict__ bv,
    u16* __restrict__ wqkvb, u16* __restrict__ wob,
    u16* __restrict__ w1b, u16* __restrict__ w2b, float* __restrict__ bqkv)
{
  int i = blockIdx.x * 256 + threadIdx.x;
  const float* src;
  u16* dst;
  int j;
  if (i < 786432) {
    src = (i < 262144) ? Wq : ((i < 524288) ? Wk : Wv);
    j = i & 262143;
    dst = wqkvb + (size_t)i * 4;
  } else if (i < 1048576) {
    src = Wo; j = i - 786432; dst = wob + (size_t)j * 4;
  } else if (i < 2097152) {
    src = W1; j = i - 1048576; dst = w1b + (size_t)j * 4;
  } else if (i < 3145728) {
    src = W2; j = i - 2097152; dst = w2b + (size_t)j * 4;
  } else {
    int k = i - 3145728;  // 0..767
    const float* bsrc = (k < 256) ? bq : ((k < 512) ? bk : bv);
    float4 v = *(const float4*)(bsrc + (k & 255) * 4);
    *(float4*)(bqkv + k * 4) = v;
    return;
  }
  float4 v = *(const float4*)(src + (size_t)j * 4);
  ushort4 o;
  o.x = f2bu(v.x); o.y = f2bu(v.y); o.z = f2bu(v.z); o.w = f2bu(v.w);
  *(ushort4*)dst = o;
}

// ---------------- gate: gate[b,h,s] ----------------
__global__ __launch_bounds__(256) void k_gate(
    const float* __restrict__ x, const float* __restrict__ Wg,
    const float* __restrict__ bg, const float* __restrict__ gc,
    float* __restrict__ gate)
{
  const int b = blockIdx.z, h = blockIdx.y;
  const int s = blockIdx.x * 256 + threadIdx.x;
  const bool vld = s < Sn;
  const float* xp = x + ((size_t)b * Cn + h * 64) * Sn + (vld ? s : 0);
  float dot[8];
#pragma unroll
  for (int o = 0; o < 8; o++) dot[o] = 0.f;
  for (int d = 0; d < 64; d++) {
    float v = xp[(size_t)d * Sn];
#pragma unroll
    for (int o = 0; o < 8; o++) dot[o] += Wg[o * 64 + d] * v;
  }
  float sa = dot[0] + dot[1] + dot[2] + dot[3] + bg[0] + bg[1] + bg[2] + bg[3];
  float sb = dot[4] + dot[5] + dot[6] + dot[7] + bg[4] + bg[5] + bg[6] + bg[7];
  float ga = 1.f / (1.f + __expf(-sa));
  float gb = 1.f / (1.f + __expf(-sb));
  float gv = ga * (gb * gc[h] - 1.f) + 2.f;
  gate[((size_t)b * Hn + h) * SPn + s] = vld ? gv : 0.f;
}

// ---------------- bf16 MFMA GEMM, BK=64, global_load_lds staging ----------------
// EPI: 0 = f32 out, 1 = gelu -> bf16, 2 = bf16 out
// SPLIT: K split in one dispatch; half 0 -> out (+bias), half 1 -> out2 (no bias)
// LDS [128][64] linear; swizzle via global source col cg=(lane&7)^(lane>>3);
// read col ((ks*4+g4) ^ (row&7)) recovers global col ks*4+g4 (2-way bank = free).
template <int EPI, int SPLIT>
__global__ __launch_bounds__(256) void k_gemm(
    const u16* __restrict__ A, const u16* __restrict__ X,
    const float* __restrict__ bias, void* __restrict__ out, void* __restrict__ out2,
    int M, int Kst, int Ktot)
{
  const int zz = blockIdx.z;
  const int b = zz / SPLIT, half = zz % SPLIT;
  const int Kc = Ktot / SPLIT;
  const int m0 = blockIdx.x * 128;
  const int s0 = blockIdx.y * 128;
  const int tid = threadIdx.x;
  const int lane = tid & 63;
  const int wid = tid >> 6;
  const int wm = (wid >> 1) * 64;
  const int wn = (wid & 1) * 64;
  const int l15 = lane & 15;
  const int g4 = lane >> 4;

  __shared__ __align__(16) u16 lA[128][64];
  __shared__ __align__(16) u16 lX[128][64];

  f32x4 acc[4][4];
  f32x4 zr; zr[0] = 0.f; zr[1] = 0.f; zr[2] = 0.f; zr[3] = 0.f;
#pragma unroll
  for (int i = 0; i < 4; i++)
#pragma unroll
    for (int j = 0; j < 4; j++) acc[i][j] = zr;

  // staging: wave wid covers rows [wid*32, +32), 4 insts of 8 rows per array
  const int rlo = lane >> 3;               // row within 8-row group
  const int cg = (lane & 7) ^ rlo;         // inverse-swizzled global col-block
  const int kbeg = half * Kc;
  const u16* gA = A + (size_t)(m0 + wid * 32 + rlo) * Kst + cg * 8 + kbeg;
  const u16* gX = X + ((size_t)b * SPn + s0 + wid * 32 + rlo) * Kst + cg * 8 + kbeg;
  u16* lAp = &lA[0][0] + wid * 2048;
  u16* lXp = &lX[0][0] + wid * 2048;
  const size_t rstep8 = (size_t)8 * Kst;

  for (int kt = 0; kt < Kc; kt += 64) {
    __syncthreads();
#pragma unroll
    for (int j = 0; j < 4; j++) {
      gl_lds16(gA + j * rstep8 + kt, lAp + j * 512);
      gl_lds16(gX + j * rstep8 + kt, lXp + j * 512);
    }
    __syncthreads();
#pragma unroll
    for (int ks = 0; ks < 2; ks++) {
      bf16x8 af[4], bfr[4];
#pragma unroll
      for (int i = 0; i < 4; i++) {
        int ra = wm + i * 16 + l15;
        af[i] = *(const bf16x8*)&lA[ra][((ks * 4 + g4) ^ (ra & 7)) * 8];
        int rb = wn + i * 16 + l15;
        bfr[i] = *(const bf16x8*)&lX[rb][((ks * 4 + g4) ^ (rb & 7)) * 8];
      }
#pragma unroll
      for (int i = 0; i < 4; i++)
#pragma unroll
        for (int j = 0; j < 4; j++)
          acc[i][j] = __builtin_amdgcn_mfma_f32_16x16x32_bf16(af[i], bfr[j], acc[i][j], 0, 0, 0);
    }
  }

  const float hsc = (half == 0) ? 1.f : 0.f;
  void* outp = (half == 0) ? out : out2;
#pragma unroll
  for (int i = 0; i < 4; i++) {
    int o = m0 + wm + i * 16 + g4 * 4;
    float4 bs = *(const float4*)(bias + o);
#pragma unroll
    for (int j = 0; j < 4; j++) {
      int s = s0 + wn + j * 16 + l15;
      size_t oidx = ((size_t)b * SPn + s) * M + o;
      f32x4 v = acc[i][j];
      float x0 = v[0] + bs.x * hsc, x1 = v[1] + bs.y * hsc;
      float x2 = v[2] + bs.z * hsc, x3 = v[3] + bs.w * hsc;
      if (EPI == 0) {
        float4 st; st.x = x0; st.y = x1; st.z = x2; st.w = x3;
        *(float4*)((float*)outp + oidx) = st;
      } else if (EPI == 1) {
        x0 = 0.5f * x0 * (1.f + erff(x0 * 0.70710678118654752f));
        x1 = 0.5f * x1 * (1.f + erff(x1 * 0.70710678118654752f));
        x2 = 0.5f * x2 * (1.f + erff(x2 * 0.70710678118654752f));
        x3 = 0.5f * x3 * (1.f + erff(x3 * 0.70710678118654752f));
        ushort4 st;
        st.x = f2bu(x0); st.y = f2bu(x1); st.z = f2bu(x2); st.w = f2bu(x3);
        *(ushort4*)((u16*)outp + oidx) = st;
      } else {
        ushort4 st;
        st.x = f2bu(x0); st.y = f2bu(x1); st.z = f2bu(x2); st.w = f2bu(x3);
        *(ushort4*)((u16*)outp + oidx) = st;
      }
    }
  }
}

// ---------------- MFMA flash attention ----------------
__global__ __launch_bounds__(256) void k_flash_mfma(
    const u16* __restrict__ qkv,    // [B][SP][3072] bf16 (Q|K|V)
    const u16* __restrict__ vT,     // [BH][64][SP] bf16
    const float* __restrict__ pb,   // [BH][S][S] f32
    const float* __restrict__ am,   // [B][S]
    const float* __restrict__ gate, // [BH][SP]
    u16* __restrict__ ctx)          // [B][SP][C] bf16
{
  const int bh = blockIdx.y, b = bh >> 4, h = bh & 15;
  const int q0 = blockIdx.x * 64;
  const int tid = threadIdx.x;
  const int lane = tid & 63, wid = tid >> 6;
  const int l15 = lane & 15, g4 = lane >> 4;
  const int q = q0 + wid * 16 + l15;

  __shared__ __align__(16) u16 kls[64][72];
  __shared__ __align__(16) u16 vls[64][72];
  __shared__ __align__(16) u16 pls[4][16][72];
  __shared__ float kpm[64];

  bf16x8 qf[2];
  {
    const u16* qp = qkv + ((size_t)b * SPn + q) * 3072 + h * 64 + g4 * 8;
    qf[0] = *(const bf16x8*)qp;
    qf[1] = *(const bf16x8*)(qp + 32);
  }
  const float gr = gate[(size_t)bh * SPn + q];
  const int qpb = (q < Sn) ? q : (Sn - 1);
  const float* pbrow = pb + ((size_t)bh * Sn + qpb) * Sn;

  float m = -3.0e38f, l = 0.f;
  f32x4 accO[4];
  f32x4 zr; zr[0] = 0.f; zr[1] = 0.f; zr[2] = 0.f; zr[3] = 0.f;
#pragma unroll
  for (int i = 0; i < 4; i++) accO[i] = zr;

  for (int kt = 0; kt < 24; kt++) {
    const int k0 = kt * 64;
    __syncthreads();
#pragma unroll
    for (int i = 0; i < 2; i++) {
      int idx = i * 256 + tid;
      int row = idx >> 3, c8 = (idx & 7) * 8;
      *(int4*)&kls[row][c8] =
          *(const int4*)(qkv + ((size_t)b * SPn + k0 + row) * 3072 + 1024 + h * 64 + c8);
      *(int4*)&vls[row][c8] =
          *(const int4*)(vT + ((size_t)bh * 64 + row) * SPn + k0 + c8);
    }
    if (tid < 64) {
      int sk = k0 + tid;
      kpm[tid] = (sk < Sn) ? (1.f - am[b * Sn + sk]) * -10000.f : -1e30f;
    }
    __syncthreads();

    f32x4 sAcc[4];
#pragma unroll
    for (int km = 0; km < 4; km++) {
      sAcc[km] = zr;
#pragma unroll
      for (int dc = 0; dc < 2; dc++) {
        bf16x8 af = *(const bf16x8*)&kls[km * 16 + l15][dc * 32 + g4 * 8];
        sAcc[km] = __builtin_amdgcn_mfma_f32_16x16x32_bf16(af, qf[dc], sAcc[km], 0, 0, 0);
      }
    }

    float sc[16];
    const bool tail = (k0 + 63 >= Sn);
#pragma unroll
    for (int km = 0; km < 4; km++) {
      int kk = k0 + km * 16 + g4 * 4;
      float4 pbv;
      if (!tail) {
        pbv = *(const float4*)(pbrow + kk);
      } else {
        pbv.x = (kk + 0 < Sn) ? pbrow[kk + 0] : 0.f;
        pbv.y = (kk + 1 < Sn) ? pbrow[kk + 1] : 0.f;
        pbv.z = (kk + 2 < Sn) ? pbrow[kk + 2] : 0.f;
        pbv.w = (kk + 3 < Sn) ? pbrow[kk + 3] : 0.f;
      }
      float4 kp = *(const float4*)&kpm[km * 16 + g4 * 4];
      sc[km * 4 + 0] = sAcc[km][0] * 0.125f + gr * pbv.x + kp.x;
      sc[km * 4 + 1] = sAcc[km][1] * 0.125f + gr * pbv.y + kp.y;
      sc[km * 4 + 2] = sAcc[km][2] * 0.125f + gr * pbv.z + kp.z;
      sc[km * 4 + 3] = sAcc[km][3] * 0.125f + gr * pbv.w + kp.w;
    }

    float mloc = sc[0];
#pragma unroll
    for (int i = 1; i < 16; i++) mloc = fmaxf(mloc, sc[i]);
    mloc = fmaxf(mloc, __shfl_xor(mloc, 16));
    mloc = fmaxf(mloc, __shfl_xor(mloc, 32));

    if (mloc > m + 8.f) {
      float corr = __expf(m - mloc);
      m = mloc;
      l *= corr;
#pragma unroll
      for (int i = 0; i < 4; i++) {
        accO[i][0] *= corr; accO[i][1] *= corr;
        accO[i][2] *= corr; accO[i][3] *= corr;
      }
    }

    float ls = 0.f;
#pragma unroll
    for (int i = 0; i < 16; i++) {
      float p = __expf(sc[i] - m);
      sc[i] = p;
      ls += p;
    }
    ls += __shfl_xor(ls, 16);
    ls += __shfl_xor(ls, 32);
    l += ls;

#pragma unroll
    for (int km = 0; km < 4; km++) {
      u32 lo = (u32)f2bu(sc[km * 4 + 0]) | ((u32)f2bu(sc[km * 4 + 1]) << 16);
      u32 hi = (u32)f2bu(sc[km * 4 + 2]) | ((u32)f2bu(sc[km * 4 + 3]) << 16);
      u32* dst = (u32*)&pls[wid][l15][km * 16 + g4 * 4];
      dst[0] = lo; dst[1] = hi;
    }

    bf16x8 pf[2];
    pf[0] = *(const bf16x8*)&pls[wid][l15][g4 * 8];
    pf[1] = *(const bf16x8*)&pls[wid][l15][32 + g4 * 8];
#pragma unroll
    for (int dm = 0; dm < 4; dm++) {
#pragma unroll
      for (int kc = 0; kc < 2; kc++) {
        bf16x8 af = *(const bf16x8*)&vls[dm * 16 + l15][kc * 32 + g4 * 8];
        accO[dm] = __builtin_amdgcn_mfma_f32_16x16x32_bf16(af, pf[kc], accO[dm], 0, 0, 0);
      }
    }
  }

  float inv = 1.f / l;
  const bool qv = q < Sn;
#pragma unroll
  for (int dm = 0; dm < 4; dm++) {
    ushort4 st;
    st.x = f2bu(qv ? accO[dm][0] * inv : 0.f);
    st.y = f2bu(qv ? accO[dm][1] * inv : 0.f);
    st.z = f2bu(qv ? accO[dm][2] * inv : 0.f);
    st.w = f2bu(qv ? accO[dm][3] * inv : 0.f);
    *(ushort4*)(ctx + ((size_t)b * SPn + q) * Cn + h * 64 + dm * 16 + g4 * 4) = st;
  }
}

// ---------------- fused 3-way residual + LayerNorm over C ----------------
__global__ __launch_bounds__(256) void k_ln3(
    const float* __restrict__ r1, const float* __restrict__ r2,
    const float* __restrict__ r3,
    const float* __restrict__ g, const float* __restrict__ be,
    float* __restrict__ outF, u16* __restrict__ outB)
{
  const int s = blockIdx.x, b = blockIdx.y;
  const size_t base = ((size_t)b * SPn + s) * Cn;
  __shared__ float buf[Cn];
  __shared__ float red[8];
  const int tid = threadIdx.x;
  float sum = 0.f;
#pragma unroll
  for (int i = 0; i < 4; i++) {
    int c = tid + i * 256;
    float t = r1[base + c] + r2[base + c] + r3[base + c];
    buf[c] = t;
    sum += t;
  }
#pragma unroll
  for (int mk = 1; mk < 64; mk <<= 1) sum += __shfl_xor(sum, mk);
  if ((tid & 63) == 0) red[tid >> 6] = sum;
  __syncthreads();
  float mu = (red[0] + red[1] + red[2] + red[3]) * (1.f / Cn);
  float vs = 0.f;
#pragma unroll
  for (int i = 0; i < 4; i++) {
    int c = tid + i * 256;
    float d = buf[c] - mu;
    vs += d * d;
  }
#pragma unroll
  for (int mk = 1; mk < 64; mk <<= 1) vs += __shfl_xor(vs, mk);
  if ((tid & 63) == 0) red[4 + (tid >> 6)] = vs;
  __syncthreads();
  float var = (red[4] + red[5] + red[6] + red[7]) * (1.f / Cn);
  float rstd = rsqrtf(var + 1e-5f);
#pragma unroll
  for (int i = 0; i < 4; i++) {
    int c = tid + i * 256;
    float val = (buf[c] - mu) * rstd * g[c] + be[c];
    outF[base + c] = val;
    if (outB) outB[base + c] = f2bu(val);
  }
}

extern "C" void kernel_launch(void* const* d_in, const int* in_sizes, int n_in,
                              void* d_out, int out_size, void* d_ws, size_t ws_size,
                              hipStream_t stream)
{
  const float* x    = (const float*)d_in[0];
  const float* am   = (const float*)d_in[1];
  const float* pb   = (const float*)d_in[2];
  const float* Wq   = (const float*)d_in[3];
  const float* bq   = (const float*)d_in[4];
  const float* Wk   = (const float*)d_in[5];
  const float* bk   = (const float*)d_in[6];
  const float* Wv   = (const float*)d_in[7];
  const float* bv   = (const float*)d_in[8];
  const float* Wo   = (const float*)d_in[9];
  const float* bo   = (const float*)d_in[10];
  const float* Wg   = (const float*)d_in[11];
  const float* bg   = (const float*)d_in[12];
  const float* gc   = (const float*)d_in[13];
  const float* ln1g = (const float*)d_in[14];
  const float* ln1b = (const float*)d_in[15];
  const float* W1   = (const float*)d_in[16];
  const float* b1   = (const float*)d_in[17];
  const float* W2   = (const float*)d_in[18];
  const float* b2   = (const float*)d_in[19];
  const float* ln2g = (const float*)d_in[20];
  const float* ln2b = (const float*)d_in[21];

  // workspace arena (94,580,736 bytes; lifetime-aliased)
  char* ws = (char*)d_ws;
  float* xT     = (float*)(ws + 0);            // [t_in .. LN1]
  u16*   xTb    = (u16*)(ws + 12582912);       // [t_in .. QKV] -> ctxT [flash..Wo]
  u16*   wqkvb  = (u16*)(ws + 18874368);       // [prep .. QKV] -> hTb [LN1..FFN1]
  u16*   wob    = (u16*)(ws + 25165824);
  u16*   w1b    = (u16*)(ws + 27262976);
  u16*   w2b    = (u16*)(ws + 35651584);
  float* bqkv   = (float*)(ws + 44040192);
  float* gate   = (float*)(ws + 44052480);
  u16*   qkvB   = (u16*)(ws + 44249088);       // [QKV .. flash]; then hT f32 [LN1..LN2]
  u16*   vT     = (u16*)(ws + 63123456);       // [vtrans .. flash]
  float* attnTa = (float*)(ws + 69414912);     // [Wo .. LN1]
  float* attnTb = (float*)(ws + 81997824);     // [Wo .. LN1]
  u16*   ctxT   = xTb;
  float* hT     = (float*)(ws + 44249088);
  u16*   hTb    = wqkvb;
  u16*   fT     = (u16*)(ws + 56832000);       // [FFN1 .. FFN2]
  float* f2Ta   = (float*)(ws + 0);            // [FFN2 .. LN2]
  float* f2Tb   = (float*)(ws + 81997824);     // [FFN2 .. LN2]
  float* outT   = (float*)(ws + 12582912);     // [LN2 .. t_out]

  dim3 blk(256);
  k_transpose_in<<<dim3(Cn / 32, SPn / 32, Bn), blk, 0, stream>>>(x, xT, xTb);
  k_prep<<<dim3(12291), blk, 0, stream>>>(Wq, Wk, Wv, Wo, W1, W2, bq, bk, bv,
                                          wqkvb, wob, w1b, w2b, bqkv);
  k_gate<<<dim3(SPn / 256, Hn, Bn), blk, 0, stream>>>(x, Wg, bg, gc, gate);

  // QKV projection -> bf16: M=3072, K=1024
  k_gemm<2, 1><<<dim3(24, 12, Bn), blk, 0, stream>>>(
      wqkvb, xTb, bqkv, qkvB, qkvB, 3072, 1024, 1024);
  // V^T for PV MFMA
  k_vtrans<<<dim3(SPn / 32, 2, Bn * Hn), blk, 0, stream>>>(qkvB, vT);
  // MFMA flash attention
  k_flash_mfma<<<dim3(SPn / 64, Bn * Hn), blk, 0, stream>>>(qkvB, vT, pb, am, gate, ctxT);
  // Wo: M=1024, K=1024, split-K=2
  k_gemm<0, 2><<<dim3(8, 12, Bn * 2), blk, 0, stream>>>(
      wob, ctxT, bo, attnTa, attnTb, 1024, 1024, 1024);
  // LN1 = LN(x + attnA + attnB) -> hT (f32) + hTb (bf16)
  k_ln3<<<dim3(SPn, Bn), blk, 0, stream>>>(xT, attnTa, attnTb, ln1g, ln1b, hT, hTb);
  // FFN1 + gelu -> fT (bf16): M=4096, K=1024
  k_gemm<1, 1><<<dim3(32, 12, Bn), blk, 0, stream>>>(
      w1b, hTb, b1, fT, fT, 4096, 1024, 1024);
  // FFN2: M=1024, K=4096, split-K=2
  k_gemm<0, 2><<<dim3(8, 12, Bn * 2), blk, 0, stream>>>(
      w2b, fT, b2, f2Ta, f2Tb, 1024, 4096, 4096);
  // LN2 = LN(h + f2a + f2b) -> outT
  k_ln3<<<dim3(SPn, Bn), blk, 0, stream>>>(hT, f2Ta, f2Tb, ln2g, ln2b, outT, (u16*)nullptr);
  // back to (B,C,1,S)
  k_transpose_out<<<dim3(Cn / 32, SPn / 32, Bn), blk, 0, stream>>>(outT, (float*)d_out);
}

// Round 6
// 295.502 us; speedup vs baseline: 3.0414x; 1.1391x over previous
//
#include <hip/hip_runtime.h>
#include <cstddef>
#include <cstdint>

#define Bn 2
#define Sn 1500
#define SPn 1536
#define Cn 1024
#define Hn 16
#define FFn 4096

typedef __attribute__((ext_vector_type(8))) short bf16x8;
typedef __attribute__((ext_vector_type(4))) float f32x4;
typedef unsigned short u16;
typedef unsigned int u32;

__device__ __forceinline__ u16 f2bu(float f) {
  unsigned u = __float_as_uint(f);
  return (u16)((u + 0x7fffu + ((u >> 16) & 1u)) >> 16);
}

// async global->LDS, 16B per lane. LDS dest = wave-uniform base + lane*16.
__device__ __forceinline__ void gl_lds16(const u16* g, u16* l) {
  __builtin_amdgcn_global_load_lds(
      (__attribute__((address_space(1))) void*)(uintptr_t)g,
      (__attribute__((address_space(3))) void*)(u32)(uintptr_t)l,
      16, 0, 0);
}

// ---------------- fused preamble: transpose_in + weight prep + gate ----------------
// segments (blockIdx.x):
//   [0,3072)            transpose+cast x -> xT f32 + xTb bf16  (32 ctiles x 48 stiles x 2 b)
//   [3072,15363)        weight casts + bias pack (12291 float4-group blocks)
//   [15363,15555)       gate (6 stiles x 16 h x 2 b)
__global__ __launch_bounds__(256) void k_pre(
    const float* __restrict__ x,
    const float* __restrict__ Wq, const float* __restrict__ Wk,
    const float* __restrict__ Wv, const float* __restrict__ Wo,
    const float* __restrict__ W1, const float* __restrict__ W2,
    const float* __restrict__ bq, const float* __restrict__ bk,
    const float* __restrict__ bv,
    const float* __restrict__ Wg, const float* __restrict__ bg,
    const float* __restrict__ gc,
    float* __restrict__ xT, u16* __restrict__ xTb,
    u16* __restrict__ wqkvb, u16* __restrict__ wob,
    u16* __restrict__ w1b, u16* __restrict__ w2b, float* __restrict__ bqkv,
    float* __restrict__ gate)
{
  const int bid = blockIdx.x;
  if (bid < 3072) {
    // ---- transpose + cast ----
    __shared__ float t[32][33];
    const int c0 = (bid & 31) * 32, s0 = ((bid >> 5) % 48) * 32, b = bid / 1536;
    const int tx = threadIdx.x & 31, ty = threadIdx.x >> 5;
#pragma unroll
    for (int i = 0; i < 32; i += 8) {
      int c = c0 + ty + i, s = s0 + tx;
      t[ty + i][tx] = (s < Sn) ? x[((size_t)b * Cn + c) * Sn + s] : 0.f;
    }
    __syncthreads();
#pragma unroll
    for (int i = 0; i < 32; i += 8) {
      int s = s0 + ty + i, c = c0 + tx;
      float v = t[tx][ty + i];
      size_t o = ((size_t)b * SPn + s) * Cn + c;
      xT[o] = v;
      xTb[o] = f2bu(v);
    }
    return;
  }
  if (bid < 15363) {
    // ---- weight cast / bias pack ----
    int i = (bid - 3072) * 256 + threadIdx.x;
    const float* src;
    u16* dst;
    int j;
    if (i < 786432) {
      src = (i < 262144) ? Wq : ((i < 524288) ? Wk : Wv);
      j = i & 262143;
      dst = wqkvb + (size_t)i * 4;
    } else if (i < 1048576) {
      src = Wo; j = i - 786432; dst = wob + (size_t)j * 4;
    } else if (i < 2097152) {
      src = W1; j = i - 1048576; dst = w1b + (size_t)j * 4;
    } else if (i < 3145728) {
      src = W2; j = i - 2097152; dst = w2b + (size_t)j * 4;
    } else {
      int k = i - 3145728;  // 0..767
      const float* bsrc = (k < 256) ? bq : ((k < 512) ? bk : bv);
      float4 v = *(const float4*)(bsrc + (k & 255) * 4);
      *(float4*)(bqkv + k * 4) = v;
      return;
    }
    float4 v = *(const float4*)(src + (size_t)j * 4);
    ushort4 o;
    o.x = f2bu(v.x); o.y = f2bu(v.y); o.z = f2bu(v.z); o.w = f2bu(v.w);
    *(ushort4*)dst = o;
    return;
  }
  {
    // ---- gate ----
    const int gid = bid - 15363;
    const int b = gid / 96, h = (gid / 6) & 15;
    const int s = (gid % 6) * 256 + threadIdx.x;
    const bool vld = s < Sn;
    const float* xp = x + ((size_t)b * Cn + h * 64) * Sn + (vld ? s : 0);
    float dot[8];
#pragma unroll
    for (int o = 0; o < 8; o++) dot[o] = 0.f;
    for (int d = 0; d < 64; d++) {
      float v = xp[(size_t)d * Sn];
#pragma unroll
      for (int o = 0; o < 8; o++) dot[o] += Wg[o * 64 + d] * v;
    }
    float sa = dot[0] + dot[1] + dot[2] + dot[3] + bg[0] + bg[1] + bg[2] + bg[3];
    float sb = dot[4] + dot[5] + dot[6] + dot[7] + bg[4] + bg[5] + bg[6] + bg[7];
    float ga = 1.f / (1.f + __expf(-sa));
    float gb = 1.f / (1.f + __expf(-sb));
    float gv = ga * (gb * gc[h] - 1.f) + 2.f;
    gate[((size_t)b * Hn + h) * SPn + s] = vld ? gv : 0.f;
  }
}

// ---------------- transpose output: outT (B,SP,C) -> out (B,C,S) ----------------
__global__ __launch_bounds__(256) void k_transpose_out(
    const float* __restrict__ oT, float* __restrict__ o)
{
  __shared__ float t[32][33];
  const int b = blockIdx.z, c0 = blockIdx.x * 32, s0 = blockIdx.y * 32;
  const int tx = threadIdx.x & 31, ty = threadIdx.x >> 5;
#pragma unroll
  for (int i = 0; i < 32; i += 8) {
    int s = s0 + ty + i, c = c0 + tx;
    t[ty + i][tx] = oT[((size_t)b * SPn + s) * Cn + c];
  }
  __syncthreads();
#pragma unroll
  for (int i = 0; i < 32; i += 8) {
    int c = c0 + ty + i, s = s0 + tx;
    if (s < Sn) o[((size_t)b * Cn + c) * Sn + s] = t[tx][ty + i];
  }
}

// ---------------- bf16 MFMA GEMM, BK=64, global_load_lds staging, tile TM x 128 ----------------
// EPI: 0 = f32 out, 1 = gelu -> bf16, 2 = bf16 out (+ V-part scatter to vT)
// SPLIT: K split in one dispatch; half 0 -> out (+bias), half 1 -> out2 (no bias)
// Grid sized so every GEMM = 768 blocks = exactly 3/CU.
template <int EPI, int SPLIT, int TM>
__global__ __launch_bounds__(256) void k_gemm(
    const u16* __restrict__ A, const u16* __restrict__ X,
    const float* __restrict__ bias, void* __restrict__ out, void* __restrict__ out2,
    u16* __restrict__ vT, int M, int Kst, int Ktot)
{
  constexpr int NI = TM / 32;          // M-frags per wave
  const int zz = blockIdx.z;
  const int b = zz / SPLIT, half = zz % SPLIT;
  const int Kc = Ktot / SPLIT;
  const int m0 = blockIdx.x * TM;
  const int s0 = blockIdx.y * 128;
  const int tid = threadIdx.x;
  const int lane = tid & 63;
  const int wid = tid >> 6;
  const int wm = (wid >> 1) * (TM / 2);
  const int wn = (wid & 1) * 64;
  const int l15 = lane & 15;
  const int g4 = lane >> 4;

  __shared__ __align__(16) u16 lA[TM][64];
  __shared__ __align__(16) u16 lX[128][64];

  f32x4 acc[NI][4];
  f32x4 zr; zr[0] = 0.f; zr[1] = 0.f; zr[2] = 0.f; zr[3] = 0.f;
#pragma unroll
  for (int i = 0; i < NI; i++)
#pragma unroll
    for (int j = 0; j < 4; j++) acc[i][j] = zr;

  // staging: 16B/lane; 8 lanes/row -> 8 rows per inst per wave
  const int rlo = lane >> 3;               // row within 8-row group
  const int cg = (lane & 7) ^ rlo;         // inverse-swizzled global col-block
  const int kbeg = half * Kc;
  const u16* gA = A + (size_t)(m0 + wid * (TM / 4) + rlo) * Kst + cg * 8 + kbeg;
  const u16* gX = X + ((size_t)b * SPn + s0 + wid * 32 + rlo) * Kst + cg * 8 + kbeg;
  u16* lAp = &lA[0][0] + wid * (TM / 4) * 64;
  u16* lXp = &lX[0][0] + wid * 2048;
  const size_t rstep8 = (size_t)8 * Kst;

  for (int kt = 0; kt < Kc; kt += 64) {
    __syncthreads();
#pragma unroll
    for (int j = 0; j < TM / 32; j++)
      gl_lds16(gA + j * rstep8 + kt, lAp + j * 512);
#pragma unroll
    for (int j = 0; j < 4; j++)
      gl_lds16(gX + j * rstep8 + kt, lXp + j * 512);
    __syncthreads();
#pragma unroll
    for (int ks = 0; ks < 2; ks++) {
      bf16x8 af[NI], bfr[4];
#pragma unroll
      for (int i = 0; i < NI; i++) {
        int ra = wm + i * 16 + l15;
        af[i] = *(const bf16x8*)&lA[ra][((ks * 4 + g4) ^ (ra & 7)) * 8];
      }
#pragma unroll
      for (int j = 0; j < 4; j++) {
        int rb = wn + j * 16 + l15;
        bfr[j] = *(const bf16x8*)&lX[rb][((ks * 4 + g4) ^ (rb & 7)) * 8];
      }
#pragma unroll
      for (int i = 0; i < NI; i++)
#pragma unroll
        for (int j = 0; j < 4; j++)
          acc[i][j] = __builtin_amdgcn_mfma_f32_16x16x32_bf16(af[i], bfr[j], acc[i][j], 0, 0, 0);
    }
  }

  const float hsc = (half == 0) ? 1.f : 0.f;
  void* outp = (half == 0) ? out : out2;
#pragma unroll
  for (int i = 0; i < NI; i++) {
    int o = m0 + wm + i * 16 + g4 * 4;
    float4 bs = *(const float4*)(bias + o);
#pragma unroll
    for (int j = 0; j < 4; j++) {
      int s = s0 + wn + j * 16 + l15;
      size_t oidx = ((size_t)b * SPn + s) * M + o;
      f32x4 v = acc[i][j];
      float x0 = v[0] + bs.x * hsc, x1 = v[1] + bs.y * hsc;
      float x2 = v[2] + bs.z * hsc, x3 = v[3] + bs.w * hsc;
      if (EPI == 0) {
        float4 st; st.x = x0; st.y = x1; st.z = x2; st.w = x3;
        *(float4*)((float*)outp + oidx) = st;
      } else if (EPI == 1) {
        x0 = 0.5f * x0 * (1.f + erff(x0 * 0.70710678118654752f));
        x1 = 0.5f * x1 * (1.f + erff(x1 * 0.70710678118654752f));
        x2 = 0.5f * x2 * (1.f + erff(x2 * 0.70710678118654752f));
        x3 = 0.5f * x3 * (1.f + erff(x3 * 0.70710678118654752f));
        ushort4 st;
        st.x = f2bu(x0); st.y = f2bu(x1); st.z = f2bu(x2); st.w = f2bu(x3);
        *(ushort4*)((u16*)outp + oidx) = st;
      } else {
        ushort4 st;
        st.x = f2bu(x0); st.y = f2bu(x1); st.z = f2bu(x2); st.w = f2bu(x3);
        *(ushort4*)((u16*)outp + oidx) = st;
        if (EPI == 2 && o >= 2048) {
          // V-part: also scatter into vT[bh][d][s]
          int oo = o - 2048;
          int h = oo >> 6, d = oo & 63;
          u16* vp = vT + ((size_t)(b * Hn + h) * 64 + d) * SPn + s;
          vp[0] = st.x;
          vp[SPn] = st.y;
          vp[2 * SPn] = st.z;
          vp[3 * SPn] = st.w;
        }
      }
    }
  }
}

// ---------------- MFMA flash attention ----------------
__global__ __launch_bounds__(256) void k_flash_mfma(
    const u16* __restrict__ qkv,    // [B][SP][3072] bf16 (Q|K|V)
    const u16* __restrict__ vT,     // [BH][64][SP] bf16
    const float* __restrict__ pb,   // [BH][S][S] f32
    const float* __restrict__ am,   // [B][S]
    const float* __restrict__ gate, // [BH][SP]
    u16* __restrict__ ctx)          // [B][SP][C] bf16
{
  const int bh = blockIdx.y, b = bh >> 4, h = bh & 15;
  const int q0 = blockIdx.x * 64;
  const int tid = threadIdx.x;
  const int lane = tid & 63, wid = tid >> 6;
  const int l15 = lane & 15, g4 = lane >> 4;
  const int q = q0 + wid * 16 + l15;

  __shared__ __align__(16) u16 kls[64][72];
  __shared__ __align__(16) u16 vls[64][72];
  __shared__ __align__(16) u16 pls[4][16][72];
  __shared__ float kpm[64];

  bf16x8 qf[2];
  {
    const u16* qp = qkv + ((size_t)b * SPn + q) * 3072 + h * 64 + g4 * 8;
    qf[0] = *(const bf16x8*)qp;
    qf[1] = *(const bf16x8*)(qp + 32);
  }
  const float gr = gate[(size_t)bh * SPn + q];
  const int qpb = (q < Sn) ? q : (Sn - 1);
  const float* pbrow = pb + ((size_t)bh * Sn + qpb) * Sn;

  float m = -3.0e38f, l = 0.f;
  f32x4 accO[4];
  f32x4 zr; zr[0] = 0.f; zr[1] = 0.f; zr[2] = 0.f; zr[3] = 0.f;
#pragma unroll
  for (int i = 0; i < 4; i++) accO[i] = zr;

  for (int kt = 0; kt < 24; kt++) {
    const int k0 = kt * 64;
    __syncthreads();
#pragma unroll
    for (int i = 0; i < 2; i++) {
      int idx = i * 256 + tid;
      int row = idx >> 3, c8 = (idx & 7) * 8;
      *(int4*)&kls[row][c8] =
          *(const int4*)(qkv + ((size_t)b * SPn + k0 + row) * 3072 + 1024 + h * 64 + c8);
      *(int4*)&vls[row][c8] =
          *(const int4*)(vT + ((size_t)bh * 64 + row) * SPn + k0 + c8);
    }
    if (tid < 64) {
      int sk = k0 + tid;
      kpm[tid] = (sk < Sn) ? (1.f - am[b * Sn + sk]) * -10000.f : -1e30f;
    }
    __syncthreads();

    f32x4 sAcc[4];
#pragma unroll
    for (int km = 0; km < 4; km++) {
      sAcc[km] = zr;
#pragma unroll
      for (int dc = 0; dc < 2; dc++) {
        bf16x8 af = *(const bf16x8*)&kls[km * 16 + l15][dc * 32 + g4 * 8];
        sAcc[km] = __builtin_amdgcn_mfma_f32_16x16x32_bf16(af, qf[dc], sAcc[km], 0, 0, 0);
      }
    }

    float sc[16];
    const bool tail = (k0 + 63 >= Sn);
#pragma unroll
    for (int km = 0; km < 4; km++) {
      int kk = k0 + km * 16 + g4 * 4;
      float4 pbv;
      if (!tail) {
        pbv = *(const float4*)(pbrow + kk);
      } else {
        pbv.x = (kk + 0 < Sn) ? pbrow[kk + 0] : 0.f;
        pbv.y = (kk + 1 < Sn) ? pbrow[kk + 1] : 0.f;
        pbv.z = (kk + 2 < Sn) ? pbrow[kk + 2] : 0.f;
        pbv.w = (kk + 3 < Sn) ? pbrow[kk + 3] : 0.f;
      }
      float4 kp = *(const float4*)&kpm[km * 16 + g4 * 4];
      sc[km * 4 + 0] = sAcc[km][0] * 0.125f + gr * pbv.x + kp.x;
      sc[km * 4 + 1] = sAcc[km][1] * 0.125f + gr * pbv.y + kp.y;
      sc[km * 4 + 2] = sAcc[km][2] * 0.125f + gr * pbv.z + kp.z;
      sc[km * 4 + 3] = sAcc[km][3] * 0.125f + gr * pbv.w + kp.w;
    }

    float mloc = sc[0];
#pragma unroll
    for (int i = 1; i < 16; i++) mloc = fmaxf(mloc, sc[i]);
    mloc = fmaxf(mloc, __shfl_xor(mloc, 16));
    mloc = fmaxf(mloc, __shfl_xor(mloc, 32));

    if (mloc > m + 8.f) {
      float corr = __expf(m - mloc);
      m = mloc;
      l *= corr;
#pragma unroll
      for (int i = 0; i < 4; i++) {
        accO[i][0] *= corr; accO[i][1] *= corr;
        accO[i][2] *= corr; accO[i][3] *= corr;
      }
    }

    float ls = 0.f;
#pragma unroll
    for (int i = 0; i < 16; i++) {
      float p = __expf(sc[i] - m);
      sc[i] = p;
      ls += p;
    }
    ls += __shfl_xor(ls, 16);
    ls += __shfl_xor(ls, 32);
    l += ls;

#pragma unroll
    for (int km = 0; km < 4; km++) {
      u32 lo = (u32)f2bu(sc[km * 4 + 0]) | ((u32)f2bu(sc[km * 4 + 1]) << 16);
      u32 hi = (u32)f2bu(sc[km * 4 + 2]) | ((u32)f2bu(sc[km * 4 + 3]) << 16);
      u32* dst = (u32*)&pls[wid][l15][km * 16 + g4 * 4];
      dst[0] = lo; dst[1] = hi;
    }

    bf16x8 pf[2];
    pf[0] = *(const bf16x8*)&pls[wid][l15][g4 * 8];
    pf[1] = *(const bf16x8*)&pls[wid][l15][32 + g4 * 8];
#pragma unroll
    for (int dm = 0; dm < 4; dm++) {
#pragma unroll
      for (int kc = 0; kc < 2; kc++) {
        bf16x8 af = *(const bf16x8*)&vls[dm * 16 + l15][kc * 32 + g4 * 8];
        accO[dm] = __builtin_amdgcn_mfma_f32_16x16x32_bf16(af, pf[kc], accO[dm], 0, 0, 0);
      }
    }
  }

  float inv = 1.f / l;
  const bool qv = q < Sn;
#pragma unroll
  for (int dm = 0; dm < 4; dm++) {
    ushort4 st;
    st.x = f2bu(qv ? accO[dm][0] * inv : 0.f);
    st.y = f2bu(qv ? accO[dm][1] * inv : 0.f);
    st.z = f2bu(qv ? accO[dm][2] * inv : 0.f);
    st.w = f2bu(qv ? accO[dm][3] * inv : 0.f);
    *(ushort4*)(ctx + ((size_t)b * SPn + q) * Cn + h * 64 + dm * 16 + g4 * 4) = st;
  }
}

// ---------------- fused 3-way residual + LayerNorm over C ----------------
__global__ __launch_bounds__(256) void k_ln3(
    const float* __restrict__ r1, const float* __restrict__ r2,
    const float* __restrict__ r3,
    const float* __restrict__ g, const float* __restrict__ be,
    float* __restrict__ outF, u16* __restrict__ outB)
{
  const int s = blockIdx.x, b = blockIdx.y;
  const size_t base = ((size_t)b * SPn + s) * Cn;
  __shared__ float buf[Cn];
  __shared__ float red[8];
  const int tid = threadIdx.x;
  float sum = 0.f;
#pragma unroll
  for (int i = 0; i < 4; i++) {
    int c = tid + i * 256;
    float t = r1[base + c] + r2[base + c] + r3[base + c];
    buf[c] = t;
    sum += t;
  }
#pragma unroll
  for (int mk = 1; mk < 64; mk <<= 1) sum += __shfl_xor(sum, mk);
  if ((tid & 63) == 0) red[tid >> 6] = sum;
  __syncthreads();
  float mu = (red[0] + red[1] + red[2] + red[3]) * (1.f / Cn);
  float vs = 0.f;
#pragma unroll
  for (int i = 0; i < 4; i++) {
    int c = tid + i * 256;
    float d = buf[c] - mu;
    vs += d * d;
  }
#pragma unroll
  for (int mk = 1; mk < 64; mk <<= 1) vs += __shfl_xor(vs, mk);
  if ((tid & 63) == 0) red[4 + (tid >> 6)] = vs;
  __syncthreads();
  float var = (red[4] + red[5] + red[6] + red[7]) * (1.f / Cn);
  float rstd = rsqrtf(var + 1e-5f);
#pragma unroll
  for (int i = 0; i < 4; i++) {
    int c = tid + i * 256;
    float val = (buf[c] - mu) * rstd * g[c] + be[c];
    outF[base + c] = val;
    if (outB) outB[base + c] = f2bu(val);
  }
}

extern "C" void kernel_launch(void* const* d_in, const int* in_sizes, int n_in,
                              void* d_out, int out_size, void* d_ws, size_t ws_size,
                              hipStream_t stream)
{
  const float* x    = (const float*)d_in[0];
  const float* am   = (const float*)d_in[1];
  const float* pb   = (const float*)d_in[2];
  const float* Wq   = (const float*)d_in[3];
  const float* bq   = (const float*)d_in[4];
  const float* Wk   = (const float*)d_in[5];
  const float* bk   = (const float*)d_in[6];
  const float* Wv   = (const float*)d_in[7];
  const float* bv   = (const float*)d_in[8];
  const float* Wo   = (const float*)d_in[9];
  const float* bo   = (const float*)d_in[10];
  const float* Wg   = (const float*)d_in[11];
  const float* bg   = (const float*)d_in[12];
  const float* gc   = (const float*)d_in[13];
  const float* ln1g = (const float*)d_in[14];
  const float* ln1b = (const float*)d_in[15];
  const float* W1   = (const float*)d_in[16];
  const float* b1   = (const float*)d_in[17];
  const float* W2   = (const float*)d_in[18];
  const float* b2   = (const float*)d_in[19];
  const float* ln2g = (const float*)d_in[20];
  const float* ln2b = (const float*)d_in[21];

  // workspace arena (94,580,736 bytes; lifetime-aliased)
  char* ws = (char*)d_ws;
  float* xT     = (float*)(ws + 0);            // [pre .. LN1]
  u16*   xTb    = (u16*)(ws + 12582912);       // [pre .. QKV] -> ctxT [flash..Wo]
  u16*   wqkvb  = (u16*)(ws + 18874368);       // [pre .. QKV] -> hTb [LN1..FFN1]
  u16*   wob    = (u16*)(ws + 25165824);
  u16*   w1b    = (u16*)(ws + 27262976);
  u16*   w2b    = (u16*)(ws + 35651584);
  float* bqkv   = (float*)(ws + 44040192);
  float* gate   = (float*)(ws + 44052480);
  u16*   qkvB   = (u16*)(ws + 44249088);       // [QKV .. flash]; then hT f32 [LN1..LN2]
  u16*   vT     = (u16*)(ws + 63123456);       // [QKV .. flash]
  float* attnTa = (float*)(ws + 69414912);     // [Wo .. LN1]
  float* attnTb = (float*)(ws + 81997824);     // [Wo .. LN1]
  u16*   ctxT   = xTb;
  float* hT     = (float*)(ws + 44249088);
  u16*   hTb    = wqkvb;
  u16*   fT     = (u16*)(ws + 56832000);       // [FFN1 .. FFN2]
  float* f2Ta   = (float*)(ws + 0);            // [FFN2 .. LN2]
  float* f2Tb   = (float*)(ws + 81997824);     // [FFN2 .. LN2]
  float* outT   = (float*)(ws + 12582912);     // [LN2 .. t_out]

  dim3 blk(256);
  // fused preamble: transpose_in (3072) + prep (12291) + gate (192)
  k_pre<<<dim3(15555), blk, 0, stream>>>(x, Wq, Wk, Wv, Wo, W1, W2, bq, bk, bv,
                                         Wg, bg, gc, xT, xTb, wqkvb, wob, w1b,
                                         w2b, bqkv, gate);

  // QKV projection -> bf16 (+fused V^T): M=3072, K=1024, TM=96 -> 768 blocks
  k_gemm<2, 1, 96><<<dim3(32, 12, Bn), blk, 0, stream>>>(
      wqkvb, xTb, bqkv, qkvB, qkvB, vT, 3072, 1024, 1024);
  // MFMA flash attention (768 blocks)
  k_flash_mfma<<<dim3(SPn / 64, Bn * Hn), blk, 0, stream>>>(qkvB, vT, pb, am, gate, ctxT);
  // Wo: M=1024, K=1024, TM=64, split-K=2 -> 768 blocks
  k_gemm<0, 2, 64><<<dim3(16, 12, Bn * 2), blk, 0, stream>>>(
      wob, ctxT, bo, attnTa, attnTb, (u16*)nullptr, 1024, 1024, 1024);
  // LN1 = LN(x + attnA + attnB) -> hT (f32) + hTb (bf16)
  k_ln3<<<dim3(SPn, Bn), blk, 0, stream>>>(xT, attnTa, attnTb, ln1g, ln1b, hT, hTb);
  // FFN1 + gelu -> fT (bf16): M=4096, K=1024, TM=128 -> 768 blocks
  k_gemm<1, 1, 128><<<dim3(32, 12, Bn), blk, 0, stream>>>(
      w1b, hTb, b1, fT, fT, (u16*)nullptr, 4096, 1024, 1024);
  // FFN2: M=1024, K=4096, TM=64, split-K=2 -> 768 blocks
  k_gemm<0, 2, 64><<<dim3(16, 12, Bn * 2), blk, 0, stream>>>(
      w2b, fT, b2, f2Ta, f2Tb, (u16*)nullptr, 1024, 4096, 4096);
  // LN2 = LN(h + f2a + f2b) -> outT
  k_ln3<<<dim3(SPn, Bn), blk, 0, stream>>>(hT, f2Ta, f2Tb, ln2g, ln2b, outT, (u16*)nullptr);
  // back to (B,C,1,S)
  k_transpose_out<<<dim3(Cn / 32, SPn / 32, Bn), blk, 0, stream>>>(outT, (float*)d_out);
}

// Round 7
// 267.643 us; speedup vs baseline: 3.3580x; 1.1041x over previous
//
#include <hip/hip_runtime.h>
#include <cstddef>
#include <cstdint>

#define Bn 2
#define Sn 1500
#define SPn 1536
#define Cn 1024
#define Hn 16
#define FFn 4096

typedef __attribute__((ext_vector_type(8))) short bf16x8;
typedef __attribute__((ext_vector_type(4))) float f32x4;
typedef unsigned short u16;
typedef unsigned int u32;

__device__ __forceinline__ u16 f2bu(float f) {
  unsigned u = __float_as_uint(f);
  return (u16)((u + 0x7fffu + ((u >> 16) & 1u)) >> 16);
}
__device__ __forceinline__ float bu2f(u16 v) {
  return __uint_as_float(((u32)v) << 16);
}

// async global->LDS, 16B per lane. LDS dest = wave-uniform base + lane*16.
__device__ __forceinline__ void gl_lds16(const u16* g, u16* l) {
  __builtin_amdgcn_global_load_lds(
      (__attribute__((address_space(1))) void*)(uintptr_t)g,
      (__attribute__((address_space(3))) void*)(u32)(uintptr_t)l,
      16, 0, 0);
}

// ---------------- fused preamble: transpose_in + weight prep + gate ----------------
__global__ __launch_bounds__(256) void k_pre(
    const float* __restrict__ x,
    const float* __restrict__ Wq, const float* __restrict__ Wk,
    const float* __restrict__ Wv, const float* __restrict__ Wo,
    const float* __restrict__ W1, const float* __restrict__ W2,
    const float* __restrict__ bq, const float* __restrict__ bk,
    const float* __restrict__ bv,
    const float* __restrict__ Wg, const float* __restrict__ bg,
    const float* __restrict__ gc,
    float* __restrict__ xT, u16* __restrict__ xTb,
    u16* __restrict__ wqkvb, u16* __restrict__ wob,
    u16* __restrict__ w1b, u16* __restrict__ w2b, float* __restrict__ bqkv,
    float* __restrict__ gate)
{
  const int bid = blockIdx.x;
  if (bid < 3072) {
    __shared__ float t[32][33];
    const int c0 = (bid & 31) * 32, s0 = ((bid >> 5) % 48) * 32, b = bid / 1536;
    const int tx = threadIdx.x & 31, ty = threadIdx.x >> 5;
#pragma unroll
    for (int i = 0; i < 32; i += 8) {
      int c = c0 + ty + i, s = s0 + tx;
      t[ty + i][tx] = (s < Sn) ? x[((size_t)b * Cn + c) * Sn + s] : 0.f;
    }
    __syncthreads();
#pragma unroll
    for (int i = 0; i < 32; i += 8) {
      int s = s0 + ty + i, c = c0 + tx;
      float v = t[tx][ty + i];
      size_t o = ((size_t)b * SPn + s) * Cn + c;
      xT[o] = v;
      xTb[o] = f2bu(v);
    }
    return;
  }
  if (bid < 15363) {
    int i = (bid - 3072) * 256 + threadIdx.x;
    const float* src;
    u16* dst;
    int j;
    if (i < 786432) {
      src = (i < 262144) ? Wq : ((i < 524288) ? Wk : Wv);
      j = i & 262143;
      dst = wqkvb + (size_t)i * 4;
    } else if (i < 1048576) {
      src = Wo; j = i - 786432; dst = wob + (size_t)j * 4;
    } else if (i < 2097152) {
      src = W1; j = i - 1048576; dst = w1b + (size_t)j * 4;
    } else if (i < 3145728) {
      src = W2; j = i - 2097152; dst = w2b + (size_t)j * 4;
    } else {
      int k = i - 3145728;
      const float* bsrc = (k < 256) ? bq : ((k < 512) ? bk : bv);
      float4 v = *(const float4*)(bsrc + (k & 255) * 4);
      *(float4*)(bqkv + k * 4) = v;
      return;
    }
    float4 v = *(const float4*)(src + (size_t)j * 4);
    ushort4 o;
    o.x = f2bu(v.x); o.y = f2bu(v.y); o.z = f2bu(v.z); o.w = f2bu(v.w);
    *(ushort4*)dst = o;
    return;
  }
  {
    const int gid = bid - 15363;
    const int b = gid / 96, h = (gid / 6) & 15;
    const int s = (gid % 6) * 256 + threadIdx.x;
    const bool vld = s < Sn;
    const float* xp = x + ((size_t)b * Cn + h * 64) * Sn + (vld ? s : 0);
    float dot[8];
#pragma unroll
    for (int o = 0; o < 8; o++) dot[o] = 0.f;
    for (int d = 0; d < 64; d++) {
      float v = xp[(size_t)d * Sn];
#pragma unroll
      for (int o = 0; o < 8; o++) dot[o] += Wg[o * 64 + d] * v;
    }
    float sa = dot[0] + dot[1] + dot[2] + dot[3] + bg[0] + bg[1] + bg[2] + bg[3];
    float sb = dot[4] + dot[5] + dot[6] + dot[7] + bg[4] + bg[5] + bg[6] + bg[7];
    float ga = 1.f / (1.f + __expf(-sa));
    float gb = 1.f / (1.f + __expf(-sb));
    float gv = ga * (gb * gc[h] - 1.f) + 2.f;
    gate[((size_t)b * Hn + h) * SPn + s] = vld ? gv : 0.f;
  }
}

// ---------------- transpose output: outT (B,SP,C) -> out (B,C,S) ----------------
__global__ __launch_bounds__(256) void k_transpose_out(
    const float* __restrict__ oT, float* __restrict__ o)
{
  __shared__ float t[32][33];
  const int b = blockIdx.z, c0 = blockIdx.x * 32, s0 = blockIdx.y * 32;
  const int tx = threadIdx.x & 31, ty = threadIdx.x >> 5;
#pragma unroll
  for (int i = 0; i < 32; i += 8) {
    int s = s0 + ty + i, c = c0 + tx;
    t[ty + i][tx] = oT[((size_t)b * SPn + s) * Cn + c];
  }
  __syncthreads();
#pragma unroll
  for (int i = 0; i < 32; i += 8) {
    int c = c0 + ty + i, s = s0 + tx;
    if (s < Sn) o[((size_t)b * Cn + c) * Sn + s] = t[tx][ty + i];
  }
}

// ---------------- bf16 MFMA GEMM, BK=64, global_load_lds staging, tile TM x 128 ----------------
// EPI: 0 = f32 out, 1 = gelu -> bf16, 2 = bf16 out (+ optional V-part scatter to vT)
template <int EPI, int SPLIT, int TM>
__global__ __launch_bounds__(256) void k_gemm(
    const u16* __restrict__ A, const u16* __restrict__ X,
    const float* __restrict__ bias, void* __restrict__ out, void* __restrict__ out2,
    u16* __restrict__ vT, int M, int Kst, int Ktot)
{
  constexpr int NI = TM / 32;
  const int zz = blockIdx.z;
  const int b = zz / SPLIT, half = zz % SPLIT;
  const int Kc = Ktot / SPLIT;
  const int m0 = blockIdx.x * TM;
  const int s0 = blockIdx.y * 128;
  const int tid = threadIdx.x;
  const int lane = tid & 63;
  const int wid = tid >> 6;
  const int wm = (wid >> 1) * (TM / 2);
  const int wn = (wid & 1) * 64;
  const int l15 = lane & 15;
  const int g4 = lane >> 4;

  __shared__ __align__(16) u16 lA[TM][64];
  __shared__ __align__(16) u16 lX[128][64];

  f32x4 acc[NI][4];
  f32x4 zr; zr[0] = 0.f; zr[1] = 0.f; zr[2] = 0.f; zr[3] = 0.f;
#pragma unroll
  for (int i = 0; i < NI; i++)
#pragma unroll
    for (int j = 0; j < 4; j++) acc[i][j] = zr;

  const int rlo = lane >> 3;
  const int cg = (lane & 7) ^ rlo;
  const int kbeg = half * Kc;
  const u16* gA = A + (size_t)(m0 + wid * (TM / 4) + rlo) * Kst + cg * 8 + kbeg;
  const u16* gX = X + ((size_t)b * SPn + s0 + wid * 32 + rlo) * Kst + cg * 8 + kbeg;
  u16* lAp = &lA[0][0] + wid * (TM / 4) * 64;
  u16* lXp = &lX[0][0] + wid * 2048;
  const size_t rstep8 = (size_t)8 * Kst;

  for (int kt = 0; kt < Kc; kt += 64) {
    __syncthreads();
#pragma unroll
    for (int j = 0; j < TM / 32; j++)
      gl_lds16(gA + j * rstep8 + kt, lAp + j * 512);
#pragma unroll
    for (int j = 0; j < 4; j++)
      gl_lds16(gX + j * rstep8 + kt, lXp + j * 512);
    __syncthreads();
#pragma unroll
    for (int ks = 0; ks < 2; ks++) {
      bf16x8 af[NI], bfr[4];
#pragma unroll
      for (int i = 0; i < NI; i++) {
        int ra = wm + i * 16 + l15;
        af[i] = *(const bf16x8*)&lA[ra][((ks * 4 + g4) ^ (ra & 7)) * 8];
      }
#pragma unroll
      for (int j = 0; j < 4; j++) {
        int rb = wn + j * 16 + l15;
        bfr[j] = *(const bf16x8*)&lX[rb][((ks * 4 + g4) ^ (rb & 7)) * 8];
      }
#pragma unroll
      for (int i = 0; i < NI; i++)
#pragma unroll
        for (int j = 0; j < 4; j++)
          acc[i][j] = __builtin_amdgcn_mfma_f32_16x16x32_bf16(af[i], bfr[j], acc[i][j], 0, 0, 0);
    }
  }

  const float hsc = (half == 0) ? 1.f : 0.f;
  void* outp = (half == 0) ? out : out2;
#pragma unroll
  for (int i = 0; i < NI; i++) {
    int o = m0 + wm + i * 16 + g4 * 4;
    float4 bs = *(const float4*)(bias + o);
#pragma unroll
    for (int j = 0; j < 4; j++) {
      int s = s0 + wn + j * 16 + l15;
      size_t oidx = ((size_t)b * SPn + s) * M + o;
      f32x4 v = acc[i][j];
      float x0 = v[0] + bs.x * hsc, x1 = v[1] + bs.y * hsc;
      float x2 = v[2] + bs.z * hsc, x3 = v[3] + bs.w * hsc;
      if (EPI == 0) {
        float4 st; st.x = x0; st.y = x1; st.z = x2; st.w = x3;
        *(float4*)((float*)outp + oidx) = st;
      } else if (EPI == 1) {
        x0 = 0.5f * x0 * (1.f + erff(x0 * 0.70710678118654752f));
        x1 = 0.5f * x1 * (1.f + erff(x1 * 0.70710678118654752f));
        x2 = 0.5f * x2 * (1.f + erff(x2 * 0.70710678118654752f));
        x3 = 0.5f * x3 * (1.f + erff(x3 * 0.70710678118654752f));
        ushort4 st;
        st.x = f2bu(x0); st.y = f2bu(x1); st.z = f2bu(x2); st.w = f2bu(x3);
        *(ushort4*)((u16*)outp + oidx) = st;
      } else {
        ushort4 st;
        st.x = f2bu(x0); st.y = f2bu(x1); st.z = f2bu(x2); st.w = f2bu(x3);
        *(ushort4*)((u16*)outp + oidx) = st;
        if (vT != nullptr && o >= 2048) {
          int oo = o - 2048;
          int h = oo >> 6, d = oo & 63;
          u16* vp = vT + ((size_t)(b * Hn + h) * 64 + d) * SPn + s;
          vp[0] = st.x;
          vp[SPn] = st.y;
          vp[2 * SPn] = st.z;
          vp[3 * SPn] = st.w;
        }
      }
    }
  }
}

// ---------------- MFMA flash attention, T14 async-stage pipeline ----------------
__global__ __launch_bounds__(256) void k_flash_mfma(
    const u16* __restrict__ qkv,    // [B][SP][3072] bf16 (Q|K|V)
    const u16* __restrict__ vT,     // [BH][64][SP] bf16
    const float* __restrict__ pb,   // [BH][S][S] f32
    const float* __restrict__ am,   // [B][S]
    const float* __restrict__ gate, // [BH][SP]
    u16* __restrict__ ctx)          // [B][SP][C] bf16
{
  const int bh = blockIdx.y, b = bh >> 4, h = bh & 15;
  const int q0 = blockIdx.x * 64;
  const int tid = threadIdx.x;
  const int lane = tid & 63, wid = tid >> 6;
  const int l15 = lane & 15, g4 = lane >> 4;
  const int q = q0 + wid * 16 + l15;

  __shared__ __align__(16) u16 kls[64][72];
  __shared__ __align__(16) u16 vls[64][72];
  __shared__ __align__(16) u16 pls[4][16][72];
  __shared__ float kpm[SPn];

  // staging geometry (per thread, i in {0,1})
  const int r0 = tid >> 3, c80 = (tid & 7) * 8;          // i=0
  const int r1 = (256 + tid) >> 3, c81 = c80;            // i=1 (row +32)
  const u16* kg0 = qkv + ((size_t)b * SPn + r0) * 3072 + 1024 + h * 64 + c80;
  const u16* kg1 = qkv + ((size_t)b * SPn + r1) * 3072 + 1024 + h * 64 + c81;
  const u16* vg0 = vT + ((size_t)bh * 64 + r0) * SPn + c80;
  const u16* vg1 = vT + ((size_t)bh * 64 + r1) * SPn + c81;

  // Q fragment + gate
  bf16x8 qf[2];
  {
    const u16* qp = qkv + ((size_t)b * SPn + q) * 3072 + h * 64 + g4 * 8;
    qf[0] = *(const bf16x8*)qp;
    qf[1] = *(const bf16x8*)(qp + 32);
  }
  const float gr = gate[(size_t)bh * SPn + q];
  const int qpb = (q < Sn) ? q : (Sn - 1);
  const float* pbrow = pb + ((size_t)bh * Sn + qpb) * Sn;

  // prologue: stage tile 0 + kpm, single barrier
  {
    int4 k0v = *(const int4*)kg0;
    int4 k1v = *(const int4*)kg1;
    int4 v0v = *(const int4*)vg0;
    int4 v1v = *(const int4*)vg1;
#pragma unroll
    for (int j = 0; j < 6; j++) {
      int idx = tid + j * 256;
      kpm[idx] = (idx < Sn) ? (1.f - am[b * Sn + idx]) * -10000.f : -1e30f;
    }
    *(int4*)&kls[r0][c80] = k0v;
    *(int4*)&kls[r1][c81] = k1v;
    *(int4*)&vls[r0][c80] = v0v;
    *(int4*)&vls[r1][c81] = v1v;
  }
  __syncthreads();

  float m = -3.0e38f, l = 0.f;
  f32x4 accO[4];
  f32x4 zr; zr[0] = 0.f; zr[1] = 0.f; zr[2] = 0.f; zr[3] = 0.f;
#pragma unroll
  for (int i = 0; i < 4; i++) accO[i] = zr;

  for (int kt = 0; kt < 24; kt++) {
    const int k0 = kt * 64;
    // issue next tile's K/V loads into regs (overlap with compute below)
    int4 krn0, krn1, vrn0, vrn1;
    if (kt < 23) {
      const int k0n = k0 + 64;
      krn0 = *(const int4*)(kg0 + (size_t)k0n * 3072);
      krn1 = *(const int4*)(kg1 + (size_t)k0n * 3072);
      vrn0 = *(const int4*)(vg0 + k0n);
      vrn1 = *(const int4*)(vg1 + k0n);
    }
    // prefetch pos_bias for current tile (before QK^T)
    float4 pbv[4];
    if (kt < 23) {
#pragma unroll
      for (int km = 0; km < 4; km++)
        pbv[km] = *(const float4*)(pbrow + k0 + km * 16 + g4 * 4);
    } else {
#pragma unroll
      for (int km = 0; km < 4; km++) {
        int kk = k0 + km * 16 + g4 * 4;
        pbv[km].x = (kk + 0 < Sn) ? pbrow[kk + 0] : 0.f;
        pbv[km].y = (kk + 1 < Sn) ? pbrow[kk + 1] : 0.f;
        pbv[km].z = (kk + 2 < Sn) ? pbrow[kk + 2] : 0.f;
        pbv[km].w = (kk + 3 < Sn) ? pbrow[kk + 3] : 0.f;
      }
    }

    // QK^T (swapped): A = K rows from LDS, B = Q regs
    f32x4 sAcc[4];
#pragma unroll
    for (int km = 0; km < 4; km++) {
      sAcc[km] = zr;
#pragma unroll
      for (int dc = 0; dc < 2; dc++) {
        bf16x8 af = *(const bf16x8*)&kls[km * 16 + l15][dc * 32 + g4 * 8];
        sAcc[km] = __builtin_amdgcn_mfma_f32_16x16x32_bf16(af, qf[dc], sAcc[km], 0, 0, 0);
      }
    }

    float sc[16];
#pragma unroll
    for (int km = 0; km < 4; km++) {
      int kk = k0 + km * 16 + g4 * 4;
      float4 kp = *(const float4*)&kpm[kk];
      sc[km * 4 + 0] = sAcc[km][0] * 0.125f + gr * pbv[km].x + kp.x;
      sc[km * 4 + 1] = sAcc[km][1] * 0.125f + gr * pbv[km].y + kp.y;
      sc[km * 4 + 2] = sAcc[km][2] * 0.125f + gr * pbv[km].z + kp.z;
      sc[km * 4 + 3] = sAcc[km][3] * 0.125f + gr * pbv[km].w + kp.w;
    }

    float mloc = sc[0];
#pragma unroll
    for (int i = 1; i < 16; i++) mloc = fmaxf(mloc, sc[i]);
    mloc = fmaxf(mloc, __shfl_xor(mloc, 16));
    mloc = fmaxf(mloc, __shfl_xor(mloc, 32));

    if (mloc > m + 8.f) {
      float corr = __expf(m - mloc);
      m = mloc;
      l *= corr;
#pragma unroll
      for (int i = 0; i < 4; i++) {
        accO[i][0] *= corr; accO[i][1] *= corr;
        accO[i][2] *= corr; accO[i][3] *= corr;
      }
    }

    float ls = 0.f;
#pragma unroll
    for (int i = 0; i < 16; i++) {
      float p = __expf(sc[i] - m);
      sc[i] = p;
      ls += p;
    }
    ls += __shfl_xor(ls, 16);
    ls += __shfl_xor(ls, 32);
    l += ls;

#pragma unroll
    for (int km = 0; km < 4; km++) {
      u32 lo = (u32)f2bu(sc[km * 4 + 0]) | ((u32)f2bu(sc[km * 4 + 1]) << 16);
      u32 hi = (u32)f2bu(sc[km * 4 + 2]) | ((u32)f2bu(sc[km * 4 + 3]) << 16);
      u32* dst = (u32*)&pls[wid][l15][km * 16 + g4 * 4];
      dst[0] = lo; dst[1] = hi;
    }

    bf16x8 pf[2];
    pf[0] = *(const bf16x8*)&pls[wid][l15][g4 * 8];
    pf[1] = *(const bf16x8*)&pls[wid][l15][32 + g4 * 8];
#pragma unroll
    for (int dm = 0; dm < 4; dm++) {
#pragma unroll
      for (int kc = 0; kc < 2; kc++) {
        bf16x8 af = *(const bf16x8*)&vls[dm * 16 + l15][kc * 32 + g4 * 8];
        accO[dm] = __builtin_amdgcn_mfma_f32_16x16x32_bf16(af, pf[kc], accO[dm], 0, 0, 0);
      }
    }

    // swap in the prefetched tile
    __syncthreads();
    if (kt < 23) {
      *(int4*)&kls[r0][c80] = krn0;
      *(int4*)&kls[r1][c81] = krn1;
      *(int4*)&vls[r0][c80] = vrn0;
      *(int4*)&vls[r1][c81] = vrn1;
      __syncthreads();
    }
  }

  float inv = 1.f / l;
  const bool qv = q < Sn;
#pragma unroll
  for (int dm = 0; dm < 4; dm++) {
    ushort4 st;
    st.x = f2bu(qv ? accO[dm][0] * inv : 0.f);
    st.y = f2bu(qv ? accO[dm][1] * inv : 0.f);
    st.z = f2bu(qv ? accO[dm][2] * inv : 0.f);
    st.w = f2bu(qv ? accO[dm][3] * inv : 0.f);
    *(ushort4*)(ctx + ((size_t)b * SPn + q) * Cn + h * 64 + dm * 16 + g4 * 4) = st;
  }
}

// ---------------- fused 3-way residual (f32 + bf16 + bf16) + LayerNorm over C ----------------
__global__ __launch_bounds__(256) void k_ln3(
    const float* __restrict__ r1, const u16* __restrict__ r2,
    const u16* __restrict__ r3,
    const float* __restrict__ g, const float* __restrict__ be,
    float* __restrict__ outF, u16* __restrict__ outB)
{
  const int s = blockIdx.x, b = blockIdx.y;
  const size_t base = ((size_t)b * SPn + s) * Cn;
  __shared__ float red[8];
  const int tid = threadIdx.x;
  const int c = tid * 4;
  float4 a = *(const float4*)(r1 + base + c);
  ushort4 v2 = *(const ushort4*)(r2 + base + c);
  ushort4 v3 = *(const ushort4*)(r3 + base + c);
  float t0 = a.x + bu2f(v2.x) + bu2f(v3.x);
  float t1 = a.y + bu2f(v2.y) + bu2f(v3.y);
  float t2 = a.z + bu2f(v2.z) + bu2f(v3.z);
  float t3 = a.w + bu2f(v2.w) + bu2f(v3.w);
  float sum = t0 + t1 + t2 + t3;
#pragma unroll
  for (int mk = 1; mk < 64; mk <<= 1) sum += __shfl_xor(sum, mk);
  if ((tid & 63) == 0) red[tid >> 6] = sum;
  __syncthreads();
  float mu = (red[0] + red[1] + red[2] + red[3]) * (1.f / Cn);
  float d0 = t0 - mu, d1 = t1 - mu, d2 = t2 - mu, d3 = t3 - mu;
  float vs = d0 * d0 + d1 * d1 + d2 * d2 + d3 * d3;
#pragma unroll
  for (int mk = 1; mk < 64; mk <<= 1) vs += __shfl_xor(vs, mk);
  if ((tid & 63) == 0) red[4 + (tid >> 6)] = vs;
  __syncthreads();
  float var = (red[4] + red[5] + red[6] + red[7]) * (1.f / Cn);
  float rstd = rsqrtf(var + 1e-5f);
  float4 gv = *(const float4*)(g + c);
  float4 bv = *(const float4*)(be + c);
  float o0 = d0 * rstd * gv.x + bv.x;
  float o1 = d1 * rstd * gv.y + bv.y;
  float o2 = d2 * rstd * gv.z + bv.z;
  float o3 = d3 * rstd * gv.w + bv.w;
  float4 st; st.x = o0; st.y = o1; st.z = o2; st.w = o3;
  *(float4*)(outF + base + c) = st;
  if (outB) {
    ushort4 sb;
    sb.x = f2bu(o0); sb.y = f2bu(o1); sb.z = f2bu(o2); sb.w = f2bu(o3);
    *(ushort4*)(outB + base + c) = sb;
  }
}

extern "C" void kernel_launch(void* const* d_in, const int* in_sizes, int n_in,
                              void* d_out, int out_size, void* d_ws, size_t ws_size,
                              hipStream_t stream)
{
  const float* x    = (const float*)d_in[0];
  const float* am   = (const float*)d_in[1];
  const float* pb   = (const float*)d_in[2];
  const float* Wq   = (const float*)d_in[3];
  const float* bq   = (const float*)d_in[4];
  const float* Wk   = (const float*)d_in[5];
  const float* bk   = (const float*)d_in[6];
  const float* Wv   = (const float*)d_in[7];
  const float* bv   = (const float*)d_in[8];
  const float* Wo   = (const float*)d_in[9];
  const float* bo   = (const float*)d_in[10];
  const float* Wg   = (const float*)d_in[11];
  const float* bg   = (const float*)d_in[12];
  const float* gc   = (const float*)d_in[13];
  const float* ln1g = (const float*)d_in[14];
  const float* ln1b = (const float*)d_in[15];
  const float* W1   = (const float*)d_in[16];
  const float* b1   = (const float*)d_in[17];
  const float* W2   = (const float*)d_in[18];
  const float* b2   = (const float*)d_in[19];
  const float* ln2g = (const float*)d_in[20];
  const float* ln2b = (const float*)d_in[21];

  // workspace arena (94,580,736 bytes; lifetime-aliased)
  char* ws = (char*)d_ws;
  float* xT     = (float*)(ws + 0);            // [pre .. LN1]
  u16*   xTb    = (u16*)(ws + 12582912);       // [pre .. QKV] -> ctxT [flash..Wo]
  u16*   wqkvb  = (u16*)(ws + 18874368);       // [pre .. QKV] -> hTb [LN1..FFN1]
  u16*   wob    = (u16*)(ws + 25165824);
  u16*   w1b    = (u16*)(ws + 27262976);
  u16*   w2b    = (u16*)(ws + 35651584);
  float* bqkv   = (float*)(ws + 44040192);
  float* gate   = (float*)(ws + 44052480);
  u16*   qkvB   = (u16*)(ws + 44249088);       // [QKV .. flash]; then hT f32 [LN1..LN2]
  u16*   vT     = (u16*)(ws + 63123456);       // [QKV .. flash]
  u16*   attnTa = (u16*)(ws + 69414912);       // [Wo .. LN1] bf16
  u16*   attnTb = (u16*)(ws + 81997824);       // [Wo .. LN1] bf16
  u16*   ctxT   = xTb;
  float* hT     = (float*)(ws + 44249088);
  u16*   hTb    = wqkvb;
  u16*   fT     = (u16*)(ws + 56832000);       // [FFN1 .. FFN2]
  u16*   f2Ta   = (u16*)(ws + 0);              // [FFN2 .. LN2] bf16
  u16*   f2Tb   = (u16*)(ws + 81997824);       // [FFN2 .. LN2] bf16
  float* outT   = (float*)(ws + 12582912);     // [LN2 .. t_out]

  dim3 blk(256);
  k_pre<<<dim3(15555), blk, 0, stream>>>(x, Wq, Wk, Wv, Wo, W1, W2, bq, bk, bv,
                                         Wg, bg, gc, xT, xTb, wqkvb, wob, w1b,
                                         w2b, bqkv, gate);

  // QKV projection -> bf16 (+fused V^T): M=3072, K=1024, TM=96 -> 768 blocks
  k_gemm<2, 1, 96><<<dim3(32, 12, Bn), blk, 0, stream>>>(
      wqkvb, xTb, bqkv, qkvB, qkvB, vT, 3072, 1024, 1024);
  // MFMA flash attention (768 blocks)
  k_flash_mfma<<<dim3(SPn / 64, Bn * Hn), blk, 0, stream>>>(qkvB, vT, pb, am, gate, ctxT);
  // Wo: M=1024, K=1024, TM=64, split-K=2 -> 768 blocks, bf16 partials
  k_gemm<2, 2, 64><<<dim3(16, 12, Bn * 2), blk, 0, stream>>>(
      wob, ctxT, bo, attnTa, attnTb, (u16*)nullptr, 1024, 1024, 1024);
  // LN1 = LN(x + attnA + attnB) -> hT (f32) + hTb (bf16)
  k_ln3<<<dim3(SPn, Bn), blk, 0, stream>>>(xT, attnTa, attnTb, ln1g, ln1b, hT, hTb);
  // FFN1 + gelu -> fT (bf16): M=4096, K=1024, TM=128 -> 768 blocks
  k_gemm<1, 1, 128><<<dim3(32, 12, Bn), blk, 0, stream>>>(
      w1b, hTb, b1, fT, fT, (u16*)nullptr, 4096, 1024, 1024);
  // FFN2: M=1024, K=4096, TM=64, split-K=2 -> 768 blocks, bf16 partials
  k_gemm<2, 2, 64><<<dim3(16, 12, Bn * 2), blk, 0, stream>>>(
      w2b, fT, b2, f2Ta, f2Tb, (u16*)nullptr, 1024, 4096, 4096);
  // LN2 = LN(h + f2a + f2b) -> outT
  k_ln3<<<dim3(SPn, Bn), blk, 0, stream>>>(hT, f2Ta, f2Tb, ln2g, ln2b, outT, (u16*)nullptr);
  // back to (B,C,1,S)
  k_transpose_out<<<dim3(Cn / 32, SPn / 32, Bn), blk, 0, stream>>>(outT, (float*)d_out);
}

// Round 8
// 267.283 us; speedup vs baseline: 3.3625x; 1.0013x over previous
//
#include <hip/hip_runtime.h>
#include <cstddef>
#include <cstdint>

#define Bn 2
#define Sn 1500
#define SPn 1536
#define Cn 1024
#define Hn 16
#define FFn 4096

typedef __attribute__((ext_vector_type(8))) short bf16x8;
typedef __attribute__((ext_vector_type(4))) float f32x4;
typedef unsigned short u16;
typedef unsigned int u32;

__device__ __forceinline__ u16 f2bu(float f) {
  unsigned u = __float_as_uint(f);
  return (u16)((u + 0x7fffu + ((u >> 16) & 1u)) >> 16);
}
__device__ __forceinline__ float bu2f(u16 v) {
  return __uint_as_float(((u32)v) << 16);
}

// async global->LDS, 16B per lane. LDS dest = wave-uniform base + lane*16.
__device__ __forceinline__ void gl_lds16(const u16* g, u16* l) {
  __builtin_amdgcn_global_load_lds(
      (__attribute__((address_space(1))) void*)(uintptr_t)g,
      (__attribute__((address_space(3))) void*)(u32)(uintptr_t)l,
      16, 0, 0);
}

// ---------------- fused preamble: transpose_in + weight prep + gate ----------------
__global__ __launch_bounds__(256) void k_pre(
    const float* __restrict__ x,
    const float* __restrict__ Wq, const float* __restrict__ Wk,
    const float* __restrict__ Wv, const float* __restrict__ Wo,
    const float* __restrict__ W1, const float* __restrict__ W2,
    const float* __restrict__ bq, const float* __restrict__ bk,
    const float* __restrict__ bv,
    const float* __restrict__ Wg, const float* __restrict__ bg,
    const float* __restrict__ gc,
    float* __restrict__ xT, u16* __restrict__ xTb,
    u16* __restrict__ wqkvb, u16* __restrict__ wob,
    u16* __restrict__ w1b, u16* __restrict__ w2b, float* __restrict__ bqkv,
    float* __restrict__ gate)
{
  const int bid = blockIdx.x;
  if (bid < 3072) {
    __shared__ float t[32][33];
    const int c0 = (bid & 31) * 32, s0 = ((bid >> 5) % 48) * 32, b = bid / 1536;
    const int tx = threadIdx.x & 31, ty = threadIdx.x >> 5;
#pragma unroll
    for (int i = 0; i < 32; i += 8) {
      int c = c0 + ty + i, s = s0 + tx;
      t[ty + i][tx] = (s < Sn) ? x[((size_t)b * Cn + c) * Sn + s] : 0.f;
    }
    __syncthreads();
#pragma unroll
    for (int i = 0; i < 32; i += 8) {
      int s = s0 + ty + i, c = c0 + tx;
      float v = t[tx][ty + i];
      size_t o = ((size_t)b * SPn + s) * Cn + c;
      xT[o] = v;
      xTb[o] = f2bu(v);
    }
    return;
  }
  if (bid < 15363) {
    int i = (bid - 3072) * 256 + threadIdx.x;
    const float* src;
    u16* dst;
    int j;
    if (i < 786432) {
      src = (i < 262144) ? Wq : ((i < 524288) ? Wk : Wv);
      j = i & 262143;
      dst = wqkvb + (size_t)i * 4;
    } else if (i < 1048576) {
      src = Wo; j = i - 786432; dst = wob + (size_t)j * 4;
    } else if (i < 2097152) {
      src = W1; j = i - 1048576; dst = w1b + (size_t)j * 4;
    } else if (i < 3145728) {
      src = W2; j = i - 2097152; dst = w2b + (size_t)j * 4;
    } else {
      int k = i - 3145728;
      const float* bsrc = (k < 256) ? bq : ((k < 512) ? bk : bv);
      float4 v = *(const float4*)(bsrc + (k & 255) * 4);
      *(float4*)(bqkv + k * 4) = v;
      return;
    }
    float4 v = *(const float4*)(src + (size_t)j * 4);
    ushort4 o;
    o.x = f2bu(v.x); o.y = f2bu(v.y); o.z = f2bu(v.z); o.w = f2bu(v.w);
    *(ushort4*)dst = o;
    return;
  }
  {
    const int gid = bid - 15363;
    const int b = gid / 96, h = (gid / 6) & 15;
    const int s = (gid % 6) * 256 + threadIdx.x;
    const bool vld = s < Sn;
    const float* xp = x + ((size_t)b * Cn + h * 64) * Sn + (vld ? s : 0);
    float dot[8];
#pragma unroll
    for (int o = 0; o < 8; o++) dot[o] = 0.f;
    for (int d = 0; d < 64; d++) {
      float v = xp[(size_t)d * Sn];
#pragma unroll
      for (int o = 0; o < 8; o++) dot[o] += Wg[o * 64 + d] * v;
    }
    float sa = dot[0] + dot[1] + dot[2] + dot[3] + bg[0] + bg[1] + bg[2] + bg[3];
    float sb = dot[4] + dot[5] + dot[6] + dot[7] + bg[4] + bg[5] + bg[6] + bg[7];
    float ga = 1.f / (1.f + __expf(-sa));
    float gb = 1.f / (1.f + __expf(-sb));
    float gv = ga * (gb * gc[h] - 1.f) + 2.f;
    gate[((size_t)b * Hn + h) * SPn + s] = vld ? gv : 0.f;
  }
}

// ---------------- transpose output: outT (B,SP,C) -> out (B,C,S) ----------------
__global__ __launch_bounds__(256) void k_transpose_out(
    const float* __restrict__ oT, float* __restrict__ o)
{
  __shared__ float t[32][33];
  const int b = blockIdx.z, c0 = blockIdx.x * 32, s0 = blockIdx.y * 32;
  const int tx = threadIdx.x & 31, ty = threadIdx.x >> 5;
#pragma unroll
  for (int i = 0; i < 32; i += 8) {
    int s = s0 + ty + i, c = c0 + tx;
    t[ty + i][tx] = oT[((size_t)b * SPn + s) * Cn + c];
  }
  __syncthreads();
#pragma unroll
  for (int i = 0; i < 32; i += 8) {
    int c = c0 + ty + i, s = s0 + tx;
    if (s < Sn) o[((size_t)b * Cn + c) * Sn + s] = t[tx][ty + i];
  }
}

// ---------------- bf16 MFMA GEMM, BK=64, global_load_lds staging, tile TM x 128 ----------------
// EPI: 0 = f32 out, 1 = gelu -> bf16, 2 = bf16 out (+ optional V-part scatter to vT)
template <int EPI, int SPLIT, int TM>
__global__ __launch_bounds__(256) void k_gemm(
    const u16* __restrict__ A, const u16* __restrict__ X,
    const float* __restrict__ bias, void* __restrict__ out, void* __restrict__ out2,
    u16* __restrict__ vT, int M, int Kst, int Ktot)
{
  constexpr int NI = TM / 32;
  const int zz = blockIdx.z;
  const int b = zz / SPLIT, half = zz % SPLIT;
  const int Kc = Ktot / SPLIT;
  const int m0 = blockIdx.x * TM;
  const int s0 = blockIdx.y * 128;
  const int tid = threadIdx.x;
  const int lane = tid & 63;
  const int wid = tid >> 6;
  const int wm = (wid >> 1) * (TM / 2);
  const int wn = (wid & 1) * 64;
  const int l15 = lane & 15;
  const int g4 = lane >> 4;

  __shared__ __align__(16) u16 lA[TM][64];
  __shared__ __align__(16) u16 lX[128][64];

  f32x4 acc[NI][4];
  f32x4 zr; zr[0] = 0.f; zr[1] = 0.f; zr[2] = 0.f; zr[3] = 0.f;
#pragma unroll
  for (int i = 0; i < NI; i++)
#pragma unroll
    for (int j = 0; j < 4; j++) acc[i][j] = zr;

  const int rlo = lane >> 3;
  const int cg = (lane & 7) ^ rlo;
  const int kbeg = half * Kc;
  const u16* gA = A + (size_t)(m0 + wid * (TM / 4) + rlo) * Kst + cg * 8 + kbeg;
  const u16* gX = X + ((size_t)b * SPn + s0 + wid * 32 + rlo) * Kst + cg * 8 + kbeg;
  u16* lAp = &lA[0][0] + wid * (TM / 4) * 64;
  u16* lXp = &lX[0][0] + wid * 2048;
  const size_t rstep8 = (size_t)8 * Kst;

  for (int kt = 0; kt < Kc; kt += 64) {
    __syncthreads();
#pragma unroll
    for (int j = 0; j < TM / 32; j++)
      gl_lds16(gA + j * rstep8 + kt, lAp + j * 512);
#pragma unroll
    for (int j = 0; j < 4; j++)
      gl_lds16(gX + j * rstep8 + kt, lXp + j * 512);
    __syncthreads();
#pragma unroll
    for (int ks = 0; ks < 2; ks++) {
      bf16x8 af[NI], bfr[4];
#pragma unroll
      for (int i = 0; i < NI; i++) {
        int ra = wm + i * 16 + l15;
        af[i] = *(const bf16x8*)&lA[ra][((ks * 4 + g4) ^ (ra & 7)) * 8];
      }
#pragma unroll
      for (int j = 0; j < 4; j++) {
        int rb = wn + j * 16 + l15;
        bfr[j] = *(const bf16x8*)&lX[rb][((ks * 4 + g4) ^ (rb & 7)) * 8];
      }
#pragma unroll
      for (int i = 0; i < NI; i++)
#pragma unroll
        for (int j = 0; j < 4; j++)
          acc[i][j] = __builtin_amdgcn_mfma_f32_16x16x32_bf16(af[i], bfr[j], acc[i][j], 0, 0, 0);
    }
  }

  const float hsc = (half == 0) ? 1.f : 0.f;
  void* outp = (half == 0) ? out : out2;
#pragma unroll
  for (int i = 0; i < NI; i++) {
    int o = m0 + wm + i * 16 + g4 * 4;
    float4 bs = *(const float4*)(bias + o);
#pragma unroll
    for (int j = 0; j < 4; j++) {
      int s = s0 + wn + j * 16 + l15;
      size_t oidx = ((size_t)b * SPn + s) * M + o;
      f32x4 v = acc[i][j];
      float x0 = v[0] + bs.x * hsc, x1 = v[1] + bs.y * hsc;
      float x2 = v[2] + bs.z * hsc, x3 = v[3] + bs.w * hsc;
      if (EPI == 0) {
        float4 st; st.x = x0; st.y = x1; st.z = x2; st.w = x3;
        *(float4*)((float*)outp + oidx) = st;
      } else if (EPI == 1) {
        x0 = 0.5f * x0 * (1.f + erff(x0 * 0.70710678118654752f));
        x1 = 0.5f * x1 * (1.f + erff(x1 * 0.70710678118654752f));
        x2 = 0.5f * x2 * (1.f + erff(x2 * 0.70710678118654752f));
        x3 = 0.5f * x3 * (1.f + erff(x3 * 0.70710678118654752f));
        ushort4 st;
        st.x = f2bu(x0); st.y = f2bu(x1); st.z = f2bu(x2); st.w = f2bu(x3);
        *(ushort4*)((u16*)outp + oidx) = st;
      } else {
        ushort4 st;
        st.x = f2bu(x0); st.y = f2bu(x1); st.z = f2bu(x2); st.w = f2bu(x3);
        *(ushort4*)((u16*)outp + oidx) = st;
        if (vT != nullptr && o >= 2048) {
          int oo = o - 2048;
          int h = oo >> 6, d = oo & 63;
          u16* vp = vT + ((size_t)(b * Hn + h) * 64 + d) * SPn + s;
          vp[0] = st.x;
          vp[SPn] = st.y;
          vp[2 * SPn] = st.z;
          vp[3 * SPn] = st.w;
        }
      }
    }
  }
}

// ---------------- MFMA flash attention, T14 async-stage + pb prefetch pipeline ----------------
__global__ __launch_bounds__(256) void k_flash_mfma(
    const u16* __restrict__ qkv,    // [B][SP][3072] bf16 (Q|K|V)
    const u16* __restrict__ vT,     // [BH][64][SP] bf16
    const float* __restrict__ pb,   // [BH][S][S] f32
    const float* __restrict__ am,   // [B][S]
    const float* __restrict__ gate, // [BH][SP]
    u16* __restrict__ ctx)          // [B][SP][C] bf16
{
  const int bh = blockIdx.y, b = bh >> 4, h = bh & 15;
  const int q0 = blockIdx.x * 64;
  const int tid = threadIdx.x;
  const int lane = tid & 63, wid = tid >> 6;
  const int l15 = lane & 15, g4 = lane >> 4;
  const int q = q0 + wid * 16 + l15;

  __shared__ __align__(16) u16 kls[64][72];
  __shared__ __align__(16) u16 vls[64][72];
  __shared__ __align__(16) u16 pls[4][16][72];
  __shared__ float kpm[SPn];

  // staging geometry (per thread, i in {0,1})
  const int r0 = tid >> 3, c80 = (tid & 7) * 8;
  const int r1 = (256 + tid) >> 3, c81 = c80;
  const u16* kg0 = qkv + ((size_t)b * SPn + r0) * 3072 + 1024 + h * 64 + c80;
  const u16* kg1 = qkv + ((size_t)b * SPn + r1) * 3072 + 1024 + h * 64 + c81;
  const u16* vg0 = vT + ((size_t)bh * 64 + r0) * SPn + c80;
  const u16* vg1 = vT + ((size_t)bh * 64 + r1) * SPn + c81;

  // Q fragment + gate
  bf16x8 qf[2];
  {
    const u16* qp = qkv + ((size_t)b * SPn + q) * 3072 + h * 64 + g4 * 8;
    qf[0] = *(const bf16x8*)qp;
    qf[1] = *(const bf16x8*)(qp + 32);
  }
  const float gr = gate[(size_t)bh * SPn + q];
  const int qpb = (q < Sn) ? q : (Sn - 1);
  const float* pbrow = pb + ((size_t)bh * Sn + qpb) * Sn;

  // prologue: stage tile 0 + kpm + pb(tile 0), single barrier
  float4 pbv[4];
  {
    int4 k0v = *(const int4*)kg0;
    int4 k1v = *(const int4*)kg1;
    int4 v0v = *(const int4*)vg0;
    int4 v1v = *(const int4*)vg1;
#pragma unroll
    for (int km = 0; km < 4; km++)
      pbv[km] = *(const float4*)(pbrow + km * 16 + g4 * 4);
#pragma unroll
    for (int j = 0; j < 6; j++) {
      int idx = tid + j * 256;
      kpm[idx] = (idx < Sn) ? (1.f - am[b * Sn + idx]) * -10000.f : -1e30f;
    }
    *(int4*)&kls[r0][c80] = k0v;
    *(int4*)&kls[r1][c81] = k1v;
    *(int4*)&vls[r0][c80] = v0v;
    *(int4*)&vls[r1][c81] = v1v;
  }
  __syncthreads();

  float m = -3.0e38f, l = 0.f;
  f32x4 accO[4];
  f32x4 zr; zr[0] = 0.f; zr[1] = 0.f; zr[2] = 0.f; zr[3] = 0.f;
#pragma unroll
  for (int i = 0; i < 4; i++) accO[i] = zr;

  for (int kt = 0; kt < 24; kt++) {
    const int k0 = kt * 64;
    // issue next tile's K/V loads into regs (overlap with compute below)
    int4 krn0, krn1, vrn0, vrn1;
    float4 pbn[4];
    if (kt < 23) {
      const int k0n = k0 + 64;
      krn0 = *(const int4*)(kg0 + (size_t)k0n * 3072);
      krn1 = *(const int4*)(kg1 + (size_t)k0n * 3072);
      vrn0 = *(const int4*)(vg0 + k0n);
      vrn1 = *(const int4*)(vg1 + k0n);
      // prefetch next tile's pos_bias (consumed next iteration)
      if (kt < 22) {
#pragma unroll
        for (int km = 0; km < 4; km++)
          pbn[km] = *(const float4*)(pbrow + k0n + km * 16 + g4 * 4);
      } else {  // next tile is the guarded tail (kt+1 == 23)
#pragma unroll
        for (int km = 0; km < 4; km++) {
          int kk = k0n + km * 16 + g4 * 4;
          pbn[km].x = (kk + 0 < Sn) ? pbrow[kk + 0] : 0.f;
          pbn[km].y = (kk + 1 < Sn) ? pbrow[kk + 1] : 0.f;
          pbn[km].z = (kk + 2 < Sn) ? pbrow[kk + 2] : 0.f;
          pbn[km].w = (kk + 3 < Sn) ? pbrow[kk + 3] : 0.f;
        }
      }
    }

    // QK^T (swapped): A = K rows from LDS, B = Q regs
    f32x4 sAcc[4];
    __builtin_amdgcn_s_setprio(1);
#pragma unroll
    for (int km = 0; km < 4; km++) {
      sAcc[km] = zr;
#pragma unroll
      for (int dc = 0; dc < 2; dc++) {
        bf16x8 af = *(const bf16x8*)&kls[km * 16 + l15][dc * 32 + g4 * 8];
        sAcc[km] = __builtin_amdgcn_mfma_f32_16x16x32_bf16(af, qf[dc], sAcc[km], 0, 0, 0);
      }
    }
    __builtin_amdgcn_s_setprio(0);

    float sc[16];
#pragma unroll
    for (int km = 0; km < 4; km++) {
      int kk = k0 + km * 16 + g4 * 4;
      float4 kp = *(const float4*)&kpm[kk];
      sc[km * 4 + 0] = sAcc[km][0] * 0.125f + gr * pbv[km].x + kp.x;
      sc[km * 4 + 1] = sAcc[km][1] * 0.125f + gr * pbv[km].y + kp.y;
      sc[km * 4 + 2] = sAcc[km][2] * 0.125f + gr * pbv[km].z + kp.z;
      sc[km * 4 + 3] = sAcc[km][3] * 0.125f + gr * pbv[km].w + kp.w;
    }

    float mloc = sc[0];
#pragma unroll
    for (int i = 1; i < 16; i++) mloc = fmaxf(mloc, sc[i]);
    mloc = fmaxf(mloc, __shfl_xor(mloc, 16));
    mloc = fmaxf(mloc, __shfl_xor(mloc, 32));

    if (mloc > m + 8.f) {
      float corr = __expf(m - mloc);
      m = mloc;
      l *= corr;
#pragma unroll
      for (int i = 0; i < 4; i++) {
        accO[i][0] *= corr; accO[i][1] *= corr;
        accO[i][2] *= corr; accO[i][3] *= corr;
      }
    }

    float ls = 0.f;
#pragma unroll
    for (int i = 0; i < 16; i++) {
      float p = __expf(sc[i] - m);
      sc[i] = p;
      ls += p;
    }
    ls += __shfl_xor(ls, 16);
    ls += __shfl_xor(ls, 32);
    l += ls;

#pragma unroll
    for (int km = 0; km < 4; km++) {
      u32 lo = (u32)f2bu(sc[km * 4 + 0]) | ((u32)f2bu(sc[km * 4 + 1]) << 16);
      u32 hi = (u32)f2bu(sc[km * 4 + 2]) | ((u32)f2bu(sc[km * 4 + 3]) << 16);
      u32* dst = (u32*)&pls[wid][l15][km * 16 + g4 * 4];
      dst[0] = lo; dst[1] = hi;
    }

    bf16x8 pf[2];
    pf[0] = *(const bf16x8*)&pls[wid][l15][g4 * 8];
    pf[1] = *(const bf16x8*)&pls[wid][l15][32 + g4 * 8];
    __builtin_amdgcn_s_setprio(1);
#pragma unroll
    for (int dm = 0; dm < 4; dm++) {
#pragma unroll
      for (int kc = 0; kc < 2; kc++) {
        bf16x8 af = *(const bf16x8*)&vls[dm * 16 + l15][kc * 32 + g4 * 8];
        accO[dm] = __builtin_amdgcn_mfma_f32_16x16x32_bf16(af, pf[kc], accO[dm], 0, 0, 0);
      }
    }
    __builtin_amdgcn_s_setprio(0);

    // swap in the prefetched tile
    __syncthreads();
    if (kt < 23) {
      *(int4*)&kls[r0][c80] = krn0;
      *(int4*)&kls[r1][c81] = krn1;
      *(int4*)&vls[r0][c80] = vrn0;
      *(int4*)&vls[r1][c81] = vrn1;
#pragma unroll
      for (int km = 0; km < 4; km++) pbv[km] = pbn[km];
      __syncthreads();
    }
  }

  float inv = 1.f / l;
  const bool qv = q < Sn;
#pragma unroll
  for (int dm = 0; dm < 4; dm++) {
    ushort4 st;
    st.x = f2bu(qv ? accO[dm][0] * inv : 0.f);
    st.y = f2bu(qv ? accO[dm][1] * inv : 0.f);
    st.z = f2bu(qv ? accO[dm][2] * inv : 0.f);
    st.w = f2bu(qv ? accO[dm][3] * inv : 0.f);
    *(ushort4*)(ctx + ((size_t)b * SPn + q) * Cn + h * 64 + dm * 16 + g4 * 4) = st;
  }
}

// ---------------- fused 3-way residual (f32 + bf16 + bf16) + LayerNorm over C ----------------
__global__ __launch_bounds__(256) void k_ln3(
    const float* __restrict__ r1, const u16* __restrict__ r2,
    const u16* __restrict__ r3,
    const float* __restrict__ g, const float* __restrict__ be,
    float* __restrict__ outF, u16* __restrict__ outB)
{
  const int s = blockIdx.x, b = blockIdx.y;
  const size_t base = ((size_t)b * SPn + s) * Cn;
  __shared__ float red[8];
  const int tid = threadIdx.x;
  const int c = tid * 4;
  float4 a = *(const float4*)(r1 + base + c);
  ushort4 v2 = *(const ushort4*)(r2 + base + c);
  ushort4 v3 = *(const ushort4*)(r3 + base + c);
  float t0 = a.x + bu2f(v2.x) + bu2f(v3.x);
  float t1 = a.y + bu2f(v2.y) + bu2f(v3.y);
  float t2 = a.z + bu2f(v2.z) + bu2f(v3.z);
  float t3 = a.w + bu2f(v2.w) + bu2f(v3.w);
  float sum = t0 + t1 + t2 + t3;
#pragma unroll
  for (int mk = 1; mk < 64; mk <<= 1) sum += __shfl_xor(sum, mk);
  if ((tid & 63) == 0) red[tid >> 6] = sum;
  __syncthreads();
  float mu = (red[0] + red[1] + red[2] + red[3]) * (1.f / Cn);
  float d0 = t0 - mu, d1 = t1 - mu, d2 = t2 - mu, d3 = t3 - mu;
  float vs = d0 * d0 + d1 * d1 + d2 * d2 + d3 * d3;
#pragma unroll
  for (int mk = 1; mk < 64; mk <<= 1) vs += __shfl_xor(vs, mk);
  if ((tid & 63) == 0) red[4 + (tid >> 6)] = vs;
  __syncthreads();
  float var = (red[4] + red[5] + red[6] + red[7]) * (1.f / Cn);
  float rstd = rsqrtf(var + 1e-5f);
  float4 gv = *(const float4*)(g + c);
  float4 bv = *(const float4*)(be + c);
  float o0 = d0 * rstd * gv.x + bv.x;
  float o1 = d1 * rstd * gv.y + bv.y;
  float o2 = d2 * rstd * gv.z + bv.z;
  float o3 = d3 * rstd * gv.w + bv.w;
  float4 st; st.x = o0; st.y = o1; st.z = o2; st.w = o3;
  *(float4*)(outF + base + c) = st;
  if (outB) {
    ushort4 sb;
    sb.x = f2bu(o0); sb.y = f2bu(o1); sb.z = f2bu(o2); sb.w = f2bu(o3);
    *(ushort4*)(outB + base + c) = sb;
  }
}

extern "C" void kernel_launch(void* const* d_in, const int* in_sizes, int n_in,
                              void* d_out, int out_size, void* d_ws, size_t ws_size,
                              hipStream_t stream)
{
  const float* x    = (const float*)d_in[0];
  const float* am   = (const float*)d_in[1];
  const float* pb   = (const float*)d_in[2];
  const float* Wq   = (const float*)d_in[3];
  const float* bq   = (const float*)d_in[4];
  const float* Wk   = (const float*)d_in[5];
  const float* bk   = (const float*)d_in[6];
  const float* Wv   = (const float*)d_in[7];
  const float* bv   = (const float*)d_in[8];
  const float* Wo   = (const float*)d_in[9];
  const float* bo   = (const float*)d_in[10];
  const float* Wg   = (const float*)d_in[11];
  const float* bg   = (const float*)d_in[12];
  const float* gc   = (const float*)d_in[13];
  const float* ln1g = (const float*)d_in[14];
  const float* ln1b = (const float*)d_in[15];
  const float* W1   = (const float*)d_in[16];
  const float* b1   = (const float*)d_in[17];
  const float* W2   = (const float*)d_in[18];
  const float* b2   = (const float*)d_in[19];
  const float* ln2g = (const float*)d_in[20];
  const float* ln2b = (const float*)d_in[21];

  // workspace arena (94,580,736 bytes; lifetime-aliased)
  char* ws = (char*)d_ws;
  float* xT     = (float*)(ws + 0);            // [pre .. LN1]
  u16*   xTb    = (u16*)(ws + 12582912);       // [pre .. QKV] -> ctxT [flash..Wo]
  u16*   wqkvb  = (u16*)(ws + 18874368);       // [pre .. QKV] -> hTb [LN1..FFN1]
  u16*   wob    = (u16*)(ws + 25165824);
  u16*   w1b    = (u16*)(ws + 27262976);
  u16*   w2b    = (u16*)(ws + 35651584);
  float* bqkv   = (float*)(ws + 44040192);
  float* gate   = (float*)(ws + 44052480);
  u16*   qkvB   = (u16*)(ws + 44249088);       // [QKV .. flash]; then hT f32 [LN1..LN2]
  u16*   vT     = (u16*)(ws + 63123456);       // [QKV .. flash]
  u16*   attnTa = (u16*)(ws + 69414912);       // [Wo .. LN1] bf16
  u16*   attnTb = (u16*)(ws + 81997824);       // [Wo .. LN1] bf16
  u16*   ctxT   = xTb;
  float* hT     = (float*)(ws + 44249088);
  u16*   hTb    = wqkvb;
  u16*   fT     = (u16*)(ws + 56832000);       // [FFN1 .. FFN2]
  u16*   f2Ta   = (u16*)(ws + 0);              // [FFN2 .. LN2] bf16
  u16*   f2Tb   = (u16*)(ws + 81997824);       // [FFN2 .. LN2] bf16
  float* outT   = (float*)(ws + 12582912);     // [LN2 .. t_out]

  dim3 blk(256);
  k_pre<<<dim3(15555), blk, 0, stream>>>(x, Wq, Wk, Wv, Wo, W1, W2, bq, bk, bv,
                                         Wg, bg, gc, xT, xTb, wqkvb, wob, w1b,
                                         w2b, bqkv, gate);

  // QKV projection -> bf16 (+fused V^T): M=3072, K=1024, TM=96 -> 768 blocks
  k_gemm<2, 1, 96><<<dim3(32, 12, Bn), blk, 0, stream>>>(
      wqkvb, xTb, bqkv, qkvB, qkvB, vT, 3072, 1024, 1024);
  // MFMA flash attention (768 blocks)
  k_flash_mfma<<<dim3(SPn / 64, Bn * Hn), blk, 0, stream>>>(qkvB, vT, pb, am, gate, ctxT);
  // Wo: M=1024, K=1024, TM=64, split-K=2 -> 768 blocks, bf16 partials
  k_gemm<2, 2, 64><<<dim3(16, 12, Bn * 2), blk, 0, stream>>>(
      wob, ctxT, bo, attnTa, attnTb, (u16*)nullptr, 1024, 1024, 1024);
  // LN1 = LN(x + attnA + attnB) -> hT (f32) + hTb (bf16)
  k_ln3<<<dim3(SPn, Bn), blk, 0, stream>>>(xT, attnTa, attnTb, ln1g, ln1b, hT, hTb);
  // FFN1 + gelu -> fT (bf16): M=4096, K=1024, TM=128 -> 768 blocks
  k_gemm<1, 1, 128><<<dim3(32, 12, Bn), blk, 0, stream>>>(
      w1b, hTb, b1, fT, fT, (u16*)nullptr, 4096, 1024, 1024);
  // FFN2: M=1024, K=4096, TM=64, split-K=2 -> 768 blocks, bf16 partials
  k_gemm<2, 2, 64><<<dim3(16, 12, Bn * 2), blk, 0, stream>>>(
      w2b, fT, b2, f2Ta, f2Tb, (u16*)nullptr, 1024, 4096, 4096);
  // LN2 = LN(h + f2a + f2b) -> outT
  k_ln3<<<dim3(SPn, Bn), blk, 0, stream>>>(hT, f2Ta, f2Tb, ln2g, ln2b, outT, (u16*)nullptr);
  // back to (B,C,1,S)
  k_transpose_out<<<dim3(Cn / 32, SPn / 32, Bn), blk, 0, stream>>>(outT, (float*)d_out);
}

// Round 9
// 262.808 us; speedup vs baseline: 3.4198x; 1.0170x over previous
//
#include <hip/hip_runtime.h>
#include <cstddef>
#include <cstdint>

#define Bn 2
#define Sn 1500
#define SPn 1536
#define Cn 1024
#define Hn 16
#define FFn 4096

typedef __attribute__((ext_vector_type(8))) short bf16x8;
typedef __attribute__((ext_vector_type(4))) float f32x4;
typedef unsigned short u16;
typedef unsigned int u32;

__device__ __forceinline__ u16 f2bu(float f) {
  unsigned u = __float_as_uint(f);
  return (u16)((u + 0x7fffu + ((u >> 16) & 1u)) >> 16);
}
__device__ __forceinline__ float bu2f(u16 v) {
  return __uint_as_float(((u32)v) << 16);
}

// async global->LDS, 16B per lane. LDS dest = wave-uniform base + lane*16.
__device__ __forceinline__ void gl_lds16(const u16* g, u16* l) {
  __builtin_amdgcn_global_load_lds(
      (__attribute__((address_space(1))) void*)(uintptr_t)g,
      (__attribute__((address_space(3))) void*)(u32)(uintptr_t)l,
      16, 0, 0);
}

// ---------------- fused preamble: gate + transpose_in + weight prep ----------------
// segments (blockIdx.x):
//   [0,192)        gate (runs FIRST so its long-latency loop overlaps the bulk)
//   [192,3264)     transpose+cast x -> xT f32 + xTb bf16
//   [3264,15555)   weight casts + bias pack
__global__ __launch_bounds__(256) void k_pre(
    const float* __restrict__ x,
    const float* __restrict__ Wq, const float* __restrict__ Wk,
    const float* __restrict__ Wv, const float* __restrict__ Wo,
    const float* __restrict__ W1, const float* __restrict__ W2,
    const float* __restrict__ bq, const float* __restrict__ bk,
    const float* __restrict__ bv,
    const float* __restrict__ Wg, const float* __restrict__ bg,
    const float* __restrict__ gc,
    float* __restrict__ xT, u16* __restrict__ xTb,
    u16* __restrict__ wqkvb, u16* __restrict__ wob,
    u16* __restrict__ w1b, u16* __restrict__ w2b, float* __restrict__ bqkv,
    float* __restrict__ gate)
{
  const int bid = blockIdx.x;
  if (bid < 192) {
    // ---- gate ----
    const int gid = bid;
    const int b = gid / 96, h = (gid / 6) & 15;
    const int s = (gid % 6) * 256 + threadIdx.x;
    const bool vld = s < Sn;
    const float* xp = x + ((size_t)b * Cn + h * 64) * Sn + (vld ? s : 0);
    float dot[8];
#pragma unroll
    for (int o = 0; o < 8; o++) dot[o] = 0.f;
#pragma unroll 4
    for (int d = 0; d < 64; d++) {
      float v = xp[(size_t)d * Sn];
#pragma unroll
      for (int o = 0; o < 8; o++) dot[o] += Wg[o * 64 + d] * v;
    }
    float sa = dot[0] + dot[1] + dot[2] + dot[3] + bg[0] + bg[1] + bg[2] + bg[3];
    float sb = dot[4] + dot[5] + dot[6] + dot[7] + bg[4] + bg[5] + bg[6] + bg[7];
    float ga = 1.f / (1.f + __expf(-sa));
    float gb = 1.f / (1.f + __expf(-sb));
    float gv = ga * (gb * gc[h] - 1.f) + 2.f;
    gate[((size_t)b * Hn + h) * SPn + s] = vld ? gv : 0.f;
    return;
  }
  if (bid < 3264) {
    // ---- transpose + cast ----
    __shared__ float t[32][33];
    const int tb = bid - 192;
    const int c0 = (tb & 31) * 32, s0 = ((tb >> 5) % 48) * 32, b = tb / 1536;
    const int tx = threadIdx.x & 31, ty = threadIdx.x >> 5;
#pragma unroll
    for (int i = 0; i < 32; i += 8) {
      int c = c0 + ty + i, s = s0 + tx;
      t[ty + i][tx] = (s < Sn) ? x[((size_t)b * Cn + c) * Sn + s] : 0.f;
    }
    __syncthreads();
#pragma unroll
    for (int i = 0; i < 32; i += 8) {
      int s = s0 + ty + i, c = c0 + tx;
      float v = t[tx][ty + i];
      size_t o = ((size_t)b * SPn + s) * Cn + c;
      xT[o] = v;
      xTb[o] = f2bu(v);
    }
    return;
  }
  {
    // ---- weight cast / bias pack ----
    int i = (bid - 3264) * 256 + threadIdx.x;
    const float* src;
    u16* dst;
    int j;
    if (i < 786432) {
      src = (i < 262144) ? Wq : ((i < 524288) ? Wk : Wv);
      j = i & 262143;
      dst = wqkvb + (size_t)i * 4;
    } else if (i < 1048576) {
      src = Wo; j = i - 786432; dst = wob + (size_t)j * 4;
    } else if (i < 2097152) {
      src = W1; j = i - 1048576; dst = w1b + (size_t)j * 4;
    } else if (i < 3145728) {
      src = W2; j = i - 2097152; dst = w2b + (size_t)j * 4;
    } else {
      int k = i - 3145728;
      const float* bsrc = (k < 256) ? bq : ((k < 512) ? bk : bv);
      float4 v = *(const float4*)(bsrc + (k & 255) * 4);
      *(float4*)(bqkv + k * 4) = v;
      return;
    }
    float4 v = *(const float4*)(src + (size_t)j * 4);
    ushort4 o;
    o.x = f2bu(v.x); o.y = f2bu(v.y); o.z = f2bu(v.z); o.w = f2bu(v.w);
    *(ushort4*)dst = o;
  }
}

// ---------------- transpose output: outT (B,SP,C) -> out (B,C,S) ----------------
__global__ __launch_bounds__(256) void k_transpose_out(
    const float* __restrict__ oT, float* __restrict__ o)
{
  __shared__ float t[32][33];
  const int b = blockIdx.z, c0 = blockIdx.x * 32, s0 = blockIdx.y * 32;
  const int tx = threadIdx.x & 31, ty = threadIdx.x >> 5;
#pragma unroll
  for (int i = 0; i < 32; i += 8) {
    int s = s0 + ty + i, c = c0 + tx;
    t[ty + i][tx] = oT[((size_t)b * SPn + s) * Cn + c];
  }
  __syncthreads();
#pragma unroll
  for (int i = 0; i < 32; i += 8) {
    int c = c0 + ty + i, s = s0 + tx;
    if (s < Sn) o[((size_t)b * Cn + c) * Sn + s] = t[tx][ty + i];
  }
}

// ---------------- bf16 MFMA GEMM, BK=64, global_load_lds staging, tile TM x 128 ----------------
// EPI: 0 = f32 out, 1 = gelu -> bf16, 2 = bf16 out (+ optional V-part scatter to vT,
//       in which case the V region is NOT written to the main output)
template <int EPI, int SPLIT, int TM>
__global__ __launch_bounds__(256) void k_gemm(
    const u16* __restrict__ A, const u16* __restrict__ X,
    const float* __restrict__ bias, void* __restrict__ out, void* __restrict__ out2,
    u16* __restrict__ vT, int M, int Kst, int Ktot)
{
  constexpr int NI = TM / 32;
  const int zz = blockIdx.z;
  const int b = zz / SPLIT, half = zz % SPLIT;
  const int Kc = Ktot / SPLIT;
  const int m0 = blockIdx.x * TM;
  const int s0 = blockIdx.y * 128;
  const int tid = threadIdx.x;
  const int lane = tid & 63;
  const int wid = tid >> 6;
  const int wm = (wid >> 1) * (TM / 2);
  const int wn = (wid & 1) * 64;
  const int l15 = lane & 15;
  const int g4 = lane >> 4;

  __shared__ __align__(16) u16 lA[TM][64];
  __shared__ __align__(16) u16 lX[128][64];

  f32x4 acc[NI][4];
  f32x4 zr; zr[0] = 0.f; zr[1] = 0.f; zr[2] = 0.f; zr[3] = 0.f;
#pragma unroll
  for (int i = 0; i < NI; i++)
#pragma unroll
    for (int j = 0; j < 4; j++) acc[i][j] = zr;

  const int rlo = lane >> 3;
  const int cg = (lane & 7) ^ rlo;
  const int kbeg = half * Kc;
  const u16* gA = A + (size_t)(m0 + wid * (TM / 4) + rlo) * Kst + cg * 8 + kbeg;
  const u16* gX = X + ((size_t)b * SPn + s0 + wid * 32 + rlo) * Kst + cg * 8 + kbeg;
  u16* lAp = &lA[0][0] + wid * (TM / 4) * 64;
  u16* lXp = &lX[0][0] + wid * 2048;
  const size_t rstep8 = (size_t)8 * Kst;

  for (int kt = 0; kt < Kc; kt += 64) {
    __syncthreads();
#pragma unroll
    for (int j = 0; j < TM / 32; j++)
      gl_lds16(gA + j * rstep8 + kt, lAp + j * 512);
#pragma unroll
    for (int j = 0; j < 4; j++)
      gl_lds16(gX + j * rstep8 + kt, lXp + j * 512);
    __syncthreads();
#pragma unroll
    for (int ks = 0; ks < 2; ks++) {
      bf16x8 af[NI], bfr[4];
#pragma unroll
      for (int i = 0; i < NI; i++) {
        int ra = wm + i * 16 + l15;
        af[i] = *(const bf16x8*)&lA[ra][((ks * 4 + g4) ^ (ra & 7)) * 8];
      }
#pragma unroll
      for (int j = 0; j < 4; j++) {
        int rb = wn + j * 16 + l15;
        bfr[j] = *(const bf16x8*)&lX[rb][((ks * 4 + g4) ^ (rb & 7)) * 8];
      }
#pragma unroll
      for (int i = 0; i < NI; i++)
#pragma unroll
        for (int j = 0; j < 4; j++)
          acc[i][j] = __builtin_amdgcn_mfma_f32_16x16x32_bf16(af[i], bfr[j], acc[i][j], 0, 0, 0);
    }
  }

  const float hsc = (half == 0) ? 1.f : 0.f;
  void* outp = (half == 0) ? out : out2;
#pragma unroll
  for (int i = 0; i < NI; i++) {
    int o = m0 + wm + i * 16 + g4 * 4;
    float4 bs = *(const float4*)(bias + o);
#pragma unroll
    for (int j = 0; j < 4; j++) {
      int s = s0 + wn + j * 16 + l15;
      size_t oidx = ((size_t)b * SPn + s) * M + o;
      f32x4 v = acc[i][j];
      float x0 = v[0] + bs.x * hsc, x1 = v[1] + bs.y * hsc;
      float x2 = v[2] + bs.z * hsc, x3 = v[3] + bs.w * hsc;
      if (EPI == 0) {
        float4 st; st.x = x0; st.y = x1; st.z = x2; st.w = x3;
        *(float4*)((float*)outp + oidx) = st;
      } else if (EPI == 1) {
        x0 = 0.5f * x0 * (1.f + erff(x0 * 0.70710678118654752f));
        x1 = 0.5f * x1 * (1.f + erff(x1 * 0.70710678118654752f));
        x2 = 0.5f * x2 * (1.f + erff(x2 * 0.70710678118654752f));
        x3 = 0.5f * x3 * (1.f + erff(x3 * 0.70710678118654752f));
        ushort4 st;
        st.x = f2bu(x0); st.y = f2bu(x1); st.z = f2bu(x2); st.w = f2bu(x3);
        *(ushort4*)((u16*)outp + oidx) = st;
      } else {
        ushort4 st;
        st.x = f2bu(x0); st.y = f2bu(x1); st.z = f2bu(x2); st.w = f2bu(x3);
        if (vT != nullptr && o >= 2048) {
          // V-part: write ONLY to vT[bh][d][s]
          int oo = o - 2048;
          int h = oo >> 6, d = oo & 63;
          u16* vp = vT + ((size_t)(b * Hn + h) * 64 + d) * SPn + s;
          vp[0] = st.x;
          vp[SPn] = st.y;
          vp[2 * SPn] = st.z;
          vp[3 * SPn] = st.w;
        } else {
          *(ushort4*)((u16*)outp + oidx) = st;
        }
      }
    }
  }
}

// ---------------- MFMA flash attention, T14 K/V pipeline + LDS-coalesced pb ----------------
__global__ __launch_bounds__(256) void k_flash_mfma(
    const u16* __restrict__ qkv,    // [B][SP][3072] bf16 (Q|K|-)
    const u16* __restrict__ vT,     // [BH][64][SP] bf16
    const float* __restrict__ pb,   // [BH][S][S] f32
    const float* __restrict__ am,   // [B][S]
    const float* __restrict__ gate, // [BH][SP]
    u16* __restrict__ ctx)          // [B][SP][C] bf16
{
  const int bh = blockIdx.y, b = bh >> 4, h = bh & 15;
  const int q0 = blockIdx.x * 64;
  const int tid = threadIdx.x;
  const int lane = tid & 63, wid = tid >> 6;
  const int l15 = lane & 15, g4 = lane >> 4;
  const int q = q0 + wid * 16 + l15;

  __shared__ __align__(16) u16 kls[64][72];
  __shared__ __align__(16) u16 vls[64][72];
  __shared__ __align__(16) u16 pls[4][16][72];
  __shared__ float pbs[4][16][69];   // per-wave pb tile [qrow][kcol], padded
  __shared__ float kpm[SPn];

  // staging geometry (per thread, i in {0,1})
  const int r0 = tid >> 3, c80 = (tid & 7) * 8;
  const int r1 = (256 + tid) >> 3, c81 = c80;
  const u16* kg0 = qkv + ((size_t)b * SPn + r0) * 3072 + 1024 + h * 64 + c80;
  const u16* kg1 = qkv + ((size_t)b * SPn + r1) * 3072 + 1024 + h * 64 + c81;
  const u16* vg0 = vT + ((size_t)bh * 64 + r0) * SPn + c80;
  const u16* vg1 = vT + ((size_t)bh * 64 + r1) * SPn + c81;

  // pb cooperative-load geometry: lane covers row (lane>>4), 16B at col (lane&15)*4
  const int prow = lane >> 4;          // 0..3, +4 per iter
  const int pcol = l15 * 4;
  // this wave's q-rows: q0 + wid*16 + row; clamp rows beyond Sn
  int pbq[4];
#pragma unroll
  for (int j = 0; j < 4; j++) {
    int qq = q0 + wid * 16 + j * 4 + prow;
    pbq[j] = (qq < Sn) ? qq : (Sn - 1);
  }
  const float* pbbase = pb + (size_t)bh * Sn * Sn;

  // Q fragment + gate
  bf16x8 qf[2];
  {
    const u16* qp = qkv + ((size_t)b * SPn + q) * 3072 + h * 64 + g4 * 8;
    qf[0] = *(const bf16x8*)qp;
    qf[1] = *(const bf16x8*)(qp + 32);
  }
  const float gr = gate[(size_t)bh * SPn + q];

  // prologue: stage tile 0 + kpm, single barrier
  {
    int4 k0v = *(const int4*)kg0;
    int4 k1v = *(const int4*)kg1;
    int4 v0v = *(const int4*)vg0;
    int4 v1v = *(const int4*)vg1;
#pragma unroll
    for (int j = 0; j < 6; j++) {
      int idx = tid + j * 256;
      kpm[idx] = (idx < Sn) ? (1.f - am[b * Sn + idx]) * -10000.f : -1e30f;
    }
    *(int4*)&kls[r0][c80] = k0v;
    *(int4*)&kls[r1][c81] = k1v;
    *(int4*)&vls[r0][c80] = v0v;
    *(int4*)&vls[r1][c81] = v1v;
  }
  __syncthreads();

  float m = -3.0e38f, l = 0.f;
  f32x4 accO[4];
  f32x4 zr; zr[0] = 0.f; zr[1] = 0.f; zr[2] = 0.f; zr[3] = 0.f;
#pragma unroll
  for (int i = 0; i < 4; i++) accO[i] = zr;

  for (int kt = 0; kt < 24; kt++) {
    const int k0 = kt * 64;
    // issue next tile's K/V loads into regs (overlap with compute below)
    int4 krn0, krn1, vrn0, vrn1;
    if (kt < 23) {
      const int k0n = k0 + 64;
      krn0 = *(const int4*)(kg0 + (size_t)k0n * 3072);
      krn1 = *(const int4*)(kg1 + (size_t)k0n * 3072);
      vrn0 = *(const int4*)(vg0 + k0n);
      vrn1 = *(const int4*)(vg1 + k0n);
    }
    // wave-cooperative coalesced pb tile load (wave-private LDS quadrant, no barrier)
    if (kt < 23) {
#pragma unroll
      for (int j = 0; j < 4; j++) {
        float4 pv = *(const float4*)(pbbase + (size_t)pbq[j] * Sn + k0 + pcol);
        *(float4*)&pbs[wid][j * 4 + prow][pcol] = pv;
      }
    } else {
#pragma unroll
      for (int j = 0; j < 4; j++) {
        float4 pv;
        int kk = k0 + pcol;
        const float* pr = pbbase + (size_t)pbq[j] * Sn;
        pv.x = (kk + 0 < Sn) ? pr[kk + 0] : 0.f;
        pv.y = (kk + 1 < Sn) ? pr[kk + 1] : 0.f;
        pv.z = (kk + 2 < Sn) ? pr[kk + 2] : 0.f;
        pv.w = (kk + 3 < Sn) ? pr[kk + 3] : 0.f;
        *(float4*)&pbs[wid][j * 4 + prow][pcol] = pv;
      }
    }

    // QK^T (swapped): A = K rows from LDS, B = Q regs
    f32x4 sAcc[4];
    __builtin_amdgcn_s_setprio(1);
#pragma unroll
    for (int km = 0; km < 4; km++) {
      sAcc[km] = zr;
#pragma unroll
      for (int dc = 0; dc < 2; dc++) {
        bf16x8 af = *(const bf16x8*)&kls[km * 16 + l15][dc * 32 + g4 * 8];
        sAcc[km] = __builtin_amdgcn_mfma_f32_16x16x32_bf16(af, qf[dc], sAcc[km], 0, 0, 0);
      }
    }
    __builtin_amdgcn_s_setprio(0);

    float sc[16];
#pragma unroll
    for (int km = 0; km < 4; km++) {
      int kk = k0 + km * 16 + g4 * 4;
      float4 kp = *(const float4*)&kpm[kk];
      float4 pbv = *(const float4*)&pbs[wid][l15][km * 16 + g4 * 4];
      sc[km * 4 + 0] = sAcc[km][0] * 0.125f + gr * pbv.x + kp.x;
      sc[km * 4 + 1] = sAcc[km][1] * 0.125f + gr * pbv.y + kp.y;
      sc[km * 4 + 2] = sAcc[km][2] * 0.125f + gr * pbv.z + kp.z;
      sc[km * 4 + 3] = sAcc[km][3] * 0.125f + gr * pbv.w + kp.w;
    }

    float mloc = sc[0];
#pragma unroll
    for (int i = 1; i < 16; i++) mloc = fmaxf(mloc, sc[i]);
    mloc = fmaxf(mloc, __shfl_xor(mloc, 16));
    mloc = fmaxf(mloc, __shfl_xor(mloc, 32));

    if (mloc > m + 8.f) {
      float corr = __expf(m - mloc);
      m = mloc;
      l *= corr;
#pragma unroll
      for (int i = 0; i < 4; i++) {
        accO[i][0] *= corr; accO[i][1] *= corr;
        accO[i][2] *= corr; accO[i][3] *= corr;
      }
    }

    float ls = 0.f;
#pragma unroll
    for (int i = 0; i < 16; i++) {
      float p = __expf(sc[i] - m);
      sc[i] = p;
      ls += p;
    }
    ls += __shfl_xor(ls, 16);
    ls += __shfl_xor(ls, 32);
    l += ls;

#pragma unroll
    for (int km = 0; km < 4; km++) {
      u32 lo = (u32)f2bu(sc[km * 4 + 0]) | ((u32)f2bu(sc[km * 4 + 1]) << 16);
      u32 hi = (u32)f2bu(sc[km * 4 + 2]) | ((u32)f2bu(sc[km * 4 + 3]) << 16);
      u32* dst = (u32*)&pls[wid][l15][km * 16 + g4 * 4];
      dst[0] = lo; dst[1] = hi;
    }

    bf16x8 pf[2];
    pf[0] = *(const bf16x8*)&pls[wid][l15][g4 * 8];
    pf[1] = *(const bf16x8*)&pls[wid][l15][32 + g4 * 8];
    __builtin_amdgcn_s_setprio(1);
#pragma unroll
    for (int dm = 0; dm < 4; dm++) {
#pragma unroll
      for (int kc = 0; kc < 2; kc++) {
        bf16x8 af = *(const bf16x8*)&vls[dm * 16 + l15][kc * 32 + g4 * 8];
        accO[dm] = __builtin_amdgcn_mfma_f32_16x16x32_bf16(af, pf[kc], accO[dm], 0, 0, 0);
      }
    }
    __builtin_amdgcn_s_setprio(0);

    // swap in the prefetched K/V tile
    __syncthreads();
    if (kt < 23) {
      *(int4*)&kls[r0][c80] = krn0;
      *(int4*)&kls[r1][c81] = krn1;
      *(int4*)&vls[r0][c80] = vrn0;
      *(int4*)&vls[r1][c81] = vrn1;
      __syncthreads();
    }
  }

  float inv = 1.f / l;
  const bool qv = q < Sn;
#pragma unroll
  for (int dm = 0; dm < 4; dm++) {
    ushort4 st;
    st.x = f2bu(qv ? accO[dm][0] * inv : 0.f);
    st.y = f2bu(qv ? accO[dm][1] * inv : 0.f);
    st.z = f2bu(qv ? accO[dm][2] * inv : 0.f);
    st.w = f2bu(qv ? accO[dm][3] * inv : 0.f);
    *(ushort4*)(ctx + ((size_t)b * SPn + q) * Cn + h * 64 + dm * 16 + g4 * 4) = st;
  }
}

// ---------------- fused 3-way residual (f32 + bf16 + bf16) + LayerNorm over C ----------------
__global__ __launch_bounds__(256) void k_ln3(
    const float* __restrict__ r1, const u16* __restrict__ r2,
    const u16* __restrict__ r3,
    const float* __restrict__ g, const float* __restrict__ be,
    float* __restrict__ outF, u16* __restrict__ outB)
{
  const int s = blockIdx.x, b = blockIdx.y;
  const size_t base = ((size_t)b * SPn + s) * Cn;
  __shared__ float red[8];
  const int tid = threadIdx.x;
  const int c = tid * 4;
  float4 a = *(const float4*)(r1 + base + c);
  ushort4 v2 = *(const ushort4*)(r2 + base + c);
  ushort4 v3 = *(const ushort4*)(r3 + base + c);
  float t0 = a.x + bu2f(v2.x) + bu2f(v3.x);
  float t1 = a.y + bu2f(v2.y) + bu2f(v3.y);
  float t2 = a.z + bu2f(v2.z) + bu2f(v3.z);
  float t3 = a.w + bu2f(v2.w) + bu2f(v3.w);
  float sum = t0 + t1 + t2 + t3;
#pragma unroll
  for (int mk = 1; mk < 64; mk <<= 1) sum += __shfl_xor(sum, mk);
  if ((tid & 63) == 0) red[tid >> 6] = sum;
  __syncthreads();
  float mu = (red[0] + red[1] + red[2] + red[3]) * (1.f / Cn);
  float d0 = t0 - mu, d1 = t1 - mu, d2 = t2 - mu, d3 = t3 - mu;
  float vs = d0 * d0 + d1 * d1 + d2 * d2 + d3 * d3;
#pragma unroll
  for (int mk = 1; mk < 64; mk <<= 1) vs += __shfl_xor(vs, mk);
  if ((tid & 63) == 0) red[4 + (tid >> 6)] = vs;
  __syncthreads();
  float var = (red[4] + red[5] + red[6] + red[7]) * (1.f / Cn);
  float rstd = rsqrtf(var + 1e-5f);
  float4 gv = *(const float4*)(g + c);
  float4 bv = *(const float4*)(be + c);
  float o0 = d0 * rstd * gv.x + bv.x;
  float o1 = d1 * rstd * gv.y + bv.y;
  float o2 = d2 * rstd * gv.z + bv.z;
  float o3 = d3 * rstd * gv.w + bv.w;
  float4 st; st.x = o0; st.y = o1; st.z = o2; st.w = o3;
  *(float4*)(outF + base + c) = st;
  if (outB) {
    ushort4 sb;
    sb.x = f2bu(o0); sb.y = f2bu(o1); sb.z = f2bu(o2); sb.w = f2bu(o3);
    *(ushort4*)(outB + base + c) = sb;
  }
}

extern "C" void kernel_launch(void* const* d_in, const int* in_sizes, int n_in,
                              void* d_out, int out_size, void* d_ws, size_t ws_size,
                              hipStream_t stream)
{
  const float* x    = (const float*)d_in[0];
  const float* am   = (const float*)d_in[1];
  const float* pb   = (const float*)d_in[2];
  const float* Wq   = (const float*)d_in[3];
  const float* bq   = (const float*)d_in[4];
  const float* Wk   = (const float*)d_in[5];
  const float* bk   = (const float*)d_in[6];
  const float* Wv   = (const float*)d_in[7];
  const float* bv   = (const float*)d_in[8];
  const float* Wo   = (const float*)d_in[9];
  const float* bo   = (const float*)d_in[10];
  const float* Wg   = (const float*)d_in[11];
  const float* bg   = (const float*)d_in[12];
  const float* gc   = (const float*)d_in[13];
  const float* ln1g = (const float*)d_in[14];
  const float* ln1b = (const float*)d_in[15];
  const float* W1   = (const float*)d_in[16];
  const float* b1   = (const float*)d_in[17];
  const float* W2   = (const float*)d_in[18];
  const float* b2   = (const float*)d_in[19];
  const float* ln2g = (const float*)d_in[20];
  const float* ln2b = (const float*)d_in[21];

  // workspace arena (94,580,736 bytes; lifetime-aliased)
  char* ws = (char*)d_ws;
  float* xT     = (float*)(ws + 0);            // [pre .. LN1]
  u16*   xTb    = (u16*)(ws + 12582912);       // [pre .. QKV] -> ctxT [flash..Wo]
  u16*   wqkvb  = (u16*)(ws + 18874368);       // [pre .. QKV] -> hTb [LN1..FFN1]
  u16*   wob    = (u16*)(ws + 25165824);
  u16*   w1b    = (u16*)(ws + 27262976);
  u16*   w2b    = (u16*)(ws + 35651584);
  float* bqkv   = (float*)(ws + 44040192);
  float* gate   = (float*)(ws + 44052480);
  u16*   qkvB   = (u16*)(ws + 44249088);       // [QKV .. flash]; then hT f32 [LN1..LN2]
  u16*   vT     = (u16*)(ws + 63123456);       // [QKV .. flash]
  u16*   attnTa = (u16*)(ws + 69414912);       // [Wo .. LN1] bf16
  u16*   attnTb = (u16*)(ws + 81997824);       // [Wo .. LN1] bf16
  u16*   ctxT   = xTb;
  float* hT     = (float*)(ws + 44249088);
  u16*   hTb    = wqkvb;
  u16*   fT     = (u16*)(ws + 56832000);       // [FFN1 .. FFN2]
  u16*   f2Ta   = (u16*)(ws + 0);              // [FFN2 .. LN2] bf16
  u16*   f2Tb   = (u16*)(ws + 81997824);       // [FFN2 .. LN2] bf16
  float* outT   = (float*)(ws + 12582912);     // [LN2 .. t_out]

  dim3 blk(256);
  k_pre<<<dim3(15555), blk, 0, stream>>>(x, Wq, Wk, Wv, Wo, W1, W2, bq, bk, bv,
                                         Wg, bg, gc, xT, xTb, wqkvb, wob, w1b,
                                         w2b, bqkv, gate);

  // QKV projection -> bf16 (+fused V^T): M=3072, K=1024, TM=96 -> 768 blocks
  k_gemm<2, 1, 96><<<dim3(32, 12, Bn), blk, 0, stream>>>(
      wqkvb, xTb, bqkv, qkvB, qkvB, vT, 3072, 1024, 1024);
  // MFMA flash attention (768 blocks)
  k_flash_mfma<<<dim3(SPn / 64, Bn * Hn), blk, 0, stream>>>(qkvB, vT, pb, am, gate, ctxT);
  // Wo: M=1024, K=1024, TM=64, split-K=2 -> 768 blocks, bf16 partials
  k_gemm<2, 2, 64><<<dim3(16, 12, Bn * 2), blk, 0, stream>>>(
      wob, ctxT, bo, attnTa, attnTb, (u16*)nullptr, 1024, 1024, 1024);
  // LN1 = LN(x + attnA + attnB) -> hT (f32) + hTb (bf16)
  k_ln3<<<dim3(SPn, Bn), blk, 0, stream>>>(xT, attnTa, attnTb, ln1g, ln1b, hT, hTb);
  // FFN1 + gelu -> fT (bf16): M=4096, K=1024, TM=128 -> 768 blocks
  k_gemm<1, 1, 128><<<dim3(32, 12, Bn), blk, 0, stream>>>(
      w1b, hTb, b1, fT, fT, (u16*)nullptr, 4096, 1024, 1024);
  // FFN2: M=1024, K=4096, TM=64, split-K=2 -> 768 blocks, bf16 partials
  k_gemm<2, 2, 64><<<dim3(16, 12, Bn * 2), blk, 0, stream>>>(
      w2b, fT, b2, f2Ta, f2Tb, (u16*)nullptr, 1024, 4096, 4096);
  // LN2 = LN(h + f2a + f2b) -> outT
  k_ln3<<<dim3(SPn, Bn), blk, 0, stream>>>(hT, f2Ta, f2Tb, ln2g, ln2b, outT, (u16*)nullptr);
  // back to (B,C,1,S)
  k_transpose_out<<<dim3(Cn / 32, SPn / 32, Bn), blk, 0, stream>>>(outT, (float*)d_out);
}